// Round 12
// baseline (326.456 us; speedup 1.0000x reference)
//
#include <hip/hip_runtime.h>

// ---------------------------------------------------------------------------
// FastMultiHeadAttention on MI355X (gfx950)
// Round 12: attn goes single-buffered-LDS (16.4KB) + __launch_bounds__(256,8)
// + grid 2048 -> 8 blocks/CU; cross-block TLP hides staging latency (m114)
// instead of intra-block double-buffering (which capped residency at 4/CU
// and left VALU 38% busy). Global longest-first queue unchanged (R10/R7
// scheduler experiments both lost to it). transposeV+rowflag fused into one
// dispatch; merge_k+fixrows fused (merge skips L==0 rows -> no write race).
// ---------------------------------------------------------------------------

typedef __attribute__((ext_vector_type(8))) short bf16x8;
typedef __attribute__((ext_vector_type(4))) float f32x4;
typedef __attribute__((ext_vector_type(4))) unsigned short us4;

#define KNEG -15000.0f              // masked logit in log2 units; exp2 -> 0
#define CEXP 0.18033688011112042f   // 0.125 * log2(e)
#define L2E  1.4426950408889634f

__device__ __forceinline__ unsigned short f2bf(float f) {
  union { float f; unsigned u; } x; x.f = f;
  unsigned r = x.u + 0x7fffu + ((x.u >> 16) & 1u);
  return (unsigned short)(r >> 16);
}

__device__ __forceinline__ float bf2f(unsigned short u) {
  union { unsigned u; float f; } x; x.u = (unsigned)u << 16;
  return x.f;
}

__device__ __forceinline__ float fexp2(float x) {
  return __builtin_amdgcn_exp2f(x);
}

__device__ __forceinline__ void load_lds16(const void* g, void* l) {
  __builtin_amdgcn_global_load_lds(
      (const __attribute__((address_space(1))) void*)g,
      (__attribute__((address_space(3))) void*)l, 16, 0, 0);
}

// -------------------- fused pack kernel --------------------

__device__ __forceinline__ void pack8(const float* __restrict__ src,
                                      unsigned short* __restrict__ dst) {
  const float4* p = (const float4*)src;
  float4 a = p[0], b = p[1];
  bf16x8 o;
  o[0] = (short)f2bf(a.x); o[1] = (short)f2bf(a.y);
  o[2] = (short)f2bf(a.z); o[3] = (short)f2bf(a.w);
  o[4] = (short)f2bf(b.x); o[5] = (short)f2bf(b.y);
  o[6] = (short)f2bf(b.z); o[7] = (short)f2bf(b.w);
  *(bf16x8*)dst = o;
}

__global__ __launch_bounds__(256) void pack_all(
    const float* __restrict__ q, const float* __restrict__ k,
    const float* __restrict__ v, const float* __restrict__ W_qkv,
    const float* __restrict__ W_out, const int* __restrict__ mask,
    unsigned short* __restrict__ xb, unsigned short* __restrict__ wqkvb,
    unsigned short* __restrict__ woutb, unsigned* __restrict__ maskw) {
  const int b = blockIdx.x;
  const int tid = threadIdx.x;
  if (b < 4608) {
    int idx = b * 256 + tid;
    int t = idx / 288;
    int c2 = (idx - t * 288) * 8;
    const float* src;
    int c;
    if (c2 < 768)       { src = q; c = c2; }
    else if (c2 < 1536) { src = k; c = c2 - 768; }
    else                { src = v; c = c2 - 1536; }
    pack8(src + (size_t)t * 768 + c, xb + (size_t)t * 2304 + c2);
  } else if (b < 7200) {
    int idx = (b - 4608) * 256 + tid;
    pack8(W_qkv + (size_t)idx * 8, wqkvb + (size_t)idx * 8);
  } else if (b < 7488) {
    int idx = (b - 7200) * 256 + tid;
    pack8(W_out + (size_t)idx * 8, woutb + (size_t)idx * 8);
  } else {
    int lane = tid & 63;
    int wid0 = ((b - 7488) * 256 + tid) >> 6;
    for (int wid = wid0; wid < 262144; wid += 8192) {
      int row = wid >> 6;
      int wp = wid & 63;
      int s = wp * 64 + lane;
      int mval = mask[(size_t)row * 4096 + s];
      unsigned long long bb = __ballot(mval != 0);
      if (lane == 0) {
        maskw[row * 128 + wp * 2]     = (unsigned)bb;
        maskw[row * 128 + wp * 2 + 1] = (unsigned)(bb >> 32);
      }
    }
  }
}

// -------- fused: transposeV (blocks 0..767) + rowflag (blocks 768..1023) ---
// transposeV: vt[h*64+d][t] = qkvb[t][h*192+128+d]  (bf16, [768][4096])
// rowflag: list rows with NO set mask bit in the attended range.

__global__ __launch_bounds__(256) void tv_rowflag(
    const unsigned short* __restrict__ qkvb, unsigned short* __restrict__ vt,
    const unsigned* __restrict__ maskw, const int* __restrict__ mask_future,
    int* __restrict__ cnt, int* __restrict__ list) {
  const int b = blockIdx.x;
  const int tid = threadIdx.x;
  if (b < 768) {
    __shared__ unsigned short tl[64][65];
    const int t0 = (b & 63) * 64;
    const int hsrc = (b >> 6) * 192 + 128;
    for (int pass = 0; pass < 2; ++pass) {
      int r = (tid >> 3) + pass * 32;
      int fc = (tid & 7) * 8;
      bf16x8 vv = *(const bf16x8*)&qkvb[(size_t)(t0 + r) * 2304 + hsrc + fc];
      for (int e = 0; e < 8; ++e) tl[fc + e][r] = (unsigned short)vv[e];
    }
    __syncthreads();
    const int f = tid >> 2;
    const int sg = (tid & 3) * 16;
    for (int j = 0; j < 2; ++j) {
      bf16x8 o;
      for (int e = 0; e < 8; ++e) o[e] = (short)tl[f][sg + j * 8 + e];
      *(bf16x8*)&vt[(size_t)((b >> 6) * 64 + f) * 4096 + t0 + sg + j * 8] = o;
    }
  } else {
    const bool causal = (mask_future[0] != 0);
    int wv = ((b - 768) * 256 + tid) >> 6;  // 0..1023
    int lane = tid & 63;
    for (int row = wv * 4; row < wv * 4 + 4; ++row) {
      unsigned acc = 0;
      int jmax = causal ? (row >> 5) : 127;
      for (int j = lane; j <= jmax; j += 64) {
        unsigned wb = maskw[row * 128 + j];
        if (causal && j == jmax) {
          int rem = row & 31;
          wb &= (rem == 31) ? 0xffffffffu : ((2u << rem) - 1u);
        }
        acc |= wb;
      }
      if (!__any(acc != 0)) {
        if (lane == 0) {
          int i = atomicAdd(cnt, 1);
          if (i < 64) list[i] = row;
        }
      }
    }
  }
}

// ------------- GEMM: C[M][N] = A[M][K] * B[N][K]^T, BM=128, BN=NF*32 -------

__device__ __forceinline__ void storeC(float* p, float v) { *p = v; }
__device__ __forceinline__ void storeC(unsigned short* p, float v) { *p = f2bf(v); }

template <typename OutT, int NF>
__global__ __launch_bounds__(256) void gemm_bt(const unsigned short* __restrict__ A,
                                               const unsigned short* __restrict__ B,
                                               OutT* __restrict__ C,
                                               int M, int N, int K) {
  constexpr int BN = NF * 32;
  __shared__ unsigned short As[128 * 64];
  __shared__ unsigned short Bs[BN * 64];
  const int tid = threadIdx.x;
  const int lane = tid & 63;
  const int w = tid >> 6;
  const int wr = w >> 1, wc = w & 1;
  const int l15 = lane & 15, lhi = lane >> 4;

  int lblk = blockIdx.y * gridDim.x + blockIdx.x;
  int nwg = gridDim.x * gridDim.y;
  int sw = (lblk & 7) * (nwg >> 3) + (lblk >> 3);
  int bxg = sw % gridDim.x;
  int byg = sw / gridDim.x;

  const size_t abase = (size_t)(bxg * 128) * K;
  const size_t bbase = (size_t)(byg * BN) * K;

  f32x4 acc[4][NF] = {};

  for (int k0 = 0; k0 < K; k0 += 64) {
    __syncthreads();
    #pragma unroll
    for (int i = 0; i < 4; ++i) {
      int c = (w << 8) + (i << 6) + lane;
      int row = c >> 3, cb = c & 7;
      load_lds16(A + abase + (size_t)row * K + k0 + cb * 8, &As[c * 8]);
    }
    #pragma unroll
    for (int i = 0; i < NF; ++i) {
      int c = w * (NF * 64) + (i << 6) + lane;
      int row = c >> 3, cb = c & 7;
      load_lds16(B + bbase + (size_t)row * K + k0 + cb * 8, &Bs[c * 8]);
    }
    __syncthreads();
    #pragma unroll
    for (int kk = 0; kk < 2; ++kk) {
      bf16x8 af[4], bfr[NF];
      #pragma unroll
      for (int m = 0; m < 4; ++m)
        af[m] = *(const bf16x8*)&As[(wr * 64 + m * 16 + l15) * 64 + kk * 32 + lhi * 8];
      #pragma unroll
      for (int n = 0; n < NF; ++n)
        bfr[n] = *(const bf16x8*)&Bs[(wc * NF * 16 + n * 16 + l15) * 64 + kk * 32 + lhi * 8];
      #pragma unroll
      for (int m = 0; m < 4; ++m)
        #pragma unroll
        for (int n = 0; n < NF; ++n)
          acc[m][n] = __builtin_amdgcn_mfma_f32_16x16x32_bf16(af[m], bfr[n], acc[m][n], 0, 0, 0);
    }
  }

  #pragma unroll
  for (int m = 0; m < 4; ++m) {
    int row0 = bxg * 128 + wr * 64 + m * 16 + lhi * 4;
    #pragma unroll
    for (int n = 0; n < NF; ++n) {
      int col = byg * BN + wc * NF * 16 + n * 16 + l15;
      #pragma unroll
      for (int r = 0; r < 4; ++r)
        storeC(&C[(size_t)(row0 + r) * N + col], acc[m][n][r]);
    }
  }
}

// -------------------- attention (single-buffer LDS, 8 blocks/CU) -----------
// Global 1296-item longest-first queue (C=28 split-K). Max-free softmax:
// Q pre-scaled by CEXP, p = exp2(logit), masked -> KNEG -> 0. Single K/V
// LDS buffer; staging latency hidden by 8-blocks/CU TLP (m114), not by
// intra-block double buffering.

__global__ __launch_bounds__(256, 8) void attn_kernel(
    const unsigned short* __restrict__ qkv,  // [4096][2304] bf16
    const unsigned short* __restrict__ vt,   // [768][4096] bf16 V^T
    const unsigned* __restrict__ maskw,      // [4096][128]
    const int* __restrict__ mask_future,
    int* __restrict__ ctr,
    float* __restrict__ parts,               // [1296][4224] f32 (O|l)
    unsigned short* __restrict__ scr) {      // scrambled [4096*768] bf16
  const int tid = threadIdx.x;
  const int lane = tid & 63;
  const int w = tid >> 6;
  const int l15 = lane & 15, lhi = lane >> 4;
  const bool causal = (mask_future[0] != 0);
  const int srcA = l15 + (((2 * lhi) & 3) << 4);
  const int srcB = l15 + (((2 * lhi + 1) & 3) << 4);
  const int hi2 = lhi >> 1;

  __shared__ unsigned short Klds[64 * 64];  // [key][d], swizzled
  __shared__ unsigned short Vs[64 * 64];    // [d][key], swizzled
  __shared__ int item_s;

  // per-lane staging geometry (item-invariant)
  int srow[2], scb[2];
  #pragma unroll
  for (int i = 0; i < 2; ++i) {
    int cc = (w << 7) + (i << 6) + lane;
    srow[i] = cc >> 3;
    scb[i] = ((cc & 7) ^ (srow[i] & 7)) * 8;
  }

  for (;;) {
    if (tid == 0) item_s = atomicAdd(ctr, 1);
    __syncthreads();  // publish item
    const int idx = item_s;
    if (idx >= 1296) break;
    int c, bx, h;
    if (idx < 444)      { c = 0; bx = 63 - idx / 12; h = idx % 12; }
    else if (idx < 552) { int j = idx - 444; c = 1; bx = 63 - j / 12; h = j % 12; }
    else if (idx < 1008) {
      int j = idx - 552; int L = 27 - j / 24; int u = j % 24;
      c = (u < 12) ? 1 : 0; bx = c ? (27 + L) : (L - 1); h = u % 12;
    } else {
      int j = idx - 1008; int L = 8 - j / 36; int u = j % 36;
      c = (u < 12) ? 2 : ((u < 24) ? 1 : 0);
      bx = (c == 2) ? (55 + L) : ((c == 1) ? (27 + L) : (L - 1)); h = u % 12;
    }

    int t0c, t1c, diag;
    bool split;
    if (causal) {
      t0c = c * 28;
      t1c = min(t0c + 28, bx + 1);
      diag = bx;
      split = (bx >= 28);
    } else {  // non-causal: c=0 items do the whole range, others skip
      if (c != 0) continue;
      t0c = 0; t1c = 64; diag = 64; split = false;
    }
    const int hoff = h * 192;
    const int l0 = bx << 6;
    const int lq = l0 + w * 16 + l15;

    // hoisted staging base pointers (advance by tile)
    const unsigned short* kb[2];
    const unsigned short* vb[2];
    #pragma unroll
    for (int i = 0; i < 2; ++i) {
      kb[i] = qkv + (size_t)(t0c * 64 + srow[i]) * 2304 + hoff + 64 + scb[i];
      vb[i] = vt + (size_t)(h * 64 + srow[i]) * 4096 + t0c * 64 + scb[i];
    }

    // Q B-fragments, pre-scaled by CEXP (logits emerge in log2 units)
    bf16x8 qf[2];
    {
      const unsigned short* qp = qkv + (size_t)lq * 2304 + hoff;
      qf[0] = *(const bf16x8*)(qp + lhi * 8);
      qf[1] = *(const bf16x8*)(qp + 32 + lhi * 8);
      #pragma unroll
      for (int i = 0; i < 2; ++i) {
        union { bf16x8 v; unsigned u[4]; } qa; qa.v = qf[i];
        #pragma unroll
        for (int p = 0; p < 4; ++p) {
          float lo = bf2f((unsigned short)(qa.u[p] & 0xffff)) * CEXP;
          float hi = bf2f((unsigned short)(qa.u[p] >> 16)) * CEXP;
          asm("v_cvt_pk_bf16_f32 %0, %1, %2" : "=v"(qa.u[p]) : "v"(lo), "v"(hi));
        }
        qf[i] = qa.v;
      }
    }
    const unsigned* mrow_p = maskw + lq * 128;
    uint2 mk_next = *(const uint2*)(mrow_p + t0c * 2);

    f32x4 oacc[4] = {};
    float lrow = 0.f;

    for (int it = t0c; it < t1c; ++it) {
      __syncthreads();  // previous tile's LDS reads done; buffer free

      // stage tile it (single buffer)
      #pragma unroll
      for (int i = 0; i < 2; ++i) {
        int cc = (w << 7) + (i << 6) + lane;
        load_lds16(kb[i], &Klds[cc * 8]);
        load_lds16(vb[i], &Vs[cc * 8]);
        kb[i] += 64 * 2304;
        vb[i] += 64;
      }
      uint2 mk = mk_next;
      if (it + 1 < t1c) mk_next = *(const uint2*)(mrow_p + (it + 1) * 2);

      __syncthreads();  // stage drained (vmcnt 0) -> LDS ready

      const int s0 = it * 64;

      // S^T (log2 units) = mfma(A=K, B=Q·CEXP); lane: S[q=lq][k=s0+n*16+lhi*4+r]
      f32x4 sacc[4] = {};
      __builtin_amdgcn_s_setprio(1);
      #pragma unroll
      for (int kk = 0; kk < 2; ++kk) {
        bf16x8 kf[4];
        #pragma unroll
        for (int n = 0; n < 4; ++n) {
          int rk = n * 16 + l15;
          int col = (kk * 32 + lhi * 8) ^ ((rk & 7) << 3);
          kf[n] = *(const bf16x8*)&Klds[rk * 64 + col];
        }
        #pragma unroll
        for (int n = 0; n < 4; ++n)
          sacc[n] = __builtin_amdgcn_mfma_f32_16x16x32_bf16(kf[n], qf[kk], sacc[n], 0, 0, 0);
      }
      __builtin_amdgcn_s_setprio(0);

      // masked logits -> p = exp2(logit); masked -> exp2(KNEG) = 0
      float vals[4][4];
      {
        unsigned a = mk.x >> (lhi * 4);
        unsigned b = mk.y >> (lhi * 4);
        if (it < diag) {
          #pragma unroll
          for (int n = 0; n < 4; ++n) {
            unsigned wsh = ((n < 2) ? a : b) >> ((n & 1) << 4);
            #pragma unroll
            for (int r = 0; r < 4; ++r)
              vals[n][r] = ((wsh >> r) & 1u) ? sacc[n][r] : KNEG;
          }
        } else {  // diagonal tile
          #pragma unroll
          for (int n = 0; n < 4; ++n) {
            unsigned wsh = ((n < 2) ? a : b) >> ((n & 1) << 4);
            int kb2 = s0 + n * 16 + lhi * 4;
            #pragma unroll
            for (int r = 0; r < 4; ++r) {
              float vv = (kb2 + r > lq) ? KNEG : sacc[n][r];
              vals[n][r] = ((wsh >> r) & 1u) ? vv : KNEG;
            }
          }
        }
      }

      float psum = 0.f;
      #pragma unroll
      for (int n = 0; n < 4; ++n)
        #pragma unroll
        for (int r = 0; r < 4; ++r) {
          float p = fexp2(vals[n][r]);
          vals[n][r] = p;
          psum += p;
        }
      psum += __shfl_xor(psum, 16);
      psum += __shfl_xor(psum, 32);
      lrow += psum;

      // pack P to bf16 pairs
      unsigned pk[4][2];
      #pragma unroll
      for (int n = 0; n < 4; ++n)
        #pragma unroll
        for (int rp = 0; rp < 2; ++rp)
          asm("v_cvt_pk_bf16_f32 %0, %1, %2"
              : "=v"(pk[n][rp])
              : "v"(vals[n][2 * rp]), "v"(vals[n][2 * rp + 1]));

      // PV
      #pragma unroll
      for (int kk = 0; kk < 2; ++kk) {
        unsigned a0 = __shfl(pk[2 * kk][0], srcA);
        unsigned a1 = __shfl(pk[2 * kk][1], srcA);
        unsigned a2 = __shfl(pk[2 * kk][0], srcB);
        unsigned a3 = __shfl(pk[2 * kk][1], srcB);
        unsigned b0 = __shfl(pk[2 * kk + 1][0], srcA);
        unsigned b1 = __shfl(pk[2 * kk + 1][1], srcA);
        unsigned b2 = __shfl(pk[2 * kk + 1][0], srcB);
        unsigned b3 = __shfl(pk[2 * kk + 1][1], srcB);
        union { bf16x8 v; unsigned u[4]; } af;
        af.u[0] = hi2 ? b0 : a0;
        af.u[1] = hi2 ? b1 : a1;
        af.u[2] = hi2 ? b2 : a2;
        af.u[3] = hi2 ? b3 : a3;
        __builtin_amdgcn_s_setprio(1);
        #pragma unroll
        for (int n = 0; n < 4; ++n) {
          int rv = n * 16 + l15;
          int col = (kk * 32 + lhi * 8) ^ ((rv & 7) << 3);
          bf16x8 vf = *(const bf16x8*)&Vs[rv * 64 + col];
          oacc[n] = __builtin_amdgcn_mfma_f32_16x16x32_bf16(af.v, vf, oacc[n], 0, 0, 0);
        }
        __builtin_amdgcn_s_setprio(0);
      }
    }

    // ---------- finalize ----------
    float lqv[4];
    #pragma unroll
    for (int r = 0; r < 4; ++r)
      lqv[r] = __shfl(lrow, (lhi << 2) + r);
    const int row0 = w * 16 + lhi * 4;

    if (split) {
      int prefix = bx + max(bx - 28, 0) + max(bx - 56, 0);
      float* pg = parts + (size_t)((prefix + c) * 12 + h) * 4224;
      #pragma unroll
      for (int n = 0; n < 4; ++n)
        #pragma unroll
        for (int r = 0; r < 4; ++r)
          pg[(size_t)(row0 + r) * 64 + n * 16 + l15] = oacc[n][r];
      if (l15 == 0) {
        #pragma unroll
        for (int r = 0; r < 4; ++r)
          pg[4096 + row0 + r] = lqv[r];
      }
    } else {
      float rq[4];
      #pragma unroll
      for (int r = 0; r < 4; ++r) rq[r] = 1.0f / lqv[r];
      #pragma unroll
      for (int n = 0; n < 4; ++n) {
        int d = n * 16 + l15;
        size_t base = (size_t)h * 262144 + (size_t)d * 4096 + (size_t)(l0 + row0);
        us4 o;
        #pragma unroll
        for (int r = 0; r < 4; ++r) o[r] = f2bf(oacc[n][r] * rq[r]);
        *(us4*)(scr + base) = o;
      }
    }
  }
}

// -------- fused: merge_k (blocks 0..431) + fixrows (blocks 432..1199) ------
// merge: pure sums of 2-3 chunks; SKIPS rows with L==0 (degenerate rows,
// exactly those fixrows writes) -> no same-byte race between block ranges.

__global__ __launch_bounds__(256) void merge_fix(
    const float* __restrict__ parts, const unsigned short* __restrict__ qkv,
    const unsigned short* __restrict__ vt, const unsigned* __restrict__ maskw,
    const int* __restrict__ mask_future, const int* __restrict__ cnt,
    const int* __restrict__ list, unsigned short* __restrict__ scr) {
  const int b = blockIdx.x;
  const bool causal = (mask_future[0] != 0);
  if (b < 432) {
    if (!causal) return;  // non-causal: no splits
    const int sg = b;
    const int bx = 28 + sg / 12;
    const int h = sg % 12;
    const int nch = 2 + (bx >= 56);
    const int prefix = bx + max(bx - 28, 0) + max(bx - 56, 0);
    const int t = threadIdx.x;
    const int row = t >> 2;
    const int dg = (t & 3) * 16;

    const float* pg[3];
    for (int cc = 0; cc < 3; ++cc)
      pg[cc] = parts + (size_t)((prefix + min(cc, nch - 1)) * 12 + h) * 4224;

    float L = pg[0][4096 + row] + pg[1][4096 + row];
    if (nch == 3) L += pg[2][4096 + row];
    if (L == 0.f) return;  // degenerate row: fixrows owns it (no race)
    float rL = 1.0f / L;

    #pragma unroll
    for (int dd = 0; dd < 16; ++dd) {
      int d = dg + dd;
      float o = pg[0][(size_t)row * 64 + d] + pg[1][(size_t)row * 64 + d];
      if (nch == 3) o += pg[2][(size_t)row * 64 + d];
      scr[(size_t)h * 262144 + (size_t)d * 4096 + bx * 64 + row] = f2bf(o * rL);
    }
  } else {
    const int bb = b - 432;
    const int i = bb / 12;
    const int h = bb % 12;
    int n = *cnt; if (n > 64) n = 64;
    if (i >= n) return;
    const int row = list[i];
    const int tid = threadIdx.x;
    const int lane = tid & 63;
    const int wv = tid >> 6;

    __shared__ float qs[64];
    __shared__ float ps[4096];
    __shared__ float red[16];

    if (tid < 64) qs[tid] = bf2f(qkv[(size_t)row * 2304 + h * 192 + tid]);
    __syncthreads();

    float pv[16];
    float mymax = -INFINITY;
    #pragma unroll
    for (int kk = 0; kk < 16; ++kk) {
      int key = tid * 16 + kk;
      const unsigned short* kp = qkv + (size_t)key * 2304 + h * 192 + 64;
      float s = 0.f;
      #pragma unroll
      for (int d8 = 0; d8 < 8; ++d8) {
        bf16x8 kv8 = *(const bf16x8*)(kp + d8 * 8);
        #pragma unroll
        for (int e = 0; e < 8; ++e)
          s += qs[d8 * 8 + e] * bf2f((unsigned short)kv8[e]);
      }
      s *= 0.125f;
      unsigned bit = (maskw[row * 128 + (key >> 5)] >> (key & 31)) & 1u;
      float val = bit ? ((causal && key > row) ? s - 10000.f : s) : -10000.f;
      pv[kk] = val;
      mymax = fmaxf(mymax, val);
    }
    for (int xx = 1; xx < 64; xx <<= 1) mymax = fmaxf(mymax, __shfl_xor(mymax, xx));
    if (lane == 0) red[wv] = mymax;
    __syncthreads();
    const float M = fmaxf(fmaxf(red[0], red[1]), fmaxf(red[2], red[3]));

    float sum = 0.f;
    #pragma unroll
    for (int kk = 0; kk < 16; ++kk) {
      float p = fexp2((pv[kk] - M) * L2E);
      ps[tid * 16 + kk] = p;
      sum += p;
    }
    for (int xx = 1; xx < 64; xx <<= 1) sum += __shfl_xor(sum, xx);
    if (lane == 0) red[8 + wv] = sum;
    __syncthreads();
    const float L = red[8] + red[9] + red[10] + red[11];

    const int d = tid >> 2, qq = tid & 3;
    float acc = 0.f;
    for (int jb = qq * 1024; jb < qq * 1024 + 1024; jb += 8) {
      bf16x8 vv8 = *(const bf16x8*)&vt[(size_t)(h * 64 + d) * 4096 + jb];
      #pragma unroll
      for (int e = 0; e < 8; ++e)
        acc += ps[jb + e] * bf2f((unsigned short)vv8[e]);
    }
    acc += __shfl_xor(acc, 1);
    acc += __shfl_xor(acc, 2);
    if (qq == 0)
      scr[(size_t)h * 262144 + (size_t)d * 4096 + row] = f2bf(acc / L);
  }
}

// -------------------- launch --------------------

extern "C" void kernel_launch(void* const* d_in, const int* in_sizes, int n_in,
                              void* d_out, int out_size, void* d_ws, size_t ws_size,
                              hipStream_t stream) {
  const float* q = (const float*)d_in[0];
  const float* k = (const float*)d_in[1];
  const float* v = (const float*)d_in[2];
  const int* attn_mask = (const int*)d_in[3];
  const int* mask_future = (const int*)d_in[4];
  const float* W_qkv = (const float*)d_in[5];
  const float* W_out = (const float*)d_in[6];
  float* out = (float*)d_out;

  char* ws = (char*)d_ws;
  unsigned short* xb    = (unsigned short*)(ws);            // [0,18.87M) live until qkv GEMM
  unsigned short* vt    = (unsigned short*)(ws);            // [0,6.29M) after tv_rowflag
  char*           ctl   = ws + 6291456;                     // 4KB, memset AFTER gemm
  int*            ctr   = (int*)(ctl);
  int*            cnt   = (int*)(ctl + 256);
  int*            list  = (int*)(ctl + 1024);               // [64]
  float*          parts = (float*)(ws + 6295552);           // 1296*4224*4 = 21.90MB
  unsigned short* wqkvb = (unsigned short*)(ws + 18874368); // dead after qkv GEMM
  unsigned short* qkvb  = (unsigned short*)(ws + 29491200);
  unsigned*       maskw = (unsigned*)(ws + 48365568);
  unsigned short* scr   = (unsigned short*)(ws + 50462720);
  unsigned short* woutb = (unsigned short*)(ws + 56754176);
  if (ws_size < 57933824) return;

  pack_all<<<9536, 256, 0, stream>>>(q, k, v, W_qkv, W_out, attn_mask,
                                     xb, wqkvb, woutb, maskw);
  gemm_bt<unsigned short, 3><<<dim3(32, 24), 256, 0, stream>>>(xb, wqkvb, qkvb, 4096, 2304, 2304);
  hipMemsetAsync(ctl, 0, 4096, stream);   // AFTER gemm: xb dead (R6 lesson)
  tv_rowflag<<<1024, 256, 0, stream>>>(qkvb, vt, maskw, mask_future, cnt, list);
  attn_kernel<<<2048, 256, 0, stream>>>(qkvb, vt, maskw, mask_future, ctr, parts, scr);
  merge_fix<<<1200, 256, 0, stream>>>(parts, qkvb, vt, maskw, mask_future, cnt, list, scr);
  gemm_bt<float, 3><<<dim3(32, 8), 256, 0, stream>>>(scr, woutb, out, 4096, 768, 768);
}

// Round 13
// 217.576 us; speedup vs baseline: 1.5004x; 1.5004x over previous
//
#include <hip/hip_runtime.h>

// ---------------------------------------------------------------------------
// FastMultiHeadAttention on MI355X (gfx950)
// Round 13: R12 structure minus the launch_bounds footgun. Single-buffered
// K/V LDS (16.9KB -> up to 9 blocks/CU by LDS) with PLAIN launch_bounds(256):
// R12's (256,8) forced total(VGPR+AGPR)<=64 on the unified gfx950 file ->
// 32 arch VGPRs -> 405MB of scratch spill traffic. Natural allocation (~64
// arch + acc) gives 6-8 waves/SIMD without spill; cross-block TLP hides the
// single-buffer staging latency (m114). Global longest-first queue, max-free
// exp2 softmax, fused tv_rowflag + merge_fix kernels (all R12-proven).
// ---------------------------------------------------------------------------

typedef __attribute__((ext_vector_type(8))) short bf16x8;
typedef __attribute__((ext_vector_type(4))) float f32x4;
typedef __attribute__((ext_vector_type(4))) unsigned short us4;

#define KNEG -15000.0f              // masked logit in log2 units; exp2 -> 0
#define CEXP 0.18033688011112042f   // 0.125 * log2(e)
#define L2E  1.4426950408889634f

__device__ __forceinline__ unsigned short f2bf(float f) {
  union { float f; unsigned u; } x; x.f = f;
  unsigned r = x.u + 0x7fffu + ((x.u >> 16) & 1u);
  return (unsigned short)(r >> 16);
}

__device__ __forceinline__ float bf2f(unsigned short u) {
  union { unsigned u; float f; } x; x.u = (unsigned)u << 16;
  return x.f;
}

__device__ __forceinline__ float fexp2(float x) {
  return __builtin_amdgcn_exp2f(x);
}

__device__ __forceinline__ void load_lds16(const void* g, void* l) {
  __builtin_amdgcn_global_load_lds(
      (const __attribute__((address_space(1))) void*)g,
      (__attribute__((address_space(3))) void*)l, 16, 0, 0);
}

// -------------------- fused pack kernel --------------------

__device__ __forceinline__ void pack8(const float* __restrict__ src,
                                      unsigned short* __restrict__ dst) {
  const float4* p = (const float4*)src;
  float4 a = p[0], b = p[1];
  bf16x8 o;
  o[0] = (short)f2bf(a.x); o[1] = (short)f2bf(a.y);
  o[2] = (short)f2bf(a.z); o[3] = (short)f2bf(a.w);
  o[4] = (short)f2bf(b.x); o[5] = (short)f2bf(b.y);
  o[6] = (short)f2bf(b.z); o[7] = (short)f2bf(b.w);
  *(bf16x8*)dst = o;
}

__global__ __launch_bounds__(256) void pack_all(
    const float* __restrict__ q, const float* __restrict__ k,
    const float* __restrict__ v, const float* __restrict__ W_qkv,
    const float* __restrict__ W_out, const int* __restrict__ mask,
    unsigned short* __restrict__ xb, unsigned short* __restrict__ wqkvb,
    unsigned short* __restrict__ woutb, unsigned* __restrict__ maskw) {
  const int b = blockIdx.x;
  const int tid = threadIdx.x;
  if (b < 4608) {
    int idx = b * 256 + tid;
    int t = idx / 288;
    int c2 = (idx - t * 288) * 8;
    const float* src;
    int c;
    if (c2 < 768)       { src = q; c = c2; }
    else if (c2 < 1536) { src = k; c = c2 - 768; }
    else                { src = v; c = c2 - 1536; }
    pack8(src + (size_t)t * 768 + c, xb + (size_t)t * 2304 + c2);
  } else if (b < 7200) {
    int idx = (b - 4608) * 256 + tid;
    pack8(W_qkv + (size_t)idx * 8, wqkvb + (size_t)idx * 8);
  } else if (b < 7488) {
    int idx = (b - 7200) * 256 + tid;
    pack8(W_out + (size_t)idx * 8, woutb + (size_t)idx * 8);
  } else {
    int lane = tid & 63;
    int wid0 = ((b - 7488) * 256 + tid) >> 6;
    for (int wid = wid0; wid < 262144; wid += 8192) {
      int row = wid >> 6;
      int wp = wid & 63;
      int s = wp * 64 + lane;
      int mval = mask[(size_t)row * 4096 + s];
      unsigned long long bb = __ballot(mval != 0);
      if (lane == 0) {
        maskw[row * 128 + wp * 2]     = (unsigned)bb;
        maskw[row * 128 + wp * 2 + 1] = (unsigned)(bb >> 32);
      }
    }
  }
}

// -------- fused: transposeV (blocks 0..767) + rowflag (blocks 768..1023) ---

__global__ __launch_bounds__(256) void tv_rowflag(
    const unsigned short* __restrict__ qkvb, unsigned short* __restrict__ vt,
    const unsigned* __restrict__ maskw, const int* __restrict__ mask_future,
    int* __restrict__ cnt, int* __restrict__ list) {
  const int b = blockIdx.x;
  const int tid = threadIdx.x;
  if (b < 768) {
    __shared__ unsigned short tl[64][65];
    const int t0 = (b & 63) * 64;
    const int hsrc = (b >> 6) * 192 + 128;
    for (int pass = 0; pass < 2; ++pass) {
      int r = (tid >> 3) + pass * 32;
      int fc = (tid & 7) * 8;
      bf16x8 vv = *(const bf16x8*)&qkvb[(size_t)(t0 + r) * 2304 + hsrc + fc];
      for (int e = 0; e < 8; ++e) tl[fc + e][r] = (unsigned short)vv[e];
    }
    __syncthreads();
    const int f = tid >> 2;
    const int sg = (tid & 3) * 16;
    for (int j = 0; j < 2; ++j) {
      bf16x8 o;
      for (int e = 0; e < 8; ++e) o[e] = (short)tl[f][sg + j * 8 + e];
      *(bf16x8*)&vt[(size_t)((b >> 6) * 64 + f) * 4096 + t0 + sg + j * 8] = o;
    }
  } else {
    const bool causal = (mask_future[0] != 0);
    int wv = ((b - 768) * 256 + tid) >> 6;  // 0..1023
    int lane = tid & 63;
    for (int row = wv * 4; row < wv * 4 + 4; ++row) {
      unsigned acc = 0;
      int jmax = causal ? (row >> 5) : 127;
      for (int j = lane; j <= jmax; j += 64) {
        unsigned wb = maskw[row * 128 + j];
        if (causal && j == jmax) {
          int rem = row & 31;
          wb &= (rem == 31) ? 0xffffffffu : ((2u << rem) - 1u);
        }
        acc |= wb;
      }
      if (!__any(acc != 0)) {
        if (lane == 0) {
          int i = atomicAdd(cnt, 1);
          if (i < 64) list[i] = row;
        }
      }
    }
  }
}

// ------------- GEMM: C[M][N] = A[M][K] * B[N][K]^T, BM=128, BN=NF*32 -------

__device__ __forceinline__ void storeC(float* p, float v) { *p = v; }
__device__ __forceinline__ void storeC(unsigned short* p, float v) { *p = f2bf(v); }

template <typename OutT, int NF>
__global__ __launch_bounds__(256) void gemm_bt(const unsigned short* __restrict__ A,
                                               const unsigned short* __restrict__ B,
                                               OutT* __restrict__ C,
                                               int M, int N, int K) {
  constexpr int BN = NF * 32;
  __shared__ unsigned short As[128 * 64];
  __shared__ unsigned short Bs[BN * 64];
  const int tid = threadIdx.x;
  const int lane = tid & 63;
  const int w = tid >> 6;
  const int wr = w >> 1, wc = w & 1;
  const int l15 = lane & 15, lhi = lane >> 4;

  int lblk = blockIdx.y * gridDim.x + blockIdx.x;
  int nwg = gridDim.x * gridDim.y;
  int sw = (lblk & 7) * (nwg >> 3) + (lblk >> 3);
  int bxg = sw % gridDim.x;
  int byg = sw / gridDim.x;

  const size_t abase = (size_t)(bxg * 128) * K;
  const size_t bbase = (size_t)(byg * BN) * K;

  f32x4 acc[4][NF] = {};

  for (int k0 = 0; k0 < K; k0 += 64) {
    __syncthreads();
    #pragma unroll
    for (int i = 0; i < 4; ++i) {
      int c = (w << 8) + (i << 6) + lane;
      int row = c >> 3, cb = c & 7;
      load_lds16(A + abase + (size_t)row * K + k0 + cb * 8, &As[c * 8]);
    }
    #pragma unroll
    for (int i = 0; i < NF; ++i) {
      int c = w * (NF * 64) + (i << 6) + lane;
      int row = c >> 3, cb = c & 7;
      load_lds16(B + bbase + (size_t)row * K + k0 + cb * 8, &Bs[c * 8]);
    }
    __syncthreads();
    #pragma unroll
    for (int kk = 0; kk < 2; ++kk) {
      bf16x8 af[4], bfr[NF];
      #pragma unroll
      for (int m = 0; m < 4; ++m)
        af[m] = *(const bf16x8*)&As[(wr * 64 + m * 16 + l15) * 64 + kk * 32 + lhi * 8];
      #pragma unroll
      for (int n = 0; n < NF; ++n)
        bfr[n] = *(const bf16x8*)&Bs[(wc * NF * 16 + n * 16 + l15) * 64 + kk * 32 + lhi * 8];
      #pragma unroll
      for (int m = 0; m < 4; ++m)
        #pragma unroll
        for (int n = 0; n < NF; ++n)
          acc[m][n] = __builtin_amdgcn_mfma_f32_16x16x32_bf16(af[m], bfr[n], acc[m][n], 0, 0, 0);
    }
  }

  #pragma unroll
  for (int m = 0; m < 4; ++m) {
    int row0 = bxg * 128 + wr * 64 + m * 16 + lhi * 4;
    #pragma unroll
    for (int n = 0; n < NF; ++n) {
      int col = byg * BN + wc * NF * 16 + n * 16 + l15;
      #pragma unroll
      for (int r = 0; r < 4; ++r)
        storeC(&C[(size_t)(row0 + r) * N + col], acc[m][n][r]);
    }
  }
}

// -------------------- attention (single-buffer LDS, natural occupancy) -----
// Global 1296-item longest-first queue (C=28 split-K). Max-free softmax:
// Q pre-scaled by CEXP, p = exp2(logit), masked -> KNEG -> 0. Single K/V
// LDS buffer (16.9KB); staging latency hidden by multi-block TLP (m114).

__global__ __launch_bounds__(256) void attn_kernel(
    const unsigned short* __restrict__ qkv,  // [4096][2304] bf16
    const unsigned short* __restrict__ vt,   // [768][4096] bf16 V^T
    const unsigned* __restrict__ maskw,      // [4096][128]
    const int* __restrict__ mask_future,
    int* __restrict__ ctr,
    float* __restrict__ parts,               // [1296][4224] f32 (O|l)
    unsigned short* __restrict__ scr) {      // scrambled [4096*768] bf16
  const int tid = threadIdx.x;
  const int lane = tid & 63;
  const int w = tid >> 6;
  const int l15 = lane & 15, lhi = lane >> 4;
  const bool causal = (mask_future[0] != 0);
  const int srcA = l15 + (((2 * lhi) & 3) << 4);
  const int srcB = l15 + (((2 * lhi + 1) & 3) << 4);
  const int hi2 = lhi >> 1;

  __shared__ unsigned short Klds[64 * 64];  // [key][d], swizzled
  __shared__ unsigned short Vs[64 * 64];    // [d][key], swizzled
  __shared__ int item_s;

  // per-lane staging geometry (item-invariant)
  int srow[2], scb[2];
  #pragma unroll
  for (int i = 0; i < 2; ++i) {
    int cc = (w << 7) + (i << 6) + lane;
    srow[i] = cc >> 3;
    scb[i] = ((cc & 7) ^ (srow[i] & 7)) * 8;
  }

  for (;;) {
    if (tid == 0) item_s = atomicAdd(ctr, 1);
    __syncthreads();  // publish item
    const int idx = item_s;
    if (idx >= 1296) break;
    int c, bx, h;
    if (idx < 444)      { c = 0; bx = 63 - idx / 12; h = idx % 12; }
    else if (idx < 552) { int j = idx - 444; c = 1; bx = 63 - j / 12; h = j % 12; }
    else if (idx < 1008) {
      int j = idx - 552; int L = 27 - j / 24; int u = j % 24;
      c = (u < 12) ? 1 : 0; bx = c ? (27 + L) : (L - 1); h = u % 12;
    } else {
      int j = idx - 1008; int L = 8 - j / 36; int u = j % 36;
      c = (u < 12) ? 2 : ((u < 24) ? 1 : 0);
      bx = (c == 2) ? (55 + L) : ((c == 1) ? (27 + L) : (L - 1)); h = u % 12;
    }

    int t0c, t1c, diag;
    bool split;
    if (causal) {
      t0c = c * 28;
      t1c = min(t0c + 28, bx + 1);
      diag = bx;
      split = (bx >= 28);
    } else {  // non-causal: c=0 items do the whole range, others skip
      if (c != 0) continue;
      t0c = 0; t1c = 64; diag = 64; split = false;
    }
    const int hoff = h * 192;
    const int l0 = bx << 6;
    const int lq = l0 + w * 16 + l15;

    // hoisted staging base pointers (advance by tile)
    const unsigned short* kb[2];
    const unsigned short* vb[2];
    #pragma unroll
    for (int i = 0; i < 2; ++i) {
      kb[i] = qkv + (size_t)(t0c * 64 + srow[i]) * 2304 + hoff + 64 + scb[i];
      vb[i] = vt + (size_t)(h * 64 + srow[i]) * 4096 + t0c * 64 + scb[i];
    }

    // Q B-fragments, pre-scaled by CEXP (logits emerge in log2 units)
    bf16x8 qf[2];
    {
      const unsigned short* qp = qkv + (size_t)lq * 2304 + hoff;
      qf[0] = *(const bf16x8*)(qp + lhi * 8);
      qf[1] = *(const bf16x8*)(qp + 32 + lhi * 8);
      #pragma unroll
      for (int i = 0; i < 2; ++i) {
        union { bf16x8 v; unsigned u[4]; } qa; qa.v = qf[i];
        #pragma unroll
        for (int p = 0; p < 4; ++p) {
          float lo = bf2f((unsigned short)(qa.u[p] & 0xffff)) * CEXP;
          float hi = bf2f((unsigned short)(qa.u[p] >> 16)) * CEXP;
          asm("v_cvt_pk_bf16_f32 %0, %1, %2" : "=v"(qa.u[p]) : "v"(lo), "v"(hi));
        }
        qf[i] = qa.v;
      }
    }
    const unsigned* mrow_p = maskw + lq * 128;
    uint2 mk_next = *(const uint2*)(mrow_p + t0c * 2);

    f32x4 oacc[4] = {};
    float lrow = 0.f;

    for (int it = t0c; it < t1c; ++it) {
      __syncthreads();  // previous tile's LDS reads done; buffer free

      // stage tile it (single buffer)
      #pragma unroll
      for (int i = 0; i < 2; ++i) {
        int cc = (w << 7) + (i << 6) + lane;
        load_lds16(kb[i], &Klds[cc * 8]);
        load_lds16(vb[i], &Vs[cc * 8]);
        kb[i] += 64 * 2304;
        vb[i] += 64;
      }
      uint2 mk = mk_next;
      if (it + 1 < t1c) mk_next = *(const uint2*)(mrow_p + (it + 1) * 2);

      __syncthreads();  // stage drained (vmcnt 0) -> LDS ready

      const int s0 = it * 64;

      // S^T (log2 units) = mfma(A=K, B=Q·CEXP); lane: S[q=lq][k=s0+n*16+lhi*4+r]
      f32x4 sacc[4] = {};
      __builtin_amdgcn_s_setprio(1);
      #pragma unroll
      for (int kk = 0; kk < 2; ++kk) {
        bf16x8 kf[4];
        #pragma unroll
        for (int n = 0; n < 4; ++n) {
          int rk = n * 16 + l15;
          int col = (kk * 32 + lhi * 8) ^ ((rk & 7) << 3);
          kf[n] = *(const bf16x8*)&Klds[rk * 64 + col];
        }
        #pragma unroll
        for (int n = 0; n < 4; ++n)
          sacc[n] = __builtin_amdgcn_mfma_f32_16x16x32_bf16(kf[n], qf[kk], sacc[n], 0, 0, 0);
      }
      __builtin_amdgcn_s_setprio(0);

      // masked logits -> p = exp2(logit); masked -> exp2(KNEG) = 0
      float vals[4][4];
      {
        unsigned a = mk.x >> (lhi * 4);
        unsigned b = mk.y >> (lhi * 4);
        if (it < diag) {
          #pragma unroll
          for (int n = 0; n < 4; ++n) {
            unsigned wsh = ((n < 2) ? a : b) >> ((n & 1) << 4);
            #pragma unroll
            for (int r = 0; r < 4; ++r)
              vals[n][r] = ((wsh >> r) & 1u) ? sacc[n][r] : KNEG;
          }
        } else {  // diagonal tile
          #pragma unroll
          for (int n = 0; n < 4; ++n) {
            unsigned wsh = ((n < 2) ? a : b) >> ((n & 1) << 4);
            int kb2 = s0 + n * 16 + lhi * 4;
            #pragma unroll
            for (int r = 0; r < 4; ++r) {
              float vv = (kb2 + r > lq) ? KNEG : sacc[n][r];
              vals[n][r] = ((wsh >> r) & 1u) ? vv : KNEG;
            }
          }
        }
      }

      float psum = 0.f;
      #pragma unroll
      for (int n = 0; n < 4; ++n)
        #pragma unroll
        for (int r = 0; r < 4; ++r) {
          float p = fexp2(vals[n][r]);
          vals[n][r] = p;
          psum += p;
        }
      psum += __shfl_xor(psum, 16);
      psum += __shfl_xor(psum, 32);
      lrow += psum;

      // pack P to bf16 pairs
      unsigned pk[4][2];
      #pragma unroll
      for (int n = 0; n < 4; ++n)
        #pragma unroll
        for (int rp = 0; rp < 2; ++rp)
          asm("v_cvt_pk_bf16_f32 %0, %1, %2"
              : "=v"(pk[n][rp])
              : "v"(vals[n][2 * rp]), "v"(vals[n][2 * rp + 1]));

      // PV
      #pragma unroll
      for (int kk = 0; kk < 2; ++kk) {
        unsigned a0 = __shfl(pk[2 * kk][0], srcA);
        unsigned a1 = __shfl(pk[2 * kk][1], srcA);
        unsigned a2 = __shfl(pk[2 * kk][0], srcB);
        unsigned a3 = __shfl(pk[2 * kk][1], srcB);
        unsigned b0 = __shfl(pk[2 * kk + 1][0], srcA);
        unsigned b1 = __shfl(pk[2 * kk + 1][1], srcA);
        unsigned b2 = __shfl(pk[2 * kk + 1][0], srcB);
        unsigned b3 = __shfl(pk[2 * kk + 1][1], srcB);
        union { bf16x8 v; unsigned u[4]; } af;
        af.u[0] = hi2 ? b0 : a0;
        af.u[1] = hi2 ? b1 : a1;
        af.u[2] = hi2 ? b2 : a2;
        af.u[3] = hi2 ? b3 : a3;
        __builtin_amdgcn_s_setprio(1);
        #pragma unroll
        for (int n = 0; n < 4; ++n) {
          int rv = n * 16 + l15;
          int col = (kk * 32 + lhi * 8) ^ ((rv & 7) << 3);
          bf16x8 vf = *(const bf16x8*)&Vs[rv * 64 + col];
          oacc[n] = __builtin_amdgcn_mfma_f32_16x16x32_bf16(af.v, vf, oacc[n], 0, 0, 0);
        }
        __builtin_amdgcn_s_setprio(0);
      }
    }

    // ---------- finalize ----------
    float lqv[4];
    #pragma unroll
    for (int r = 0; r < 4; ++r)
      lqv[r] = __shfl(lrow, (lhi << 2) + r);
    const int row0 = w * 16 + lhi * 4;

    if (split) {
      int prefix = bx + max(bx - 28, 0) + max(bx - 56, 0);
      float* pg = parts + (size_t)((prefix + c) * 12 + h) * 4224;
      #pragma unroll
      for (int n = 0; n < 4; ++n)
        #pragma unroll
        for (int r = 0; r < 4; ++r)
          pg[(size_t)(row0 + r) * 64 + n * 16 + l15] = oacc[n][r];
      if (l15 == 0) {
        #pragma unroll
        for (int r = 0; r < 4; ++r)
          pg[4096 + row0 + r] = lqv[r];
      }
    } else {
      float rq[4];
      #pragma unroll
      for (int r = 0; r < 4; ++r) rq[r] = 1.0f / lqv[r];
      #pragma unroll
      for (int n = 0; n < 4; ++n) {
        int d = n * 16 + l15;
        size_t base = (size_t)h * 262144 + (size_t)d * 4096 + (size_t)(l0 + row0);
        us4 o;
        #pragma unroll
        for (int r = 0; r < 4; ++r) o[r] = f2bf(oacc[n][r] * rq[r]);
        *(us4*)(scr + base) = o;
      }
    }
  }
}

// -------- fused: merge_k (blocks 0..431) + fixrows (blocks 432..1199) ------

__global__ __launch_bounds__(256) void merge_fix(
    const float* __restrict__ parts, const unsigned short* __restrict__ qkv,
    const unsigned short* __restrict__ vt, const unsigned* __restrict__ maskw,
    const int* __restrict__ mask_future, const int* __restrict__ cnt,
    const int* __restrict__ list, unsigned short* __restrict__ scr) {
  const int b = blockIdx.x;
  const bool causal = (mask_future[0] != 0);
  if (b < 432) {
    if (!causal) return;  // non-causal: no splits
    const int sg = b;
    const int bx = 28 + sg / 12;
    const int h = sg % 12;
    const int nch = 2 + (bx >= 56);
    const int prefix = bx + max(bx - 28, 0) + max(bx - 56, 0);
    const int t = threadIdx.x;
    const int row = t >> 2;
    const int dg = (t & 3) * 16;

    const float* pg[3];
    for (int cc = 0; cc < 3; ++cc)
      pg[cc] = parts + (size_t)((prefix + min(cc, nch - 1)) * 12 + h) * 4224;

    float L = pg[0][4096 + row] + pg[1][4096 + row];
    if (nch == 3) L += pg[2][4096 + row];
    if (L == 0.f) return;  // degenerate row: fixrows owns it (no race)
    float rL = 1.0f / L;

    #pragma unroll
    for (int dd = 0; dd < 16; ++dd) {
      int d = dg + dd;
      float o = pg[0][(size_t)row * 64 + d] + pg[1][(size_t)row * 64 + d];
      if (nch == 3) o += pg[2][(size_t)row * 64 + d];
      scr[(size_t)h * 262144 + (size_t)d * 4096 + bx * 64 + row] = f2bf(o * rL);
    }
  } else {
    const int bb = b - 432;
    const int i = bb / 12;
    const int h = bb % 12;
    int n = *cnt; if (n > 64) n = 64;
    if (i >= n) return;
    const int row = list[i];
    const int tid = threadIdx.x;
    const int lane = tid & 63;
    const int wv = tid >> 6;

    __shared__ float qs[64];
    __shared__ float ps[4096];
    __shared__ float red[16];

    if (tid < 64) qs[tid] = bf2f(qkv[(size_t)row * 2304 + h * 192 + tid]);
    __syncthreads();

    float pv[16];
    float mymax = -INFINITY;
    #pragma unroll
    for (int kk = 0; kk < 16; ++kk) {
      int key = tid * 16 + kk;
      const unsigned short* kp = qkv + (size_t)key * 2304 + h * 192 + 64;
      float s = 0.f;
      #pragma unroll
      for (int d8 = 0; d8 < 8; ++d8) {
        bf16x8 kv8 = *(const bf16x8*)(kp + d8 * 8);
        #pragma unroll
        for (int e = 0; e < 8; ++e)
          s += qs[d8 * 8 + e] * bf2f((unsigned short)kv8[e]);
      }
      s *= 0.125f;
      unsigned bit = (maskw[row * 128 + (key >> 5)] >> (key & 31)) & 1u;
      float val = bit ? ((causal && key > row) ? s - 10000.f : s) : -10000.f;
      pv[kk] = val;
      mymax = fmaxf(mymax, val);
    }
    for (int xx = 1; xx < 64; xx <<= 1) mymax = fmaxf(mymax, __shfl_xor(mymax, xx));
    if (lane == 0) red[wv] = mymax;
    __syncthreads();
    const float M = fmaxf(fmaxf(red[0], red[1]), fmaxf(red[2], red[3]));

    float sum = 0.f;
    #pragma unroll
    for (int kk = 0; kk < 16; ++kk) {
      float p = fexp2((pv[kk] - M) * L2E);
      ps[tid * 16 + kk] = p;
      sum += p;
    }
    for (int xx = 1; xx < 64; xx <<= 1) sum += __shfl_xor(sum, xx);
    if (lane == 0) red[8 + wv] = sum;
    __syncthreads();
    const float L = red[8] + red[9] + red[10] + red[11];

    const int d = tid >> 2, qq = tid & 3;
    float acc = 0.f;
    for (int jb = qq * 1024; jb < qq * 1024 + 1024; jb += 8) {
      bf16x8 vv8 = *(const bf16x8*)&vt[(size_t)(h * 64 + d) * 4096 + jb];
      #pragma unroll
      for (int e = 0; e < 8; ++e)
        acc += ps[jb + e] * bf2f((unsigned short)vv8[e]);
    }
    acc += __shfl_xor(acc, 1);
    acc += __shfl_xor(acc, 2);
    if (qq == 0)
      scr[(size_t)h * 262144 + (size_t)d * 4096 + row] = f2bf(acc / L);
  }
}

// -------------------- launch --------------------

extern "C" void kernel_launch(void* const* d_in, const int* in_sizes, int n_in,
                              void* d_out, int out_size, void* d_ws, size_t ws_size,
                              hipStream_t stream) {
  const float* q = (const float*)d_in[0];
  const float* k = (const float*)d_in[1];
  const float* v = (const float*)d_in[2];
  const int* attn_mask = (const int*)d_in[3];
  const int* mask_future = (const int*)d_in[4];
  const float* W_qkv = (const float*)d_in[5];
  const float* W_out = (const float*)d_in[6];
  float* out = (float*)d_out;

  char* ws = (char*)d_ws;
  unsigned short* xb    = (unsigned short*)(ws);            // [0,18.87M) live until qkv GEMM
  unsigned short* vt    = (unsigned short*)(ws);            // [0,6.29M) after tv_rowflag
  char*           ctl   = ws + 6291456;                     // 4KB, memset AFTER gemm
  int*            ctr   = (int*)(ctl);
  int*            cnt   = (int*)(ctl + 256);
  int*            list  = (int*)(ctl + 1024);               // [64]
  float*          parts = (float*)(ws + 6295552);           // 1296*4224*4 = 21.90MB
  unsigned short* wqkvb = (unsigned short*)(ws + 18874368); // dead after qkv GEMM
  unsigned short* qkvb  = (unsigned short*)(ws + 29491200);
  unsigned*       maskw = (unsigned*)(ws + 48365568);
  unsigned short* scr   = (unsigned short*)(ws + 50462720);
  unsigned short* woutb = (unsigned short*)(ws + 56754176);
  if (ws_size < 57933824) return;

  pack_all<<<9536, 256, 0, stream>>>(q, k, v, W_qkv, W_out, attn_mask,
                                     xb, wqkvb, woutb, maskw);
  gemm_bt<unsigned short, 3><<<dim3(32, 24), 256, 0, stream>>>(xb, wqkvb, qkvb, 4096, 2304, 2304);
  hipMemsetAsync(ctl, 0, 4096, stream);   // AFTER gemm: xb dead (R6 lesson)
  tv_rowflag<<<1024, 256, 0, stream>>>(qkvb, vt, maskw, mask_future, cnt, list);
  attn_kernel<<<2048, 256, 0, stream>>>(qkvb, vt, maskw, mask_future, ctr, parts, scr);
  merge_fix<<<1200, 256, 0, stream>>>(parts, qkvb, vt, maskw, mask_future, cnt, list, scr);
  gemm_bt<float, 3><<<dim3(32, 8), 256, 0, stream>>>(scr, woutb, out, 4096, 768, 768);
}

// Round 14
// 203.627 us; speedup vs baseline: 1.6032x; 1.0685x over previous
//
#include <hip/hip_runtime.h>

// ---------------------------------------------------------------------------
// FastMultiHeadAttention on MI355X (gfx950)
// Round 14: consolidation. attn = R11 double-buffered 1-barrier/tile body
// (80.5us measured; R10 XCD-queues, R12 launch-bounds spill, R13 single-
// buffer all regressed). Keep R12/R13-proven fusions: pack_all (4 packs in
// one dispatch), tv_rowflag (transposeV + degenerate-row scan), merge_fix
// (split-K merge + exact degenerate-row recompute; merge skips L==0 rows so
// no write race). Global longest-first C=28 split-K queue, max-free exp2
// softmax (Q pre-scaled by CEXP), ctl memset after QKV GEMM (R6 lesson).
// ---------------------------------------------------------------------------

typedef __attribute__((ext_vector_type(8))) short bf16x8;
typedef __attribute__((ext_vector_type(4))) float f32x4;
typedef __attribute__((ext_vector_type(4))) unsigned short us4;

#define KNEG -15000.0f              // masked logit in log2 units; exp2 -> 0
#define CEXP 0.18033688011112042f   // 0.125 * log2(e)
#define L2E  1.4426950408889634f

__device__ __forceinline__ unsigned short f2bf(float f) {
  union { float f; unsigned u; } x; x.f = f;
  unsigned r = x.u + 0x7fffu + ((x.u >> 16) & 1u);
  return (unsigned short)(r >> 16);
}

__device__ __forceinline__ float bf2f(unsigned short u) {
  union { unsigned u; float f; } x; x.u = (unsigned)u << 16;
  return x.f;
}

__device__ __forceinline__ float fexp2(float x) {
  return __builtin_amdgcn_exp2f(x);
}

__device__ __forceinline__ void load_lds16(const void* g, void* l) {
  __builtin_amdgcn_global_load_lds(
      (const __attribute__((address_space(1))) void*)g,
      (__attribute__((address_space(3))) void*)l, 16, 0, 0);
}

// -------------------- fused pack kernel --------------------

__device__ __forceinline__ void pack8(const float* __restrict__ src,
                                      unsigned short* __restrict__ dst) {
  const float4* p = (const float4*)src;
  float4 a = p[0], b = p[1];
  bf16x8 o;
  o[0] = (short)f2bf(a.x); o[1] = (short)f2bf(a.y);
  o[2] = (short)f2bf(a.z); o[3] = (short)f2bf(a.w);
  o[4] = (short)f2bf(b.x); o[5] = (short)f2bf(b.y);
  o[6] = (short)f2bf(b.z); o[7] = (short)f2bf(b.w);
  *(bf16x8*)dst = o;
}

__global__ __launch_bounds__(256) void pack_all(
    const float* __restrict__ q, const float* __restrict__ k,
    const float* __restrict__ v, const float* __restrict__ W_qkv,
    const float* __restrict__ W_out, const int* __restrict__ mask,
    unsigned short* __restrict__ xb, unsigned short* __restrict__ wqkvb,
    unsigned short* __restrict__ woutb, unsigned* __restrict__ maskw) {
  const int b = blockIdx.x;
  const int tid = threadIdx.x;
  if (b < 4608) {
    int idx = b * 256 + tid;
    int t = idx / 288;
    int c2 = (idx - t * 288) * 8;
    const float* src;
    int c;
    if (c2 < 768)       { src = q; c = c2; }
    else if (c2 < 1536) { src = k; c = c2 - 768; }
    else                { src = v; c = c2 - 1536; }
    pack8(src + (size_t)t * 768 + c, xb + (size_t)t * 2304 + c2);
  } else if (b < 7200) {
    int idx = (b - 4608) * 256 + tid;
    pack8(W_qkv + (size_t)idx * 8, wqkvb + (size_t)idx * 8);
  } else if (b < 7488) {
    int idx = (b - 7200) * 256 + tid;
    pack8(W_out + (size_t)idx * 8, woutb + (size_t)idx * 8);
  } else {
    int lane = tid & 63;
    int wid0 = ((b - 7488) * 256 + tid) >> 6;
    for (int wid = wid0; wid < 262144; wid += 8192) {
      int row = wid >> 6;
      int wp = wid & 63;
      int s = wp * 64 + lane;
      int mval = mask[(size_t)row * 4096 + s];
      unsigned long long bb = __ballot(mval != 0);
      if (lane == 0) {
        maskw[row * 128 + wp * 2]     = (unsigned)bb;
        maskw[row * 128 + wp * 2 + 1] = (unsigned)(bb >> 32);
      }
    }
  }
}

// -------- fused: transposeV (blocks 0..767) + rowflag (blocks 768..1023) ---

__global__ __launch_bounds__(256) void tv_rowflag(
    const unsigned short* __restrict__ qkvb, unsigned short* __restrict__ vt,
    const unsigned* __restrict__ maskw, const int* __restrict__ mask_future,
    int* __restrict__ cnt, int* __restrict__ list) {
  const int b = blockIdx.x;
  const int tid = threadIdx.x;
  if (b < 768) {
    __shared__ unsigned short tl[64][65];
    const int t0 = (b & 63) * 64;
    const int hsrc = (b >> 6) * 192 + 128;
    for (int pass = 0; pass < 2; ++pass) {
      int r = (tid >> 3) + pass * 32;
      int fc = (tid & 7) * 8;
      bf16x8 vv = *(const bf16x8*)&qkvb[(size_t)(t0 + r) * 2304 + hsrc + fc];
      for (int e = 0; e < 8; ++e) tl[fc + e][r] = (unsigned short)vv[e];
    }
    __syncthreads();
    const int f = tid >> 2;
    const int sg = (tid & 3) * 16;
    for (int j = 0; j < 2; ++j) {
      bf16x8 o;
      for (int e = 0; e < 8; ++e) o[e] = (short)tl[f][sg + j * 8 + e];
      *(bf16x8*)&vt[(size_t)((b >> 6) * 64 + f) * 4096 + t0 + sg + j * 8] = o;
    }
  } else {
    const bool causal = (mask_future[0] != 0);
    int wv = ((b - 768) * 256 + tid) >> 6;  // 0..1023
    int lane = tid & 63;
    for (int row = wv * 4; row < wv * 4 + 4; ++row) {
      unsigned acc = 0;
      int jmax = causal ? (row >> 5) : 127;
      for (int j = lane; j <= jmax; j += 64) {
        unsigned wb = maskw[row * 128 + j];
        if (causal && j == jmax) {
          int rem = row & 31;
          wb &= (rem == 31) ? 0xffffffffu : ((2u << rem) - 1u);
        }
        acc |= wb;
      }
      if (!__any(acc != 0)) {
        if (lane == 0) {
          int i = atomicAdd(cnt, 1);
          if (i < 64) list[i] = row;
        }
      }
    }
  }
}

// ------------- GEMM: C[M][N] = A[M][K] * B[N][K]^T, BM=128, BN=NF*32 -------

__device__ __forceinline__ void storeC(float* p, float v) { *p = v; }
__device__ __forceinline__ void storeC(unsigned short* p, float v) { *p = f2bf(v); }

template <typename OutT, int NF>
__global__ __launch_bounds__(256) void gemm_bt(const unsigned short* __restrict__ A,
                                               const unsigned short* __restrict__ B,
                                               OutT* __restrict__ C,
                                               int M, int N, int K) {
  constexpr int BN = NF * 32;
  __shared__ unsigned short As[128 * 64];
  __shared__ unsigned short Bs[BN * 64];
  const int tid = threadIdx.x;
  const int lane = tid & 63;
  const int w = tid >> 6;
  const int wr = w >> 1, wc = w & 1;
  const int l15 = lane & 15, lhi = lane >> 4;

  int lblk = blockIdx.y * gridDim.x + blockIdx.x;
  int nwg = gridDim.x * gridDim.y;
  int sw = (lblk & 7) * (nwg >> 3) + (lblk >> 3);
  int bxg = sw % gridDim.x;
  int byg = sw / gridDim.x;

  const size_t abase = (size_t)(bxg * 128) * K;
  const size_t bbase = (size_t)(byg * BN) * K;

  f32x4 acc[4][NF] = {};

  for (int k0 = 0; k0 < K; k0 += 64) {
    __syncthreads();
    #pragma unroll
    for (int i = 0; i < 4; ++i) {
      int c = (w << 8) + (i << 6) + lane;
      int row = c >> 3, cb = c & 7;
      load_lds16(A + abase + (size_t)row * K + k0 + cb * 8, &As[c * 8]);
    }
    #pragma unroll
    for (int i = 0; i < NF; ++i) {
      int c = w * (NF * 64) + (i << 6) + lane;
      int row = c >> 3, cb = c & 7;
      load_lds16(B + bbase + (size_t)row * K + k0 + cb * 8, &Bs[c * 8]);
    }
    __syncthreads();
    #pragma unroll
    for (int kk = 0; kk < 2; ++kk) {
      bf16x8 af[4], bfr[NF];
      #pragma unroll
      for (int m = 0; m < 4; ++m)
        af[m] = *(const bf16x8*)&As[(wr * 64 + m * 16 + l15) * 64 + kk * 32 + lhi * 8];
      #pragma unroll
      for (int n = 0; n < NF; ++n)
        bfr[n] = *(const bf16x8*)&Bs[(wc * NF * 16 + n * 16 + l15) * 64 + kk * 32 + lhi * 8];
      #pragma unroll
      for (int m = 0; m < 4; ++m)
        #pragma unroll
        for (int n = 0; n < NF; ++n)
          acc[m][n] = __builtin_amdgcn_mfma_f32_16x16x32_bf16(af[m], bfr[n], acc[m][n], 0, 0, 0);
    }
  }

  #pragma unroll
  for (int m = 0; m < 4; ++m) {
    int row0 = bxg * 128 + wr * 64 + m * 16 + lhi * 4;
    #pragma unroll
    for (int n = 0; n < NF; ++n) {
      int col = byg * BN + wc * NF * 16 + n * 16 + l15;
      #pragma unroll
      for (int r = 0; r < 4; ++r)
        storeC(&C[(size_t)(row0 + r) * N + col], acc[m][n][r]);
    }
  }
}

// -------------------- attention (R11 body: dbuf LDS, 1 barrier/tile) -------
// Global 1296-item longest-first queue (C=28 split-K). Max-free softmax:
// Q pre-scaled by CEXP, p = exp2(logit), masked -> KNEG -> 0. Double-
// buffered K/V LDS; stage(it+1) issued right after the single per-tile
// barrier, overlapping compute(it).

__global__ __launch_bounds__(256) void attn_kernel(
    const unsigned short* __restrict__ qkv,  // [4096][2304] bf16
    const unsigned short* __restrict__ vt,   // [768][4096] bf16 V^T
    const unsigned* __restrict__ maskw,      // [4096][128]
    const int* __restrict__ mask_future,
    int* __restrict__ ctr,
    float* __restrict__ parts,               // [1296][4224] f32 (O|l)
    unsigned short* __restrict__ scr) {      // scrambled [4096*768] bf16
  const int tid = threadIdx.x;
  const int lane = tid & 63;
  const int w = tid >> 6;
  const int l15 = lane & 15, lhi = lane >> 4;
  const bool causal = (mask_future[0] != 0);
  const int srcA = l15 + (((2 * lhi) & 3) << 4);
  const int srcB = l15 + (((2 * lhi + 1) & 3) << 4);
  const int hi2 = lhi >> 1;

  __shared__ unsigned short Klds[2][64 * 64];  // [key][d], swizzled
  __shared__ unsigned short Vs[2][64 * 64];    // [d][key], swizzled
  __shared__ int item_s;

  // per-lane staging geometry (item-invariant)
  int srow[2], scb[2];
  #pragma unroll
  for (int i = 0; i < 2; ++i) {
    int cc = (w << 7) + (i << 6) + lane;
    srow[i] = cc >> 3;
    scb[i] = ((cc & 7) ^ (srow[i] & 7)) * 8;
  }

  for (;;) {
    if (tid == 0) item_s = atomicAdd(ctr, 1);
    __syncthreads();  // publish item; drains previous item's in-flight stages
    const int idx = item_s;
    if (idx >= 1296) break;
    int c, bx, h;
    if (idx < 444)      { c = 0; bx = 63 - idx / 12; h = idx % 12; }
    else if (idx < 552) { int j = idx - 444; c = 1; bx = 63 - j / 12; h = j % 12; }
    else if (idx < 1008) {
      int j = idx - 552; int L = 27 - j / 24; int u = j % 24;
      c = (u < 12) ? 1 : 0; bx = c ? (27 + L) : (L - 1); h = u % 12;
    } else {
      int j = idx - 1008; int L = 8 - j / 36; int u = j % 36;
      c = (u < 12) ? 2 : ((u < 24) ? 1 : 0);
      bx = (c == 2) ? (55 + L) : ((c == 1) ? (27 + L) : (L - 1)); h = u % 12;
    }

    int t0c, t1c, diag;
    bool split;
    if (causal) {
      t0c = c * 28;
      t1c = min(t0c + 28, bx + 1);
      diag = bx;
      split = (bx >= 28);
    } else {  // non-causal: c=0 items do the whole range, others skip
      if (c != 0) continue;
      t0c = 0; t1c = 64; diag = 64; split = false;
    }
    const int hoff = h * 192;
    const int l0 = bx << 6;
    const int lq = l0 + w * 16 + l15;

    // hoisted staging base pointers (advance by tile)
    const unsigned short* kb[2];
    const unsigned short* vb[2];
    #pragma unroll
    for (int i = 0; i < 2; ++i) {
      kb[i] = qkv + (size_t)(t0c * 64 + srow[i]) * 2304 + hoff + 64 + scb[i];
      vb[i] = vt + (size_t)(h * 64 + srow[i]) * 4096 + t0c * 64 + scb[i];
    }

    // Q B-fragments, pre-scaled by CEXP (logits emerge in log2 units)
    bf16x8 qf[2];
    {
      const unsigned short* qp = qkv + (size_t)lq * 2304 + hoff;
      qf[0] = *(const bf16x8*)(qp + lhi * 8);
      qf[1] = *(const bf16x8*)(qp + 32 + lhi * 8);
      #pragma unroll
      for (int i = 0; i < 2; ++i) {
        union { bf16x8 v; unsigned u[4]; } qa; qa.v = qf[i];
        #pragma unroll
        for (int p = 0; p < 4; ++p) {
          float lo = bf2f((unsigned short)(qa.u[p] & 0xffff)) * CEXP;
          float hi = bf2f((unsigned short)(qa.u[p] >> 16)) * CEXP;
          asm("v_cvt_pk_bf16_f32 %0, %1, %2" : "=v"(qa.u[p]) : "v"(lo), "v"(hi));
        }
        qf[i] = qa.v;
      }
    }
    // prologue: stage tile t0c -> buf 0
    #pragma unroll
    for (int i = 0; i < 2; ++i) {
      int cc = (w << 7) + (i << 6) + lane;
      load_lds16(kb[i], &Klds[0][cc * 8]);
      load_lds16(vb[i], &Vs[0][cc * 8]);
    }
    const unsigned* mrow_p = maskw + lq * 128;
    uint2 mk_next = *(const uint2*)(mrow_p + t0c * 2);

    f32x4 oacc[4] = {};
    float lrow = 0.f;
    int cur = 0;

    for (int it = t0c; it < t1c; ++it) {
      __syncthreads();  // drains stage(it); protects buf reuse

      if (it + 1 < t1c) {
        #pragma unroll
        for (int i = 0; i < 2; ++i) {
          kb[i] += 64 * 2304;
          vb[i] += 64;
          int cc = (w << 7) + (i << 6) + lane;
          load_lds16(kb[i], &Klds[cur ^ 1][cc * 8]);
          load_lds16(vb[i], &Vs[cur ^ 1][cc * 8]);
        }
      }
      uint2 mk = mk_next;
      if (it + 1 < t1c) mk_next = *(const uint2*)(mrow_p + (it + 1) * 2);

      const int s0 = it * 64;

      // S^T (log2 units) = mfma(A=K, B=Q·CEXP); lane: S[q=lq][k=s0+n*16+lhi*4+r]
      f32x4 sacc[4] = {};
      __builtin_amdgcn_s_setprio(1);
      #pragma unroll
      for (int kk = 0; kk < 2; ++kk) {
        bf16x8 kf[4];
        #pragma unroll
        for (int n = 0; n < 4; ++n) {
          int rk = n * 16 + l15;
          int col = (kk * 32 + lhi * 8) ^ ((rk & 7) << 3);
          kf[n] = *(const bf16x8*)&Klds[cur][rk * 64 + col];
        }
        #pragma unroll
        for (int n = 0; n < 4; ++n)
          sacc[n] = __builtin_amdgcn_mfma_f32_16x16x32_bf16(kf[n], qf[kk], sacc[n], 0, 0, 0);
      }
      __builtin_amdgcn_s_setprio(0);

      // masked logits -> p = exp2(logit); masked -> exp2(KNEG) = 0
      float vals[4][4];
      {
        unsigned a = mk.x >> (lhi * 4);
        unsigned b = mk.y >> (lhi * 4);
        if (it < diag) {
          #pragma unroll
          for (int n = 0; n < 4; ++n) {
            unsigned wsh = ((n < 2) ? a : b) >> ((n & 1) << 4);
            #pragma unroll
            for (int r = 0; r < 4; ++r)
              vals[n][r] = ((wsh >> r) & 1u) ? sacc[n][r] : KNEG;
          }
        } else {  // diagonal tile
          #pragma unroll
          for (int n = 0; n < 4; ++n) {
            unsigned wsh = ((n < 2) ? a : b) >> ((n & 1) << 4);
            int kb2 = s0 + n * 16 + lhi * 4;
            #pragma unroll
            for (int r = 0; r < 4; ++r) {
              float vv = (kb2 + r > lq) ? KNEG : sacc[n][r];
              vals[n][r] = ((wsh >> r) & 1u) ? vv : KNEG;
            }
          }
        }
      }

      float psum = 0.f;
      #pragma unroll
      for (int n = 0; n < 4; ++n)
        #pragma unroll
        for (int r = 0; r < 4; ++r) {
          float p = fexp2(vals[n][r]);
          vals[n][r] = p;
          psum += p;
        }
      psum += __shfl_xor(psum, 16);
      psum += __shfl_xor(psum, 32);
      lrow += psum;

      // pack P to bf16 pairs
      unsigned pk[4][2];
      #pragma unroll
      for (int n = 0; n < 4; ++n)
        #pragma unroll
        for (int rp = 0; rp < 2; ++rp)
          asm("v_cvt_pk_bf16_f32 %0, %1, %2"
              : "=v"(pk[n][rp])
              : "v"(vals[n][2 * rp]), "v"(vals[n][2 * rp + 1]));

      // PV
      #pragma unroll
      for (int kk = 0; kk < 2; ++kk) {
        unsigned a0 = __shfl(pk[2 * kk][0], srcA);
        unsigned a1 = __shfl(pk[2 * kk][1], srcA);
        unsigned a2 = __shfl(pk[2 * kk][0], srcB);
        unsigned a3 = __shfl(pk[2 * kk][1], srcB);
        unsigned b0 = __shfl(pk[2 * kk + 1][0], srcA);
        unsigned b1 = __shfl(pk[2 * kk + 1][1], srcA);
        unsigned b2 = __shfl(pk[2 * kk + 1][0], srcB);
        unsigned b3 = __shfl(pk[2 * kk + 1][1], srcB);
        union { bf16x8 v; unsigned u[4]; } af;
        af.u[0] = hi2 ? b0 : a0;
        af.u[1] = hi2 ? b1 : a1;
        af.u[2] = hi2 ? b2 : a2;
        af.u[3] = hi2 ? b3 : a3;
        __builtin_amdgcn_s_setprio(1);
        #pragma unroll
        for (int n = 0; n < 4; ++n) {
          int rv = n * 16 + l15;
          int col = (kk * 32 + lhi * 8) ^ ((rv & 7) << 3);
          bf16x8 vf = *(const bf16x8*)&Vs[cur][rv * 64 + col];
          oacc[n] = __builtin_amdgcn_mfma_f32_16x16x32_bf16(af.v, vf, oacc[n], 0, 0, 0);
        }
        __builtin_amdgcn_s_setprio(0);
      }
      cur ^= 1;
    }

    // ---------- finalize ----------
    float lqv[4];
    #pragma unroll
    for (int r = 0; r < 4; ++r)
      lqv[r] = __shfl(lrow, (lhi << 2) + r);
    const int row0 = w * 16 + lhi * 4;

    if (split) {
      int prefix = bx + max(bx - 28, 0) + max(bx - 56, 0);
      float* pg = parts + (size_t)((prefix + c) * 12 + h) * 4224;
      #pragma unroll
      for (int n = 0; n < 4; ++n)
        #pragma unroll
        for (int r = 0; r < 4; ++r)
          pg[(size_t)(row0 + r) * 64 + n * 16 + l15] = oacc[n][r];
      if (l15 == 0) {
        #pragma unroll
        for (int r = 0; r < 4; ++r)
          pg[4096 + row0 + r] = lqv[r];
      }
    } else {
      float rq[4];
      #pragma unroll
      for (int r = 0; r < 4; ++r) rq[r] = 1.0f / lqv[r];
      #pragma unroll
      for (int n = 0; n < 4; ++n) {
        int d = n * 16 + l15;
        size_t base = (size_t)h * 262144 + (size_t)d * 4096 + (size_t)(l0 + row0);
        us4 o;
        #pragma unroll
        for (int r = 0; r < 4; ++r) o[r] = f2bf(oacc[n][r] * rq[r]);
        *(us4*)(scr + base) = o;
      }
    }
  }
}

// -------- fused: merge_k (blocks 0..431) + fixrows (blocks 432..1199) ------

__global__ __launch_bounds__(256) void merge_fix(
    const float* __restrict__ parts, const unsigned short* __restrict__ qkv,
    const unsigned short* __restrict__ vt, const unsigned* __restrict__ maskw,
    const int* __restrict__ mask_future, const int* __restrict__ cnt,
    const int* __restrict__ list, unsigned short* __restrict__ scr) {
  const int b = blockIdx.x;
  const bool causal = (mask_future[0] != 0);
  if (b < 432) {
    if (!causal) return;  // non-causal: no splits
    const int sg = b;
    const int bx = 28 + sg / 12;
    const int h = sg % 12;
    const int nch = 2 + (bx >= 56);
    const int prefix = bx + max(bx - 28, 0) + max(bx - 56, 0);
    const int t = threadIdx.x;
    const int row = t >> 2;
    const int dg = (t & 3) * 16;

    const float* pg[3];
    for (int cc = 0; cc < 3; ++cc)
      pg[cc] = parts + (size_t)((prefix + min(cc, nch - 1)) * 12 + h) * 4224;

    float L = pg[0][4096 + row] + pg[1][4096 + row];
    if (nch == 3) L += pg[2][4096 + row];
    if (L == 0.f) return;  // degenerate row: fixrows owns it (no race)
    float rL = 1.0f / L;

    #pragma unroll
    for (int dd = 0; dd < 16; ++dd) {
      int d = dg + dd;
      float o = pg[0][(size_t)row * 64 + d] + pg[1][(size_t)row * 64 + d];
      if (nch == 3) o += pg[2][(size_t)row * 64 + d];
      scr[(size_t)h * 262144 + (size_t)d * 4096 + bx * 64 + row] = f2bf(o * rL);
    }
  } else {
    const int bb = b - 432;
    const int i = bb / 12;
    const int h = bb % 12;
    int n = *cnt; if (n > 64) n = 64;
    if (i >= n) return;
    const int row = list[i];
    const int tid = threadIdx.x;
    const int lane = tid & 63;
    const int wv = tid >> 6;

    __shared__ float qs[64];
    __shared__ float ps[4096];
    __shared__ float red[16];

    if (tid < 64) qs[tid] = bf2f(qkv[(size_t)row * 2304 + h * 192 + tid]);
    __syncthreads();

    float pv[16];
    float mymax = -INFINITY;
    #pragma unroll
    for (int kk = 0; kk < 16; ++kk) {
      int key = tid * 16 + kk;
      const unsigned short* kp = qkv + (size_t)key * 2304 + h * 192 + 64;
      float s = 0.f;
      #pragma unroll
      for (int d8 = 0; d8 < 8; ++d8) {
        bf16x8 kv8 = *(const bf16x8*)(kp + d8 * 8);
        #pragma unroll
        for (int e = 0; e < 8; ++e)
          s += qs[d8 * 8 + e] * bf2f((unsigned short)kv8[e]);
      }
      s *= 0.125f;
      unsigned bit = (maskw[row * 128 + (key >> 5)] >> (key & 31)) & 1u;
      float val = bit ? ((causal && key > row) ? s - 10000.f : s) : -10000.f;
      pv[kk] = val;
      mymax = fmaxf(mymax, val);
    }
    for (int xx = 1; xx < 64; xx <<= 1) mymax = fmaxf(mymax, __shfl_xor(mymax, xx));
    if (lane == 0) red[wv] = mymax;
    __syncthreads();
    const float M = fmaxf(fmaxf(red[0], red[1]), fmaxf(red[2], red[3]));

    float sum = 0.f;
    #pragma unroll
    for (int kk = 0; kk < 16; ++kk) {
      float p = fexp2((pv[kk] - M) * L2E);
      ps[tid * 16 + kk] = p;
      sum += p;
    }
    for (int xx = 1; xx < 64; xx <<= 1) sum += __shfl_xor(sum, xx);
    if (lane == 0) red[8 + wv] = sum;
    __syncthreads();
    const float L = red[8] + red[9] + red[10] + red[11];

    const int d = tid >> 2, qq = tid & 3;
    float acc = 0.f;
    for (int jb = qq * 1024; jb < qq * 1024 + 1024; jb += 8) {
      bf16x8 vv8 = *(const bf16x8*)&vt[(size_t)(h * 64 + d) * 4096 + jb];
      #pragma unroll
      for (int e = 0; e < 8; ++e)
        acc += ps[jb + e] * bf2f((unsigned short)vv8[e]);
    }
    acc += __shfl_xor(acc, 1);
    acc += __shfl_xor(acc, 2);
    if (qq == 0)
      scr[(size_t)h * 262144 + (size_t)d * 4096 + row] = f2bf(acc / L);
  }
}

// -------------------- launch --------------------

extern "C" void kernel_launch(void* const* d_in, const int* in_sizes, int n_in,
                              void* d_out, int out_size, void* d_ws, size_t ws_size,
                              hipStream_t stream) {
  const float* q = (const float*)d_in[0];
  const float* k = (const float*)d_in[1];
  const float* v = (const float*)d_in[2];
  const int* attn_mask = (const int*)d_in[3];
  const int* mask_future = (const int*)d_in[4];
  const float* W_qkv = (const float*)d_in[5];
  const float* W_out = (const float*)d_in[6];
  float* out = (float*)d_out;

  char* ws = (char*)d_ws;
  unsigned short* xb    = (unsigned short*)(ws);            // [0,18.87M) live until qkv GEMM
  unsigned short* vt    = (unsigned short*)(ws);            // [0,6.29M) after tv_rowflag
  char*           ctl   = ws + 6291456;                     // 4KB, memset AFTER gemm
  int*            ctr   = (int*)(ctl);
  int*            cnt   = (int*)(ctl + 256);
  int*            list  = (int*)(ctl + 1024);               // [64]
  float*          parts = (float*)(ws + 6295552);           // 1296*4224*4 = 21.90MB
  unsigned short* wqkvb = (unsigned short*)(ws + 18874368); // dead after qkv GEMM
  unsigned short* qkvb  = (unsigned short*)(ws + 29491200);
  unsigned*       maskw = (unsigned*)(ws + 48365568);
  unsigned short* scr   = (unsigned short*)(ws + 50462720);
  unsigned short* woutb = (unsigned short*)(ws + 56754176);
  if (ws_size < 57933824) return;

  pack_all<<<9536, 256, 0, stream>>>(q, k, v, W_qkv, W_out, attn_mask,
                                     xb, wqkvb, woutb, maskw);
  gemm_bt<unsigned short, 3><<<dim3(32, 24), 256, 0, stream>>>(xb, wqkvb, qkvb, 4096, 2304, 2304);
  hipMemsetAsync(ctl, 0, 4096, stream);   // AFTER gemm: xb dead (R6 lesson)
  tv_rowflag<<<1024, 256, 0, stream>>>(qkvb, vt, maskw, mask_future, cnt, list);
  attn_kernel<<<1024, 256, 0, stream>>>(qkvb, vt, maskw, mask_future, ctr, parts, scr);
  merge_fix<<<1200, 256, 0, stream>>>(parts, qkvb, vt, maskw, mask_future, cnt, list, scr);
  gemm_bt<float, 3><<<dim3(32, 8), 256, 0, stream>>>(scr, woutb, out, 4096, 768, 768);
}

// Round 15
// 203.015 us; speedup vs baseline: 1.6080x; 1.0030x over previous
//
#include <hip/hip_runtime.h>

// ---------------------------------------------------------------------------
// FastMultiHeadAttention on MI355X (gfx950)
// Round 15: R14 + softmax denominator via MFMA ones-trick. The PV
// A-fragments (P in registers) are multiplied by a constant all-ones B
// fragment: osum = mfma(af, ones, osum) gives per-row sums on the MFMA pipe
// (13% utilized) and in the exact (lhi,r) lane layout finalize needs --
// deleting the 15-add+2-shuffle psum tree and the finalize broadcasts.
// Denominator now sums the same bf16-rounded p values the numerator uses
// (unbiased rounding; degenerate rows still sum to exactly 0 -> fixrows).
// Everything else identical to R14 (203.6us, best known).
// ---------------------------------------------------------------------------

typedef __attribute__((ext_vector_type(8))) short bf16x8;
typedef __attribute__((ext_vector_type(4))) float f32x4;
typedef __attribute__((ext_vector_type(4))) unsigned short us4;

#define KNEG -15000.0f              // masked logit in log2 units; exp2 -> 0
#define CEXP 0.18033688011112042f   // 0.125 * log2(e)
#define L2E  1.4426950408889634f

__device__ __forceinline__ unsigned short f2bf(float f) {
  union { float f; unsigned u; } x; x.f = f;
  unsigned r = x.u + 0x7fffu + ((x.u >> 16) & 1u);
  return (unsigned short)(r >> 16);
}

__device__ __forceinline__ float bf2f(unsigned short u) {
  union { unsigned u; float f; } x; x.u = (unsigned)u << 16;
  return x.f;
}

__device__ __forceinline__ float fexp2(float x) {
  return __builtin_amdgcn_exp2f(x);
}

__device__ __forceinline__ void load_lds16(const void* g, void* l) {
  __builtin_amdgcn_global_load_lds(
      (const __attribute__((address_space(1))) void*)g,
      (__attribute__((address_space(3))) void*)l, 16, 0, 0);
}

// -------------------- fused pack kernel --------------------

__device__ __forceinline__ void pack8(const float* __restrict__ src,
                                      unsigned short* __restrict__ dst) {
  const float4* p = (const float4*)src;
  float4 a = p[0], b = p[1];
  bf16x8 o;
  o[0] = (short)f2bf(a.x); o[1] = (short)f2bf(a.y);
  o[2] = (short)f2bf(a.z); o[3] = (short)f2bf(a.w);
  o[4] = (short)f2bf(b.x); o[5] = (short)f2bf(b.y);
  o[6] = (short)f2bf(b.z); o[7] = (short)f2bf(b.w);
  *(bf16x8*)dst = o;
}

__global__ __launch_bounds__(256) void pack_all(
    const float* __restrict__ q, const float* __restrict__ k,
    const float* __restrict__ v, const float* __restrict__ W_qkv,
    const float* __restrict__ W_out, const int* __restrict__ mask,
    unsigned short* __restrict__ xb, unsigned short* __restrict__ wqkvb,
    unsigned short* __restrict__ woutb, unsigned* __restrict__ maskw) {
  const int b = blockIdx.x;
  const int tid = threadIdx.x;
  if (b < 4608) {
    int idx = b * 256 + tid;
    int t = idx / 288;
    int c2 = (idx - t * 288) * 8;
    const float* src;
    int c;
    if (c2 < 768)       { src = q; c = c2; }
    else if (c2 < 1536) { src = k; c = c2 - 768; }
    else                { src = v; c = c2 - 1536; }
    pack8(src + (size_t)t * 768 + c, xb + (size_t)t * 2304 + c2);
  } else if (b < 7200) {
    int idx = (b - 4608) * 256 + tid;
    pack8(W_qkv + (size_t)idx * 8, wqkvb + (size_t)idx * 8);
  } else if (b < 7488) {
    int idx = (b - 7200) * 256 + tid;
    pack8(W_out + (size_t)idx * 8, woutb + (size_t)idx * 8);
  } else {
    int lane = tid & 63;
    int wid0 = ((b - 7488) * 256 + tid) >> 6;
    for (int wid = wid0; wid < 262144; wid += 8192) {
      int row = wid >> 6;
      int wp = wid & 63;
      int s = wp * 64 + lane;
      int mval = mask[(size_t)row * 4096 + s];
      unsigned long long bb = __ballot(mval != 0);
      if (lane == 0) {
        maskw[row * 128 + wp * 2]     = (unsigned)bb;
        maskw[row * 128 + wp * 2 + 1] = (unsigned)(bb >> 32);
      }
    }
  }
}

// -------- fused: transposeV (blocks 0..767) + rowflag (blocks 768..1023) ---

__global__ __launch_bounds__(256) void tv_rowflag(
    const unsigned short* __restrict__ qkvb, unsigned short* __restrict__ vt,
    const unsigned* __restrict__ maskw, const int* __restrict__ mask_future,
    int* __restrict__ cnt, int* __restrict__ list) {
  const int b = blockIdx.x;
  const int tid = threadIdx.x;
  if (b < 768) {
    __shared__ unsigned short tl[64][65];
    const int t0 = (b & 63) * 64;
    const int hsrc = (b >> 6) * 192 + 128;
    for (int pass = 0; pass < 2; ++pass) {
      int r = (tid >> 3) + pass * 32;
      int fc = (tid & 7) * 8;
      bf16x8 vv = *(const bf16x8*)&qkvb[(size_t)(t0 + r) * 2304 + hsrc + fc];
      for (int e = 0; e < 8; ++e) tl[fc + e][r] = (unsigned short)vv[e];
    }
    __syncthreads();
    const int f = tid >> 2;
    const int sg = (tid & 3) * 16;
    for (int j = 0; j < 2; ++j) {
      bf16x8 o;
      for (int e = 0; e < 8; ++e) o[e] = (short)tl[f][sg + j * 8 + e];
      *(bf16x8*)&vt[(size_t)((b >> 6) * 64 + f) * 4096 + t0 + sg + j * 8] = o;
    }
  } else {
    const bool causal = (mask_future[0] != 0);
    int wv = ((b - 768) * 256 + tid) >> 6;  // 0..1023
    int lane = tid & 63;
    for (int row = wv * 4; row < wv * 4 + 4; ++row) {
      unsigned acc = 0;
      int jmax = causal ? (row >> 5) : 127;
      for (int j = lane; j <= jmax; j += 64) {
        unsigned wb = maskw[row * 128 + j];
        if (causal && j == jmax) {
          int rem = row & 31;
          wb &= (rem == 31) ? 0xffffffffu : ((2u << rem) - 1u);
        }
        acc |= wb;
      }
      if (!__any(acc != 0)) {
        if (lane == 0) {
          int i = atomicAdd(cnt, 1);
          if (i < 64) list[i] = row;
        }
      }
    }
  }
}

// ------------- GEMM: C[M][N] = A[M][K] * B[N][K]^T, BM=128, BN=NF*32 -------

__device__ __forceinline__ void storeC(float* p, float v) { *p = v; }
__device__ __forceinline__ void storeC(unsigned short* p, float v) { *p = f2bf(v); }

template <typename OutT, int NF>
__global__ __launch_bounds__(256) void gemm_bt(const unsigned short* __restrict__ A,
                                               const unsigned short* __restrict__ B,
                                               OutT* __restrict__ C,
                                               int M, int N, int K) {
  constexpr int BN = NF * 32;
  __shared__ unsigned short As[128 * 64];
  __shared__ unsigned short Bs[BN * 64];
  const int tid = threadIdx.x;
  const int lane = tid & 63;
  const int w = tid >> 6;
  const int wr = w >> 1, wc = w & 1;
  const int l15 = lane & 15, lhi = lane >> 4;

  int lblk = blockIdx.y * gridDim.x + blockIdx.x;
  int nwg = gridDim.x * gridDim.y;
  int sw = (lblk & 7) * (nwg >> 3) + (lblk >> 3);
  int bxg = sw % gridDim.x;
  int byg = sw / gridDim.x;

  const size_t abase = (size_t)(bxg * 128) * K;
  const size_t bbase = (size_t)(byg * BN) * K;

  f32x4 acc[4][NF] = {};

  for (int k0 = 0; k0 < K; k0 += 64) {
    __syncthreads();
    #pragma unroll
    for (int i = 0; i < 4; ++i) {
      int c = (w << 8) + (i << 6) + lane;
      int row = c >> 3, cb = c & 7;
      load_lds16(A + abase + (size_t)row * K + k0 + cb * 8, &As[c * 8]);
    }
    #pragma unroll
    for (int i = 0; i < NF; ++i) {
      int c = w * (NF * 64) + (i << 6) + lane;
      int row = c >> 3, cb = c & 7;
      load_lds16(B + bbase + (size_t)row * K + k0 + cb * 8, &Bs[c * 8]);
    }
    __syncthreads();
    #pragma unroll
    for (int kk = 0; kk < 2; ++kk) {
      bf16x8 af[4], bfr[NF];
      #pragma unroll
      for (int m = 0; m < 4; ++m)
        af[m] = *(const bf16x8*)&As[(wr * 64 + m * 16 + l15) * 64 + kk * 32 + lhi * 8];
      #pragma unroll
      for (int n = 0; n < NF; ++n)
        bfr[n] = *(const bf16x8*)&Bs[(wc * NF * 16 + n * 16 + l15) * 64 + kk * 32 + lhi * 8];
      #pragma unroll
      for (int m = 0; m < 4; ++m)
        #pragma unroll
        for (int n = 0; n < NF; ++n)
          acc[m][n] = __builtin_amdgcn_mfma_f32_16x16x32_bf16(af[m], bfr[n], acc[m][n], 0, 0, 0);
    }
  }

  #pragma unroll
  for (int m = 0; m < 4; ++m) {
    int row0 = bxg * 128 + wr * 64 + m * 16 + lhi * 4;
    #pragma unroll
    for (int n = 0; n < NF; ++n) {
      int col = byg * BN + wc * NF * 16 + n * 16 + l15;
      #pragma unroll
      for (int r = 0; r < 4; ++r)
        storeC(&C[(size_t)(row0 + r) * N + col], acc[m][n][r]);
    }
  }
}

// -------------------- attention (R14 body + MFMA row-sum) ------------------
// Global 1296-item longest-first queue (C=28 split-K). Max-free softmax:
// Q pre-scaled by CEXP, p = exp2(logit), masked -> KNEG -> 0. Double-
// buffered K/V LDS, 1 barrier/tile. Row sums via ones-vector MFMA: osum[r]
// holds sum_k P[q=w*16+lhi*4+r][k] directly in finalize layout.

__global__ __launch_bounds__(256) void attn_kernel(
    const unsigned short* __restrict__ qkv,  // [4096][2304] bf16
    const unsigned short* __restrict__ vt,   // [768][4096] bf16 V^T
    const unsigned* __restrict__ maskw,      // [4096][128]
    const int* __restrict__ mask_future,
    int* __restrict__ ctr,
    float* __restrict__ parts,               // [1296][4224] f32 (O|l)
    unsigned short* __restrict__ scr) {      // scrambled [4096*768] bf16
  const int tid = threadIdx.x;
  const int lane = tid & 63;
  const int w = tid >> 6;
  const int l15 = lane & 15, lhi = lane >> 4;
  const bool causal = (mask_future[0] != 0);
  const int srcA = l15 + (((2 * lhi) & 3) << 4);
  const int srcB = l15 + (((2 * lhi + 1) & 3) << 4);
  const int hi2 = lhi >> 1;

  // all-ones bf16 B-fragment for row-sum MFMA
  union { bf16x8 v; unsigned u[4]; } onesf;
  #pragma unroll
  for (int i = 0; i < 4; ++i) onesf.u[i] = 0x3F803F80u;

  __shared__ unsigned short Klds[2][64 * 64];  // [key][d], swizzled
  __shared__ unsigned short Vs[2][64 * 64];    // [d][key], swizzled
  __shared__ int item_s;

  // per-lane staging geometry (item-invariant)
  int srow[2], scb[2];
  #pragma unroll
  for (int i = 0; i < 2; ++i) {
    int cc = (w << 7) + (i << 6) + lane;
    srow[i] = cc >> 3;
    scb[i] = ((cc & 7) ^ (srow[i] & 7)) * 8;
  }

  for (;;) {
    if (tid == 0) item_s = atomicAdd(ctr, 1);
    __syncthreads();  // publish item; drains previous item's in-flight stages
    const int idx = item_s;
    if (idx >= 1296) break;
    int c, bx, h;
    if (idx < 444)      { c = 0; bx = 63 - idx / 12; h = idx % 12; }
    else if (idx < 552) { int j = idx - 444; c = 1; bx = 63 - j / 12; h = j % 12; }
    else if (idx < 1008) {
      int j = idx - 552; int L = 27 - j / 24; int u = j % 24;
      c = (u < 12) ? 1 : 0; bx = c ? (27 + L) : (L - 1); h = u % 12;
    } else {
      int j = idx - 1008; int L = 8 - j / 36; int u = j % 36;
      c = (u < 12) ? 2 : ((u < 24) ? 1 : 0);
      bx = (c == 2) ? (55 + L) : ((c == 1) ? (27 + L) : (L - 1)); h = u % 12;
    }

    int t0c, t1c, diag;
    bool split;
    if (causal) {
      t0c = c * 28;
      t1c = min(t0c + 28, bx + 1);
      diag = bx;
      split = (bx >= 28);
    } else {  // non-causal: c=0 items do the whole range, others skip
      if (c != 0) continue;
      t0c = 0; t1c = 64; diag = 64; split = false;
    }
    const int hoff = h * 192;
    const int l0 = bx << 6;
    const int lq = l0 + w * 16 + l15;

    // hoisted staging base pointers (advance by tile)
    const unsigned short* kb[2];
    const unsigned short* vb[2];
    #pragma unroll
    for (int i = 0; i < 2; ++i) {
      kb[i] = qkv + (size_t)(t0c * 64 + srow[i]) * 2304 + hoff + 64 + scb[i];
      vb[i] = vt + (size_t)(h * 64 + srow[i]) * 4096 + t0c * 64 + scb[i];
    }

    // Q B-fragments, pre-scaled by CEXP (logits emerge in log2 units)
    bf16x8 qf[2];
    {
      const unsigned short* qp = qkv + (size_t)lq * 2304 + hoff;
      qf[0] = *(const bf16x8*)(qp + lhi * 8);
      qf[1] = *(const bf16x8*)(qp + 32 + lhi * 8);
      #pragma unroll
      for (int i = 0; i < 2; ++i) {
        union { bf16x8 v; unsigned u[4]; } qa; qa.v = qf[i];
        #pragma unroll
        for (int p = 0; p < 4; ++p) {
          float lo = bf2f((unsigned short)(qa.u[p] & 0xffff)) * CEXP;
          float hi = bf2f((unsigned short)(qa.u[p] >> 16)) * CEXP;
          asm("v_cvt_pk_bf16_f32 %0, %1, %2" : "=v"(qa.u[p]) : "v"(lo), "v"(hi));
        }
        qf[i] = qa.v;
      }
    }
    // prologue: stage tile t0c -> buf 0
    #pragma unroll
    for (int i = 0; i < 2; ++i) {
      int cc = (w << 7) + (i << 6) + lane;
      load_lds16(kb[i], &Klds[0][cc * 8]);
      load_lds16(vb[i], &Vs[0][cc * 8]);
    }
    const unsigned* mrow_p = maskw + lq * 128;
    uint2 mk_next = *(const uint2*)(mrow_p + t0c * 2);

    f32x4 oacc[4] = {};
    f32x4 osum = {};  // row sums of P, rows = w*16 + lhi*4 + r
    int cur = 0;

    for (int it = t0c; it < t1c; ++it) {
      __syncthreads();  // drains stage(it); protects buf reuse

      if (it + 1 < t1c) {
        #pragma unroll
        for (int i = 0; i < 2; ++i) {
          kb[i] += 64 * 2304;
          vb[i] += 64;
          int cc = (w << 7) + (i << 6) + lane;
          load_lds16(kb[i], &Klds[cur ^ 1][cc * 8]);
          load_lds16(vb[i], &Vs[cur ^ 1][cc * 8]);
        }
      }
      uint2 mk = mk_next;
      if (it + 1 < t1c) mk_next = *(const uint2*)(mrow_p + (it + 1) * 2);

      const int s0 = it * 64;

      // S^T (log2 units) = mfma(A=K, B=Q·CEXP); lane: S[q=lq][k=s0+n*16+lhi*4+r]
      f32x4 sacc[4] = {};
      __builtin_amdgcn_s_setprio(1);
      #pragma unroll
      for (int kk = 0; kk < 2; ++kk) {
        bf16x8 kf[4];
        #pragma unroll
        for (int n = 0; n < 4; ++n) {
          int rk = n * 16 + l15;
          int col = (kk * 32 + lhi * 8) ^ ((rk & 7) << 3);
          kf[n] = *(const bf16x8*)&Klds[cur][rk * 64 + col];
        }
        #pragma unroll
        for (int n = 0; n < 4; ++n)
          sacc[n] = __builtin_amdgcn_mfma_f32_16x16x32_bf16(kf[n], qf[kk], sacc[n], 0, 0, 0);
      }
      __builtin_amdgcn_s_setprio(0);

      // masked logits -> p = exp2(logit); masked -> exp2(KNEG) = 0
      float vals[4][4];
      {
        unsigned a = mk.x >> (lhi * 4);
        unsigned b = mk.y >> (lhi * 4);
        if (it < diag) {
          #pragma unroll
          for (int n = 0; n < 4; ++n) {
            unsigned wsh = ((n < 2) ? a : b) >> ((n & 1) << 4);
            #pragma unroll
            for (int r = 0; r < 4; ++r)
              vals[n][r] = ((wsh >> r) & 1u) ? sacc[n][r] : KNEG;
          }
        } else {  // diagonal tile
          #pragma unroll
          for (int n = 0; n < 4; ++n) {
            unsigned wsh = ((n < 2) ? a : b) >> ((n & 1) << 4);
            int kb2 = s0 + n * 16 + lhi * 4;
            #pragma unroll
            for (int r = 0; r < 4; ++r) {
              float vv = (kb2 + r > lq) ? KNEG : sacc[n][r];
              vals[n][r] = ((wsh >> r) & 1u) ? vv : KNEG;
            }
          }
        }
      }

      #pragma unroll
      for (int n = 0; n < 4; ++n)
        #pragma unroll
        for (int r = 0; r < 4; ++r)
          vals[n][r] = fexp2(vals[n][r]);

      // pack P to bf16 pairs
      unsigned pk[4][2];
      #pragma unroll
      for (int n = 0; n < 4; ++n)
        #pragma unroll
        for (int rp = 0; rp < 2; ++rp)
          asm("v_cvt_pk_bf16_f32 %0, %1, %2"
              : "=v"(pk[n][rp])
              : "v"(vals[n][2 * rp]), "v"(vals[n][2 * rp + 1]));

      // PV + row-sum (ones-vector MFMA shares the A fragment)
      #pragma unroll
      for (int kk = 0; kk < 2; ++kk) {
        unsigned a0 = __shfl(pk[2 * kk][0], srcA);
        unsigned a1 = __shfl(pk[2 * kk][1], srcA);
        unsigned a2 = __shfl(pk[2 * kk][0], srcB);
        unsigned a3 = __shfl(pk[2 * kk][1], srcB);
        unsigned b0 = __shfl(pk[2 * kk + 1][0], srcA);
        unsigned b1 = __shfl(pk[2 * kk + 1][1], srcA);
        unsigned b2 = __shfl(pk[2 * kk + 1][0], srcB);
        unsigned b3 = __shfl(pk[2 * kk + 1][1], srcB);
        union { bf16x8 v; unsigned u[4]; } af;
        af.u[0] = hi2 ? b0 : a0;
        af.u[1] = hi2 ? b1 : a1;
        af.u[2] = hi2 ? b2 : a2;
        af.u[3] = hi2 ? b3 : a3;
        __builtin_amdgcn_s_setprio(1);
        osum = __builtin_amdgcn_mfma_f32_16x16x32_bf16(af.v, onesf.v, osum, 0, 0, 0);
        #pragma unroll
        for (int n = 0; n < 4; ++n) {
          int rv = n * 16 + l15;
          int col = (kk * 32 + lhi * 8) ^ ((rv & 7) << 3);
          bf16x8 vf = *(const bf16x8*)&Vs[cur][rv * 64 + col];
          oacc[n] = __builtin_amdgcn_mfma_f32_16x16x32_bf16(af.v, vf, oacc[n], 0, 0, 0);
        }
        __builtin_amdgcn_s_setprio(0);
      }
      cur ^= 1;
    }

    // ---------- finalize (osum[r] already in (lhi,r) row layout) ----------
    const int row0 = w * 16 + lhi * 4;

    if (split) {
      int prefix = bx + max(bx - 28, 0) + max(bx - 56, 0);
      float* pg = parts + (size_t)((prefix + c) * 12 + h) * 4224;
      #pragma unroll
      for (int n = 0; n < 4; ++n)
        #pragma unroll
        for (int r = 0; r < 4; ++r)
          pg[(size_t)(row0 + r) * 64 + n * 16 + l15] = oacc[n][r];
      if (l15 == 0) {
        #pragma unroll
        for (int r = 0; r < 4; ++r)
          pg[4096 + row0 + r] = osum[r];
      }
    } else {
      float rq[4];
      #pragma unroll
      for (int r = 0; r < 4; ++r) rq[r] = 1.0f / osum[r];
      #pragma unroll
      for (int n = 0; n < 4; ++n) {
        int d = n * 16 + l15;
        size_t base = (size_t)h * 262144 + (size_t)d * 4096 + (size_t)(l0 + row0);
        us4 o;
        #pragma unroll
        for (int r = 0; r < 4; ++r) o[r] = f2bf(oacc[n][r] * rq[r]);
        *(us4*)(scr + base) = o;
      }
    }
  }
}

// -------- fused: merge_k (blocks 0..431) + fixrows (blocks 432..1199) ------

__global__ __launch_bounds__(256) void merge_fix(
    const float* __restrict__ parts, const unsigned short* __restrict__ qkv,
    const unsigned short* __restrict__ vt, const unsigned* __restrict__ maskw,
    const int* __restrict__ mask_future, const int* __restrict__ cnt,
    const int* __restrict__ list, unsigned short* __restrict__ scr) {
  const int b = blockIdx.x;
  const bool causal = (mask_future[0] != 0);
  if (b < 432) {
    if (!causal) return;  // non-causal: no splits
    const int sg = b;
    const int bx = 28 + sg / 12;
    const int h = sg % 12;
    const int nch = 2 + (bx >= 56);
    const int prefix = bx + max(bx - 28, 0) + max(bx - 56, 0);
    const int t = threadIdx.x;
    const int row = t >> 2;
    const int dg = (t & 3) * 16;

    const float* pg[3];
    for (int cc = 0; cc < 3; ++cc)
      pg[cc] = parts + (size_t)((prefix + min(cc, nch - 1)) * 12 + h) * 4224;

    float L = pg[0][4096 + row] + pg[1][4096 + row];
    if (nch == 3) L += pg[2][4096 + row];
    if (L == 0.f) return;  // degenerate row: fixrows owns it (no race)
    float rL = 1.0f / L;

    #pragma unroll
    for (int dd = 0; dd < 16; ++dd) {
      int d = dg + dd;
      float o = pg[0][(size_t)row * 64 + d] + pg[1][(size_t)row * 64 + d];
      if (nch == 3) o += pg[2][(size_t)row * 64 + d];
      scr[(size_t)h * 262144 + (size_t)d * 4096 + bx * 64 + row] = f2bf(o * rL);
    }
  } else {
    const int bb = b - 432;
    const int i = bb / 12;
    const int h = bb % 12;
    int n = *cnt; if (n > 64) n = 64;
    if (i >= n) return;
    const int row = list[i];
    const int tid = threadIdx.x;
    const int lane = tid & 63;
    const int wv = tid >> 6;

    __shared__ float qs[64];
    __shared__ float ps[4096];
    __shared__ float red[16];

    if (tid < 64) qs[tid] = bf2f(qkv[(size_t)row * 2304 + h * 192 + tid]);
    __syncthreads();

    float pv[16];
    float mymax = -INFINITY;
    #pragma unroll
    for (int kk = 0; kk < 16; ++kk) {
      int key = tid * 16 + kk;
      const unsigned short* kp = qkv + (size_t)key * 2304 + h * 192 + 64;
      float s = 0.f;
      #pragma unroll
      for (int d8 = 0; d8 < 8; ++d8) {
        bf16x8 kv8 = *(const bf16x8*)(kp + d8 * 8);
        #pragma unroll
        for (int e = 0; e < 8; ++e)
          s += qs[d8 * 8 + e] * bf2f((unsigned short)kv8[e]);
      }
      s *= 0.125f;
      unsigned bit = (maskw[row * 128 + (key >> 5)] >> (key & 31)) & 1u;
      float val = bit ? ((causal && key > row) ? s - 10000.f : s) : -10000.f;
      pv[kk] = val;
      mymax = fmaxf(mymax, val);
    }
    for (int xx = 1; xx < 64; xx <<= 1) mymax = fmaxf(mymax, __shfl_xor(mymax, xx));
    if (lane == 0) red[wv] = mymax;
    __syncthreads();
    const float M = fmaxf(fmaxf(red[0], red[1]), fmaxf(red[2], red[3]));

    float sum = 0.f;
    #pragma unroll
    for (int kk = 0; kk < 16; ++kk) {
      float p = fexp2((pv[kk] - M) * L2E);
      ps[tid * 16 + kk] = p;
      sum += p;
    }
    for (int xx = 1; xx < 64; xx <<= 1) sum += __shfl_xor(sum, xx);
    if (lane == 0) red[8 + wv] = sum;
    __syncthreads();
    const float L = red[8] + red[9] + red[10] + red[11];

    const int d = tid >> 2, qq = tid & 3;
    float acc = 0.f;
    for (int jb = qq * 1024; jb < qq * 1024 + 1024; jb += 8) {
      bf16x8 vv8 = *(const bf16x8*)&vt[(size_t)(h * 64 + d) * 4096 + jb];
      #pragma unroll
      for (int e = 0; e < 8; ++e)
        acc += ps[jb + e] * bf2f((unsigned short)vv8[e]);
    }
    acc += __shfl_xor(acc, 1);
    acc += __shfl_xor(acc, 2);
    if (qq == 0)
      scr[(size_t)h * 262144 + (size_t)d * 4096 + row] = f2bf(acc / L);
  }
}

// -------------------- launch --------------------

extern "C" void kernel_launch(void* const* d_in, const int* in_sizes, int n_in,
                              void* d_out, int out_size, void* d_ws, size_t ws_size,
                              hipStream_t stream) {
  const float* q = (const float*)d_in[0];
  const float* k = (const float*)d_in[1];
  const float* v = (const float*)d_in[2];
  const int* attn_mask = (const int*)d_in[3];
  const int* mask_future = (const int*)d_in[4];
  const float* W_qkv = (const float*)d_in[5];
  const float* W_out = (const float*)d_in[6];
  float* out = (float*)d_out;

  char* ws = (char*)d_ws;
  unsigned short* xb    = (unsigned short*)(ws);            // [0,18.87M) live until qkv GEMM
  unsigned short* vt    = (unsigned short*)(ws);            // [0,6.29M) after tv_rowflag
  char*           ctl   = ws + 6291456;                     // 4KB, memset AFTER gemm
  int*            ctr   = (int*)(ctl);
  int*            cnt   = (int*)(ctl + 256);
  int*            list  = (int*)(ctl + 1024);               // [64]
  float*          parts = (float*)(ws + 6295552);           // 1296*4224*4 = 21.90MB
  unsigned short* wqkvb = (unsigned short*)(ws + 18874368); // dead after qkv GEMM
  unsigned short* qkvb  = (unsigned short*)(ws + 29491200);
  unsigned*       maskw = (unsigned*)(ws + 48365568);
  unsigned short* scr   = (unsigned short*)(ws + 50462720);
  unsigned short* woutb = (unsigned short*)(ws + 56754176);
  if (ws_size < 57933824) return;

  pack_all<<<9536, 256, 0, stream>>>(q, k, v, W_qkv, W_out, attn_mask,
                                     xb, wqkvb, woutb, maskw);
  gemm_bt<unsigned short, 3><<<dim3(32, 24), 256, 0, stream>>>(xb, wqkvb, qkvb, 4096, 2304, 2304);
  hipMemsetAsync(ctl, 0, 4096, stream);   // AFTER gemm: xb dead (R6 lesson)
  tv_rowflag<<<1024, 256, 0, stream>>>(qkvb, vt, maskw, mask_future, cnt, list);
  attn_kernel<<<1024, 256, 0, stream>>>(qkvb, vt, maskw, mask_future, ctr, parts, scr);
  merge_fix<<<1200, 256, 0, stream>>>(parts, qkvb, vt, maskw, mask_future, cnt, list, scr);
  gemm_bt<float, 3><<<dim3(32, 8), 256, 0, stream>>>(scr, woutb, out, 4096, 768, 768);
}

// Round 17
// 199.587 us; speedup vs baseline: 1.6357x; 1.0172x over previous
//
#include <hip/hip_runtime.h>

// ---------------------------------------------------------------------------
// FastMultiHeadAttention on MI355X (gfx950)
// Round 17: revert attn to the R15 body (203.0us known-good; R16's counted-
// vmcnt pipeline failed correctness and is abandoned -- 3rd failed sync
// restructure). One isolated change: output-projection GEMM NF=3->NF=1
// (BN=32), grid (32,24)=768 blocks = 3/CU instead of 1/CU. Its working set
// (~20MB) is L3-resident, so it is latency/occupancy-bound, not BW-bound;
// tripled A-refetch is L3-absorbed. Everything else identical to R15.
// ---------------------------------------------------------------------------

typedef __attribute__((ext_vector_type(8))) short bf16x8;
typedef __attribute__((ext_vector_type(4))) float f32x4;
typedef __attribute__((ext_vector_type(4))) unsigned short us4;

#define KNEG -15000.0f              // masked logit in log2 units; exp2 -> 0
#define CEXP 0.18033688011112042f   // 0.125 * log2(e)
#define L2E  1.4426950408889634f

__device__ __forceinline__ unsigned short f2bf(float f) {
  union { float f; unsigned u; } x; x.f = f;
  unsigned r = x.u + 0x7fffu + ((x.u >> 16) & 1u);
  return (unsigned short)(r >> 16);
}

__device__ __forceinline__ float bf2f(unsigned short u) {
  union { unsigned u; float f; } x; x.u = (unsigned)u << 16;
  return x.f;
}

__device__ __forceinline__ float fexp2(float x) {
  return __builtin_amdgcn_exp2f(x);
}

__device__ __forceinline__ void load_lds16(const void* g, void* l) {
  __builtin_amdgcn_global_load_lds(
      (const __attribute__((address_space(1))) void*)g,
      (__attribute__((address_space(3))) void*)l, 16, 0, 0);
}

// -------------------- fused pack kernel --------------------

__device__ __forceinline__ void pack8(const float* __restrict__ src,
                                      unsigned short* __restrict__ dst) {
  const float4* p = (const float4*)src;
  float4 a = p[0], b = p[1];
  bf16x8 o;
  o[0] = (short)f2bf(a.x); o[1] = (short)f2bf(a.y);
  o[2] = (short)f2bf(a.z); o[3] = (short)f2bf(a.w);
  o[4] = (short)f2bf(b.x); o[5] = (short)f2bf(b.y);
  o[6] = (short)f2bf(b.z); o[7] = (short)f2bf(b.w);
  *(bf16x8*)dst = o;
}

__global__ __launch_bounds__(256) void pack_all(
    const float* __restrict__ q, const float* __restrict__ k,
    const float* __restrict__ v, const float* __restrict__ W_qkv,
    const float* __restrict__ W_out, const int* __restrict__ mask,
    unsigned short* __restrict__ xb, unsigned short* __restrict__ wqkvb,
    unsigned short* __restrict__ woutb, unsigned* __restrict__ maskw) {
  const int b = blockIdx.x;
  const int tid = threadIdx.x;
  if (b < 4608) {
    int idx = b * 256 + tid;
    int t = idx / 288;
    int c2 = (idx - t * 288) * 8;
    const float* src;
    int c;
    if (c2 < 768)       { src = q; c = c2; }
    else if (c2 < 1536) { src = k; c = c2 - 768; }
    else                { src = v; c = c2 - 1536; }
    pack8(src + (size_t)t * 768 + c, xb + (size_t)t * 2304 + c2);
  } else if (b < 7200) {
    int idx = (b - 4608) * 256 + tid;
    pack8(W_qkv + (size_t)idx * 8, wqkvb + (size_t)idx * 8);
  } else if (b < 7488) {
    int idx = (b - 7200) * 256 + tid;
    pack8(W_out + (size_t)idx * 8, woutb + (size_t)idx * 8);
  } else {
    int lane = tid & 63;
    int wid0 = ((b - 7488) * 256 + tid) >> 6;
    for (int wid = wid0; wid < 262144; wid += 8192) {
      int row = wid >> 6;
      int wp = wid & 63;
      int s = wp * 64 + lane;
      int mval = mask[(size_t)row * 4096 + s];
      unsigned long long bb = __ballot(mval != 0);
      if (lane == 0) {
        maskw[row * 128 + wp * 2]     = (unsigned)bb;
        maskw[row * 128 + wp * 2 + 1] = (unsigned)(bb >> 32);
      }
    }
  }
}

// -------- fused: transposeV (blocks 0..767) + rowflag (blocks 768..1023) ---

__global__ __launch_bounds__(256) void tv_rowflag(
    const unsigned short* __restrict__ qkvb, unsigned short* __restrict__ vt,
    const unsigned* __restrict__ maskw, const int* __restrict__ mask_future,
    int* __restrict__ cnt, int* __restrict__ list) {
  const int b = blockIdx.x;
  const int tid = threadIdx.x;
  if (b < 768) {
    __shared__ unsigned short tl[64][65];
    const int t0 = (b & 63) * 64;
    const int hsrc = (b >> 6) * 192 + 128;
    for (int pass = 0; pass < 2; ++pass) {
      int r = (tid >> 3) + pass * 32;
      int fc = (tid & 7) * 8;
      bf16x8 vv = *(const bf16x8*)&qkvb[(size_t)(t0 + r) * 2304 + hsrc + fc];
      for (int e = 0; e < 8; ++e) tl[fc + e][r] = (unsigned short)vv[e];
    }
    __syncthreads();
    const int f = tid >> 2;
    const int sg = (tid & 3) * 16;
    for (int j = 0; j < 2; ++j) {
      bf16x8 o;
      for (int e = 0; e < 8; ++e) o[e] = (short)tl[f][sg + j * 8 + e];
      *(bf16x8*)&vt[(size_t)((b >> 6) * 64 + f) * 4096 + t0 + sg + j * 8] = o;
    }
  } else {
    const bool causal = (mask_future[0] != 0);
    int wv = ((b - 768) * 256 + tid) >> 6;  // 0..1023
    int lane = tid & 63;
    for (int row = wv * 4; row < wv * 4 + 4; ++row) {
      unsigned acc = 0;
      int jmax = causal ? (row >> 5) : 127;
      for (int j = lane; j <= jmax; j += 64) {
        unsigned wb = maskw[row * 128 + j];
        if (causal && j == jmax) {
          int rem = row & 31;
          wb &= (rem == 31) ? 0xffffffffu : ((2u << rem) - 1u);
        }
        acc |= wb;
      }
      if (!__any(acc != 0)) {
        if (lane == 0) {
          int i = atomicAdd(cnt, 1);
          if (i < 64) list[i] = row;
        }
      }
    }
  }
}

// ------------- GEMM: C[M][N] = A[M][K] * B[N][K]^T, BM=128, BN=NF*32 -------

__device__ __forceinline__ void storeC(float* p, float v) { *p = v; }
__device__ __forceinline__ void storeC(unsigned short* p, float v) { *p = f2bf(v); }

template <typename OutT, int NF>
__global__ __launch_bounds__(256) void gemm_bt(const unsigned short* __restrict__ A,
                                               const unsigned short* __restrict__ B,
                                               OutT* __restrict__ C,
                                               int M, int N, int K) {
  constexpr int BN = NF * 32;
  __shared__ unsigned short As[128 * 64];
  __shared__ unsigned short Bs[BN * 64];
  const int tid = threadIdx.x;
  const int lane = tid & 63;
  const int w = tid >> 6;
  const int wr = w >> 1, wc = w & 1;
  const int l15 = lane & 15, lhi = lane >> 4;

  int lblk = blockIdx.y * gridDim.x + blockIdx.x;
  int nwg = gridDim.x * gridDim.y;
  int sw = (lblk & 7) * (nwg >> 3) + (lblk >> 3);
  int bxg = sw % gridDim.x;
  int byg = sw / gridDim.x;

  const size_t abase = (size_t)(bxg * 128) * K;
  const size_t bbase = (size_t)(byg * BN) * K;

  f32x4 acc[4][NF] = {};

  for (int k0 = 0; k0 < K; k0 += 64) {
    __syncthreads();
    #pragma unroll
    for (int i = 0; i < 4; ++i) {
      int c = (w << 8) + (i << 6) + lane;
      int row = c >> 3, cb = c & 7;
      load_lds16(A + abase + (size_t)row * K + k0 + cb * 8, &As[c * 8]);
    }
    #pragma unroll
    for (int i = 0; i < NF; ++i) {
      int c = w * (NF * 64) + (i << 6) + lane;
      int row = c >> 3, cb = c & 7;
      load_lds16(B + bbase + (size_t)row * K + k0 + cb * 8, &Bs[c * 8]);
    }
    __syncthreads();
    #pragma unroll
    for (int kk = 0; kk < 2; ++kk) {
      bf16x8 af[4], bfr[NF];
      #pragma unroll
      for (int m = 0; m < 4; ++m)
        af[m] = *(const bf16x8*)&As[(wr * 64 + m * 16 + l15) * 64 + kk * 32 + lhi * 8];
      #pragma unroll
      for (int n = 0; n < NF; ++n)
        bfr[n] = *(const bf16x8*)&Bs[(wc * NF * 16 + n * 16 + l15) * 64 + kk * 32 + lhi * 8];
      #pragma unroll
      for (int m = 0; m < 4; ++m)
        #pragma unroll
        for (int n = 0; n < NF; ++n)
          acc[m][n] = __builtin_amdgcn_mfma_f32_16x16x32_bf16(af[m], bfr[n], acc[m][n], 0, 0, 0);
    }
  }

  #pragma unroll
  for (int m = 0; m < 4; ++m) {
    int row0 = bxg * 128 + wr * 64 + m * 16 + lhi * 4;
    #pragma unroll
    for (int n = 0; n < NF; ++n) {
      int col = byg * BN + wc * NF * 16 + n * 16 + l15;
      #pragma unroll
      for (int r = 0; r < 4; ++r)
        storeC(&C[(size_t)(row0 + r) * N + col], acc[m][n][r]);
    }
  }
}

// -------------------- attention (R15 body: dbuf LDS, 1 barrier/tile) -------
// Global 1296-item longest-first queue (C=28 split-K). Max-free softmax:
// Q pre-scaled by CEXP, p = exp2(logit), masked -> KNEG -> 0. Row sums via
// ones-vector MFMA (osum in finalize layout). Double-buffered K/V LDS.

__global__ __launch_bounds__(256) void attn_kernel(
    const unsigned short* __restrict__ qkv,  // [4096][2304] bf16
    const unsigned short* __restrict__ vt,   // [768][4096] bf16 V^T
    const unsigned* __restrict__ maskw,      // [4096][128]
    const int* __restrict__ mask_future,
    int* __restrict__ ctr,
    float* __restrict__ parts,               // [1296][4224] f32 (O|l)
    unsigned short* __restrict__ scr) {      // scrambled [4096*768] bf16
  const int tid = threadIdx.x;
  const int lane = tid & 63;
  const int w = tid >> 6;
  const int l15 = lane & 15, lhi = lane >> 4;
  const bool causal = (mask_future[0] != 0);
  const int srcA = l15 + (((2 * lhi) & 3) << 4);
  const int srcB = l15 + (((2 * lhi + 1) & 3) << 4);
  const int hi2 = lhi >> 1;

  // all-ones bf16 B-fragment for row-sum MFMA
  union { bf16x8 v; unsigned u[4]; } onesf;
  #pragma unroll
  for (int i = 0; i < 4; ++i) onesf.u[i] = 0x3F803F80u;

  __shared__ unsigned short Klds[2][64 * 64];  // [key][d], swizzled
  __shared__ unsigned short Vs[2][64 * 64];    // [d][key], swizzled
  __shared__ int item_s;

  // per-lane staging geometry (item-invariant)
  int srow[2], scb[2];
  #pragma unroll
  for (int i = 0; i < 2; ++i) {
    int cc = (w << 7) + (i << 6) + lane;
    srow[i] = cc >> 3;
    scb[i] = ((cc & 7) ^ (srow[i] & 7)) * 8;
  }

  for (;;) {
    if (tid == 0) item_s = atomicAdd(ctr, 1);
    __syncthreads();  // publish item; drains previous item's in-flight stages
    const int idx = item_s;
    if (idx >= 1296) break;
    int c, bx, h;
    if (idx < 444)      { c = 0; bx = 63 - idx / 12; h = idx % 12; }
    else if (idx < 552) { int j = idx - 444; c = 1; bx = 63 - j / 12; h = j % 12; }
    else if (idx < 1008) {
      int j = idx - 552; int L = 27 - j / 24; int u = j % 24;
      c = (u < 12) ? 1 : 0; bx = c ? (27 + L) : (L - 1); h = u % 12;
    } else {
      int j = idx - 1008; int L = 8 - j / 36; int u = j % 36;
      c = (u < 12) ? 2 : ((u < 24) ? 1 : 0);
      bx = (c == 2) ? (55 + L) : ((c == 1) ? (27 + L) : (L - 1)); h = u % 12;
    }

    int t0c, t1c, diag;
    bool split;
    if (causal) {
      t0c = c * 28;
      t1c = min(t0c + 28, bx + 1);
      diag = bx;
      split = (bx >= 28);
    } else {  // non-causal: c=0 items do the whole range, others skip
      if (c != 0) continue;
      t0c = 0; t1c = 64; diag = 64; split = false;
    }
    const int hoff = h * 192;
    const int l0 = bx << 6;
    const int lq = l0 + w * 16 + l15;

    // hoisted staging base pointers (advance by tile)
    const unsigned short* kb[2];
    const unsigned short* vb[2];
    #pragma unroll
    for (int i = 0; i < 2; ++i) {
      kb[i] = qkv + (size_t)(t0c * 64 + srow[i]) * 2304 + hoff + 64 + scb[i];
      vb[i] = vt + (size_t)(h * 64 + srow[i]) * 4096 + t0c * 64 + scb[i];
    }

    // Q B-fragments, pre-scaled by CEXP (logits emerge in log2 units)
    bf16x8 qf[2];
    {
      const unsigned short* qp = qkv + (size_t)lq * 2304 + hoff;
      qf[0] = *(const bf16x8*)(qp + lhi * 8);
      qf[1] = *(const bf16x8*)(qp + 32 + lhi * 8);
      #pragma unroll
      for (int i = 0; i < 2; ++i) {
        union { bf16x8 v; unsigned u[4]; } qa; qa.v = qf[i];
        #pragma unroll
        for (int p = 0; p < 4; ++p) {
          float lo = bf2f((unsigned short)(qa.u[p] & 0xffff)) * CEXP;
          float hi = bf2f((unsigned short)(qa.u[p] >> 16)) * CEXP;
          asm("v_cvt_pk_bf16_f32 %0, %1, %2" : "=v"(qa.u[p]) : "v"(lo), "v"(hi));
        }
        qf[i] = qa.v;
      }
    }
    // prologue: stage tile t0c -> buf 0
    #pragma unroll
    for (int i = 0; i < 2; ++i) {
      int cc = (w << 7) + (i << 6) + lane;
      load_lds16(kb[i], &Klds[0][cc * 8]);
      load_lds16(vb[i], &Vs[0][cc * 8]);
    }
    const unsigned* mrow_p = maskw + lq * 128;
    uint2 mk_next = *(const uint2*)(mrow_p + t0c * 2);

    f32x4 oacc[4] = {};
    f32x4 osum = {};  // row sums of P, rows = w*16 + lhi*4 + r
    int cur = 0;

    for (int it = t0c; it < t1c; ++it) {
      __syncthreads();  // drains stage(it); protects buf reuse

      if (it + 1 < t1c) {
        #pragma unroll
        for (int i = 0; i < 2; ++i) {
          kb[i] += 64 * 2304;
          vb[i] += 64;
          int cc = (w << 7) + (i << 6) + lane;
          load_lds16(kb[i], &Klds[cur ^ 1][cc * 8]);
          load_lds16(vb[i], &Vs[cur ^ 1][cc * 8]);
        }
      }
      uint2 mk = mk_next;
      if (it + 1 < t1c) mk_next = *(const uint2*)(mrow_p + (it + 1) * 2);

      const int s0 = it * 64;

      // S^T (log2 units) = mfma(A=K, B=Q·CEXP); lane: S[q=lq][k=s0+n*16+lhi*4+r]
      f32x4 sacc[4] = {};
      __builtin_amdgcn_s_setprio(1);
      #pragma unroll
      for (int kk = 0; kk < 2; ++kk) {
        bf16x8 kf[4];
        #pragma unroll
        for (int n = 0; n < 4; ++n) {
          int rk = n * 16 + l15;
          int col = (kk * 32 + lhi * 8) ^ ((rk & 7) << 3);
          kf[n] = *(const bf16x8*)&Klds[cur][rk * 64 + col];
        }
        #pragma unroll
        for (int n = 0; n < 4; ++n)
          sacc[n] = __builtin_amdgcn_mfma_f32_16x16x32_bf16(kf[n], qf[kk], sacc[n], 0, 0, 0);
      }
      __builtin_amdgcn_s_setprio(0);

      // masked logits -> p = exp2(logit); masked -> exp2(KNEG) = 0
      float vals[4][4];
      {
        unsigned a = mk.x >> (lhi * 4);
        unsigned b = mk.y >> (lhi * 4);
        if (it < diag) {
          #pragma unroll
          for (int n = 0; n < 4; ++n) {
            unsigned wsh = ((n < 2) ? a : b) >> ((n & 1) << 4);
            #pragma unroll
            for (int r = 0; r < 4; ++r)
              vals[n][r] = ((wsh >> r) & 1u) ? sacc[n][r] : KNEG;
          }
        } else {  // diagonal tile
          #pragma unroll
          for (int n = 0; n < 4; ++n) {
            unsigned wsh = ((n < 2) ? a : b) >> ((n & 1) << 4);
            int kb2 = s0 + n * 16 + lhi * 4;
            #pragma unroll
            for (int r = 0; r < 4; ++r) {
              float vv = (kb2 + r > lq) ? KNEG : sacc[n][r];
              vals[n][r] = ((wsh >> r) & 1u) ? vv : KNEG;
            }
          }
        }
      }

      #pragma unroll
      for (int n = 0; n < 4; ++n)
        #pragma unroll
        for (int r = 0; r < 4; ++r)
          vals[n][r] = fexp2(vals[n][r]);

      // pack P to bf16 pairs
      unsigned pk[4][2];
      #pragma unroll
      for (int n = 0; n < 4; ++n)
        #pragma unroll
        for (int rp = 0; rp < 2; ++rp)
          asm("v_cvt_pk_bf16_f32 %0, %1, %2"
              : "=v"(pk[n][rp])
              : "v"(vals[n][2 * rp]), "v"(vals[n][2 * rp + 1]));

      // PV + row-sum (ones-vector MFMA shares the A fragment)
      #pragma unroll
      for (int kk = 0; kk < 2; ++kk) {
        unsigned a0 = __shfl(pk[2 * kk][0], srcA);
        unsigned a1 = __shfl(pk[2 * kk][1], srcA);
        unsigned a2 = __shfl(pk[2 * kk][0], srcB);
        unsigned a3 = __shfl(pk[2 * kk][1], srcB);
        unsigned b0 = __shfl(pk[2 * kk + 1][0], srcA);
        unsigned b1 = __shfl(pk[2 * kk + 1][1], srcA);
        unsigned b2 = __shfl(pk[2 * kk + 1][0], srcB);
        unsigned b3 = __shfl(pk[2 * kk + 1][1], srcB);
        union { bf16x8 v; unsigned u[4]; } af;
        af.u[0] = hi2 ? b0 : a0;
        af.u[1] = hi2 ? b1 : a1;
        af.u[2] = hi2 ? b2 : a2;
        af.u[3] = hi2 ? b3 : a3;
        __builtin_amdgcn_s_setprio(1);
        osum = __builtin_amdgcn_mfma_f32_16x16x32_bf16(af.v, onesf.v, osum, 0, 0, 0);
        #pragma unroll
        for (int n = 0; n < 4; ++n) {
          int rv = n * 16 + l15;
          int col = (kk * 32 + lhi * 8) ^ ((rv & 7) << 3);
          bf16x8 vf = *(const bf16x8*)&Vs[cur][rv * 64 + col];
          oacc[n] = __builtin_amdgcn_mfma_f32_16x16x32_bf16(af.v, vf, oacc[n], 0, 0, 0);
        }
        __builtin_amdgcn_s_setprio(0);
      }
      cur ^= 1;
    }

    // ---------- finalize (osum[r] already in (lhi,r) row layout) ----------
    const int row0 = w * 16 + lhi * 4;

    if (split) {
      int prefix = bx + max(bx - 28, 0) + max(bx - 56, 0);
      float* pg = parts + (size_t)((prefix + c) * 12 + h) * 4224;
      #pragma unroll
      for (int n = 0; n < 4; ++n)
        #pragma unroll
        for (int r = 0; r < 4; ++r)
          pg[(size_t)(row0 + r) * 64 + n * 16 + l15] = oacc[n][r];
      if (l15 == 0) {
        #pragma unroll
        for (int r = 0; r < 4; ++r)
          pg[4096 + row0 + r] = osum[r];
      }
    } else {
      float rq[4];
      #pragma unroll
      for (int r = 0; r < 4; ++r) rq[r] = 1.0f / osum[r];
      #pragma unroll
      for (int n = 0; n < 4; ++n) {
        int d = n * 16 + l15;
        size_t base = (size_t)h * 262144 + (size_t)d * 4096 + (size_t)(l0 + row0);
        us4 o;
        #pragma unroll
        for (int r = 0; r < 4; ++r) o[r] = f2bf(oacc[n][r] * rq[r]);
        *(us4*)(scr + base) = o;
      }
    }
  }
}

// -------- fused: merge_k (blocks 0..431) + fixrows (blocks 432..1199) ------

__global__ __launch_bounds__(256) void merge_fix(
    const float* __restrict__ parts, const unsigned short* __restrict__ qkv,
    const unsigned short* __restrict__ vt, const unsigned* __restrict__ maskw,
    const int* __restrict__ mask_future, const int* __restrict__ cnt,
    const int* __restrict__ list, unsigned short* __restrict__ scr) {
  const int b = blockIdx.x;
  const bool causal = (mask_future[0] != 0);
  if (b < 432) {
    if (!causal) return;  // non-causal: no splits
    const int sg = b;
    const int bx = 28 + sg / 12;
    const int h = sg % 12;
    const int nch = 2 + (bx >= 56);
    const int prefix = bx + max(bx - 28, 0) + max(bx - 56, 0);
    const int t = threadIdx.x;
    const int row = t >> 2;
    const int dg = (t & 3) * 16;

    const float* pg[3];
    for (int cc = 0; cc < 3; ++cc)
      pg[cc] = parts + (size_t)((prefix + min(cc, nch - 1)) * 12 + h) * 4224;

    float L = pg[0][4096 + row] + pg[1][4096 + row];
    if (nch == 3) L += pg[2][4096 + row];
    if (L == 0.f) return;  // degenerate row: fixrows owns it (no race)
    float rL = 1.0f / L;

    #pragma unroll
    for (int dd = 0; dd < 16; ++dd) {
      int d = dg + dd;
      float o = pg[0][(size_t)row * 64 + d] + pg[1][(size_t)row * 64 + d];
      if (nch == 3) o += pg[2][(size_t)row * 64 + d];
      scr[(size_t)h * 262144 + (size_t)d * 4096 + bx * 64 + row] = f2bf(o * rL);
    }
  } else {
    const int bb = b - 432;
    const int i = bb / 12;
    const int h = bb % 12;
    int n = *cnt; if (n > 64) n = 64;
    if (i >= n) return;
    const int row = list[i];
    const int tid = threadIdx.x;
    const int lane = tid & 63;
    const int wv = tid >> 6;

    __shared__ float qs[64];
    __shared__ float ps[4096];
    __shared__ float red[16];

    if (tid < 64) qs[tid] = bf2f(qkv[(size_t)row * 2304 + h * 192 + tid]);
    __syncthreads();

    float pv[16];
    float mymax = -INFINITY;
    #pragma unroll
    for (int kk = 0; kk < 16; ++kk) {
      int key = tid * 16 + kk;
      const unsigned short* kp = qkv + (size_t)key * 2304 + h * 192 + 64;
      float s = 0.f;
      #pragma unroll
      for (int d8 = 0; d8 < 8; ++d8) {
        bf16x8 kv8 = *(const bf16x8*)(kp + d8 * 8);
        #pragma unroll
        for (int e = 0; e < 8; ++e)
          s += qs[d8 * 8 + e] * bf2f((unsigned short)kv8[e]);
      }
      s *= 0.125f;
      unsigned bit = (maskw[row * 128 + (key >> 5)] >> (key & 31)) & 1u;
      float val = bit ? ((causal && key > row) ? s - 10000.f : s) : -10000.f;
      pv[kk] = val;
      mymax = fmaxf(mymax, val);
    }
    for (int xx = 1; xx < 64; xx <<= 1) mymax = fmaxf(mymax, __shfl_xor(mymax, xx));
    if (lane == 0) red[wv] = mymax;
    __syncthreads();
    const float M = fmaxf(fmaxf(red[0], red[1]), fmaxf(red[2], red[3]));

    float sum = 0.f;
    #pragma unroll
    for (int kk = 0; kk < 16; ++kk) {
      float p = fexp2((pv[kk] - M) * L2E);
      ps[tid * 16 + kk] = p;
      sum += p;
    }
    for (int xx = 1; xx < 64; xx <<= 1) sum += __shfl_xor(sum, xx);
    if (lane == 0) red[8 + wv] = sum;
    __syncthreads();
    const float L = red[8] + red[9] + red[10] + red[11];

    const int d = tid >> 2, qq = tid & 3;
    float acc = 0.f;
    for (int jb = qq * 1024; jb < qq * 1024 + 1024; jb += 8) {
      bf16x8 vv8 = *(const bf16x8*)&vt[(size_t)(h * 64 + d) * 4096 + jb];
      #pragma unroll
      for (int e = 0; e < 8; ++e)
        acc += ps[jb + e] * bf2f((unsigned short)vv8[e]);
    }
    acc += __shfl_xor(acc, 1);
    acc += __shfl_xor(acc, 2);
    if (qq == 0)
      scr[(size_t)h * 262144 + (size_t)d * 4096 + row] = f2bf(acc / L);
  }
}

// -------------------- launch --------------------

extern "C" void kernel_launch(void* const* d_in, const int* in_sizes, int n_in,
                              void* d_out, int out_size, void* d_ws, size_t ws_size,
                              hipStream_t stream) {
  const float* q = (const float*)d_in[0];
  const float* k = (const float*)d_in[1];
  const float* v = (const float*)d_in[2];
  const int* attn_mask = (const int*)d_in[3];
  const int* mask_future = (const int*)d_in[4];
  const float* W_qkv = (const float*)d_in[5];
  const float* W_out = (const float*)d_in[6];
  float* out = (float*)d_out;

  char* ws = (char*)d_ws;
  unsigned short* xb    = (unsigned short*)(ws);            // [0,18.87M) live until qkv GEMM
  unsigned short* vt    = (unsigned short*)(ws);            // [0,6.29M) after tv_rowflag
  char*           ctl   = ws + 6291456;                     // 4KB, memset AFTER gemm
  int*            ctr   = (int*)(ctl);
  int*            cnt   = (int*)(ctl + 256);
  int*            list  = (int*)(ctl + 1024);               // [64]
  float*          parts = (float*)(ws + 6295552);           // 1296*4224*4 = 21.90MB
  unsigned short* wqkvb = (unsigned short*)(ws + 18874368); // dead after qkv GEMM
  unsigned short* qkvb  = (unsigned short*)(ws + 29491200);
  unsigned*       maskw = (unsigned*)(ws + 48365568);
  unsigned short* scr   = (unsigned short*)(ws + 50462720);
  unsigned short* woutb = (unsigned short*)(ws + 56754176);
  if (ws_size < 57933824) return;

  pack_all<<<9536, 256, 0, stream>>>(q, k, v, W_qkv, W_out, attn_mask,
                                     xb, wqkvb, woutb, maskw);
  gemm_bt<unsigned short, 3><<<dim3(32, 24), 256, 0, stream>>>(xb, wqkvb, qkvb, 4096, 2304, 2304);
  hipMemsetAsync(ctl, 0, 4096, stream);   // AFTER gemm: xb dead (R6 lesson)
  tv_rowflag<<<1024, 256, 0, stream>>>(qkvb, vt, maskw, mask_future, cnt, list);
  attn_kernel<<<1024, 256, 0, stream>>>(qkvb, vt, maskw, mask_future, ctr, parts, scr);
  merge_fix<<<1200, 256, 0, stream>>>(parts, qkvb, vt, maskw, mask_future, cnt, list, scr);
  gemm_bt<float, 1><<<dim3(32, 24), 256, 0, stream>>>(scr, woutb, out, 4096, 768, 768);
}

// Round 18
// 183.838 us; speedup vs baseline: 1.7758x; 1.0857x over previous
//
#include <hip/hip_runtime.h>

// ---------------------------------------------------------------------------
// FastMultiHeadAttention on MI355X (gfx950)
// Round 18: attn residency 4->5 blocks/CU. The 4-byte item_s pushed LDS to
// 32.5KB (4 blocks/CU); replacing the atomic queue with a STATIC longest-
// first schedule (block b: item b; blocks 752..1023 also take tail item
// 1024+(1023-b), pairing shortest-with-shortest -> makespan still bounded
// by the 28-tile items) removes item_s -> LDS exactly 32768B -> 5 blocks/CU
// (5*32KB = 160KB exactly; 20 waves; VGPR 60 <= 102 budget). No sync or
// arithmetic changes; R17 body (199.6us) otherwise verbatim.
// ---------------------------------------------------------------------------

typedef __attribute__((ext_vector_type(8))) short bf16x8;
typedef __attribute__((ext_vector_type(4))) float f32x4;
typedef __attribute__((ext_vector_type(4))) unsigned short us4;

#define KNEG -15000.0f              // masked logit in log2 units; exp2 -> 0
#define CEXP 0.18033688011112042f   // 0.125 * log2(e)
#define L2E  1.4426950408889634f

__device__ __forceinline__ unsigned short f2bf(float f) {
  union { float f; unsigned u; } x; x.f = f;
  unsigned r = x.u + 0x7fffu + ((x.u >> 16) & 1u);
  return (unsigned short)(r >> 16);
}

__device__ __forceinline__ float bf2f(unsigned short u) {
  union { unsigned u; float f; } x; x.u = (unsigned)u << 16;
  return x.f;
}

__device__ __forceinline__ float fexp2(float x) {
  return __builtin_amdgcn_exp2f(x);
}

__device__ __forceinline__ void load_lds16(const void* g, void* l) {
  __builtin_amdgcn_global_load_lds(
      (const __attribute__((address_space(1))) void*)g,
      (__attribute__((address_space(3))) void*)l, 16, 0, 0);
}

// -------------------- fused pack kernel --------------------

__device__ __forceinline__ void pack8(const float* __restrict__ src,
                                      unsigned short* __restrict__ dst) {
  const float4* p = (const float4*)src;
  float4 a = p[0], b = p[1];
  bf16x8 o;
  o[0] = (short)f2bf(a.x); o[1] = (short)f2bf(a.y);
  o[2] = (short)f2bf(a.z); o[3] = (short)f2bf(a.w);
  o[4] = (short)f2bf(b.x); o[5] = (short)f2bf(b.y);
  o[6] = (short)f2bf(b.z); o[7] = (short)f2bf(b.w);
  *(bf16x8*)dst = o;
}

__global__ __launch_bounds__(256) void pack_all(
    const float* __restrict__ q, const float* __restrict__ k,
    const float* __restrict__ v, const float* __restrict__ W_qkv,
    const float* __restrict__ W_out, const int* __restrict__ mask,
    unsigned short* __restrict__ xb, unsigned short* __restrict__ wqkvb,
    unsigned short* __restrict__ woutb, unsigned* __restrict__ maskw) {
  const int b = blockIdx.x;
  const int tid = threadIdx.x;
  if (b < 4608) {
    int idx = b * 256 + tid;
    int t = idx / 288;
    int c2 = (idx - t * 288) * 8;
    const float* src;
    int c;
    if (c2 < 768)       { src = q; c = c2; }
    else if (c2 < 1536) { src = k; c = c2 - 768; }
    else                { src = v; c = c2 - 1536; }
    pack8(src + (size_t)t * 768 + c, xb + (size_t)t * 2304 + c2);
  } else if (b < 7200) {
    int idx = (b - 4608) * 256 + tid;
    pack8(W_qkv + (size_t)idx * 8, wqkvb + (size_t)idx * 8);
  } else if (b < 7488) {
    int idx = (b - 7200) * 256 + tid;
    pack8(W_out + (size_t)idx * 8, woutb + (size_t)idx * 8);
  } else {
    int lane = tid & 63;
    int wid0 = ((b - 7488) * 256 + tid) >> 6;
    for (int wid = wid0; wid < 262144; wid += 8192) {
      int row = wid >> 6;
      int wp = wid & 63;
      int s = wp * 64 + lane;
      int mval = mask[(size_t)row * 4096 + s];
      unsigned long long bb = __ballot(mval != 0);
      if (lane == 0) {
        maskw[row * 128 + wp * 2]     = (unsigned)bb;
        maskw[row * 128 + wp * 2 + 1] = (unsigned)(bb >> 32);
      }
    }
  }
}

// -------- fused: transposeV (blocks 0..767) + rowflag (blocks 768..1023) ---

__global__ __launch_bounds__(256) void tv_rowflag(
    const unsigned short* __restrict__ qkvb, unsigned short* __restrict__ vt,
    const unsigned* __restrict__ maskw, const int* __restrict__ mask_future,
    int* __restrict__ cnt, int* __restrict__ list) {
  const int b = blockIdx.x;
  const int tid = threadIdx.x;
  if (b < 768) {
    __shared__ unsigned short tl[64][65];
    const int t0 = (b & 63) * 64;
    const int hsrc = (b >> 6) * 192 + 128;
    for (int pass = 0; pass < 2; ++pass) {
      int r = (tid >> 3) + pass * 32;
      int fc = (tid & 7) * 8;
      bf16x8 vv = *(const bf16x8*)&qkvb[(size_t)(t0 + r) * 2304 + hsrc + fc];
      for (int e = 0; e < 8; ++e) tl[fc + e][r] = (unsigned short)vv[e];
    }
    __syncthreads();
    const int f = tid >> 2;
    const int sg = (tid & 3) * 16;
    for (int j = 0; j < 2; ++j) {
      bf16x8 o;
      for (int e = 0; e < 8; ++e) o[e] = (short)tl[f][sg + j * 8 + e];
      *(bf16x8*)&vt[(size_t)((b >> 6) * 64 + f) * 4096 + t0 + sg + j * 8] = o;
    }
  } else {
    const bool causal = (mask_future[0] != 0);
    int wv = ((b - 768) * 256 + tid) >> 6;  // 0..1023
    int lane = tid & 63;
    for (int row = wv * 4; row < wv * 4 + 4; ++row) {
      unsigned acc = 0;
      int jmax = causal ? (row >> 5) : 127;
      for (int j = lane; j <= jmax; j += 64) {
        unsigned wb = maskw[row * 128 + j];
        if (causal && j == jmax) {
          int rem = row & 31;
          wb &= (rem == 31) ? 0xffffffffu : ((2u << rem) - 1u);
        }
        acc |= wb;
      }
      if (!__any(acc != 0)) {
        if (lane == 0) {
          int i = atomicAdd(cnt, 1);
          if (i < 64) list[i] = row;
        }
      }
    }
  }
}

// ------------- GEMM: C[M][N] = A[M][K] * B[N][K]^T, BM=128, BN=NF*32 -------

__device__ __forceinline__ void storeC(float* p, float v) { *p = v; }
__device__ __forceinline__ void storeC(unsigned short* p, float v) { *p = f2bf(v); }

template <typename OutT, int NF>
__global__ __launch_bounds__(256) void gemm_bt(const unsigned short* __restrict__ A,
                                               const unsigned short* __restrict__ B,
                                               OutT* __restrict__ C,
                                               int M, int N, int K) {
  constexpr int BN = NF * 32;
  __shared__ unsigned short As[128 * 64];
  __shared__ unsigned short Bs[BN * 64];
  const int tid = threadIdx.x;
  const int lane = tid & 63;
  const int w = tid >> 6;
  const int wr = w >> 1, wc = w & 1;
  const int l15 = lane & 15, lhi = lane >> 4;

  int lblk = blockIdx.y * gridDim.x + blockIdx.x;
  int nwg = gridDim.x * gridDim.y;
  int sw = (lblk & 7) * (nwg >> 3) + (lblk >> 3);
  int bxg = sw % gridDim.x;
  int byg = sw / gridDim.x;

  const size_t abase = (size_t)(bxg * 128) * K;
  const size_t bbase = (size_t)(byg * BN) * K;

  f32x4 acc[4][NF] = {};

  for (int k0 = 0; k0 < K; k0 += 64) {
    __syncthreads();
    #pragma unroll
    for (int i = 0; i < 4; ++i) {
      int c = (w << 8) + (i << 6) + lane;
      int row = c >> 3, cb = c & 7;
      load_lds16(A + abase + (size_t)row * K + k0 + cb * 8, &As[c * 8]);
    }
    #pragma unroll
    for (int i = 0; i < NF; ++i) {
      int c = w * (NF * 64) + (i << 6) + lane;
      int row = c >> 3, cb = c & 7;
      load_lds16(B + bbase + (size_t)row * K + k0 + cb * 8, &Bs[c * 8]);
    }
    __syncthreads();
    #pragma unroll
    for (int kk = 0; kk < 2; ++kk) {
      bf16x8 af[4], bfr[NF];
      #pragma unroll
      for (int m = 0; m < 4; ++m)
        af[m] = *(const bf16x8*)&As[(wr * 64 + m * 16 + l15) * 64 + kk * 32 + lhi * 8];
      #pragma unroll
      for (int n = 0; n < NF; ++n)
        bfr[n] = *(const bf16x8*)&Bs[(wc * NF * 16 + n * 16 + l15) * 64 + kk * 32 + lhi * 8];
      #pragma unroll
      for (int m = 0; m < 4; ++m)
        #pragma unroll
        for (int n = 0; n < NF; ++n)
          acc[m][n] = __builtin_amdgcn_mfma_f32_16x16x32_bf16(af[m], bfr[n], acc[m][n], 0, 0, 0);
    }
  }

  #pragma unroll
  for (int m = 0; m < 4; ++m) {
    int row0 = bxg * 128 + wr * 64 + m * 16 + lhi * 4;
    #pragma unroll
    for (int n = 0; n < NF; ++n) {
      int col = byg * BN + wc * NF * 16 + n * 16 + l15;
      #pragma unroll
      for (int r = 0; r < 4; ++r)
        storeC(&C[(size_t)(row0 + r) * N + col], acc[m][n][r]);
    }
  }
}

// ------------ attention (R17 body, static schedule, 5 blocks/CU) -----------
// Static longest-first: block b -> item b; blocks 752..1023 also take tail
// item 1024+(1023-b). Item idx -> (c,bx,h) decode as before (C=28 split-K).
// Max-free softmax: Q pre-scaled by CEXP, p = exp2(logit), masked -> KNEG.
// Row sums via ones-vector MFMA. Double-buffered K/V LDS, 1 barrier/tile.
// Shared memory exactly 32KB -> 5 blocks/CU.

__global__ __launch_bounds__(256) void attn_kernel(
    const unsigned short* __restrict__ qkv,  // [4096][2304] bf16
    const unsigned short* __restrict__ vt,   // [768][4096] bf16 V^T
    const unsigned* __restrict__ maskw,      // [4096][128]
    const int* __restrict__ mask_future,
    float* __restrict__ parts,               // [1296][4224] f32 (O|l)
    unsigned short* __restrict__ scr) {      // scrambled [4096*768] bf16
  const int tid = threadIdx.x;
  const int lane = tid & 63;
  const int w = tid >> 6;
  const int l15 = lane & 15, lhi = lane >> 4;
  const bool causal = (mask_future[0] != 0);
  const int srcA = l15 + (((2 * lhi) & 3) << 4);
  const int srcB = l15 + (((2 * lhi + 1) & 3) << 4);
  const int hi2 = lhi >> 1;
  const int blk = blockIdx.x;

  // all-ones bf16 B-fragment for row-sum MFMA
  union { bf16x8 v; unsigned u[4]; } onesf;
  #pragma unroll
  for (int i = 0; i < 4; ++i) onesf.u[i] = 0x3F803F80u;

  __shared__ unsigned short Klds[2][64 * 64];  // [key][d], swizzled
  __shared__ unsigned short Vs[2][64 * 64];    // [d][key], swizzled
  // total shared = 32768B exactly -> 5 blocks/CU

  // per-lane staging geometry (item-invariant)
  int srow[2], scb[2];
  #pragma unroll
  for (int i = 0; i < 2; ++i) {
    int cc = (w << 7) + (i << 6) + lane;
    srow[i] = cc >> 3;
    scb[i] = ((cc & 7) ^ (srow[i] & 7)) * 8;
  }

  for (int s = 0; s < 2; ++s) {
    int idx;
    if (s == 0) idx = blk;
    else if (blk >= 752) idx = 1024 + (1023 - blk);
    else break;

    __syncthreads();  // previous item's LDS reads complete before restage

    int c, bx, h;
    if (idx < 444)      { c = 0; bx = 63 - idx / 12; h = idx % 12; }
    else if (idx < 552) { int j = idx - 444; c = 1; bx = 63 - j / 12; h = j % 12; }
    else if (idx < 1008) {
      int j = idx - 552; int L = 27 - j / 24; int u = j % 24;
      c = (u < 12) ? 1 : 0; bx = c ? (27 + L) : (L - 1); h = u % 12;
    } else {
      int j = idx - 1008; int L = 8 - j / 36; int u = j % 36;
      c = (u < 12) ? 2 : ((u < 24) ? 1 : 0);
      bx = (c == 2) ? (55 + L) : ((c == 1) ? (27 + L) : (L - 1)); h = u % 12;
    }

    int t0c, t1c, diag;
    bool split;
    if (causal) {
      t0c = c * 28;
      t1c = min(t0c + 28, bx + 1);
      diag = bx;
      split = (bx >= 28);
    } else {  // non-causal: c=0 items do the whole range, others skip
      if (c != 0) continue;
      t0c = 0; t1c = 64; diag = 64; split = false;
    }
    const int hoff = h * 192;
    const int l0 = bx << 6;
    const int lq = l0 + w * 16 + l15;

    // hoisted staging base pointers (advance by tile)
    const unsigned short* kb[2];
    const unsigned short* vb[2];
    #pragma unroll
    for (int i = 0; i < 2; ++i) {
      kb[i] = qkv + (size_t)(t0c * 64 + srow[i]) * 2304 + hoff + 64 + scb[i];
      vb[i] = vt + (size_t)(h * 64 + srow[i]) * 4096 + t0c * 64 + scb[i];
    }

    // Q B-fragments, pre-scaled by CEXP (logits emerge in log2 units)
    bf16x8 qf[2];
    {
      const unsigned short* qp = qkv + (size_t)lq * 2304 + hoff;
      qf[0] = *(const bf16x8*)(qp + lhi * 8);
      qf[1] = *(const bf16x8*)(qp + 32 + lhi * 8);
      #pragma unroll
      for (int i = 0; i < 2; ++i) {
        union { bf16x8 v; unsigned u[4]; } qa; qa.v = qf[i];
        #pragma unroll
        for (int p = 0; p < 4; ++p) {
          float lo = bf2f((unsigned short)(qa.u[p] & 0xffff)) * CEXP;
          float hi = bf2f((unsigned short)(qa.u[p] >> 16)) * CEXP;
          asm("v_cvt_pk_bf16_f32 %0, %1, %2" : "=v"(qa.u[p]) : "v"(lo), "v"(hi));
        }
        qf[i] = qa.v;
      }
    }
    // prologue: stage tile t0c -> buf 0
    #pragma unroll
    for (int i = 0; i < 2; ++i) {
      int cc = (w << 7) + (i << 6) + lane;
      load_lds16(kb[i], &Klds[0][cc * 8]);
      load_lds16(vb[i], &Vs[0][cc * 8]);
    }
    const unsigned* mrow_p = maskw + lq * 128;
    uint2 mk_next = *(const uint2*)(mrow_p + t0c * 2);

    f32x4 oacc[4] = {};
    f32x4 osum = {};  // row sums of P, rows = w*16 + lhi*4 + r
    int cur = 0;

    for (int it = t0c; it < t1c; ++it) {
      __syncthreads();  // drains stage(it); protects buf reuse

      if (it + 1 < t1c) {
        #pragma unroll
        for (int i = 0; i < 2; ++i) {
          kb[i] += 64 * 2304;
          vb[i] += 64;
          int cc = (w << 7) + (i << 6) + lane;
          load_lds16(kb[i], &Klds[cur ^ 1][cc * 8]);
          load_lds16(vb[i], &Vs[cur ^ 1][cc * 8]);
        }
      }
      uint2 mk = mk_next;
      if (it + 1 < t1c) mk_next = *(const uint2*)(mrow_p + (it + 1) * 2);

      const int s0 = it * 64;

      // S^T (log2 units) = mfma(A=K, B=Q·CEXP); lane: S[q=lq][k=s0+n*16+lhi*4+r]
      f32x4 sacc[4] = {};
      __builtin_amdgcn_s_setprio(1);
      #pragma unroll
      for (int kk = 0; kk < 2; ++kk) {
        bf16x8 kf[4];
        #pragma unroll
        for (int n = 0; n < 4; ++n) {
          int rk = n * 16 + l15;
          int col = (kk * 32 + lhi * 8) ^ ((rk & 7) << 3);
          kf[n] = *(const bf16x8*)&Klds[cur][rk * 64 + col];
        }
        #pragma unroll
        for (int n = 0; n < 4; ++n)
          sacc[n] = __builtin_amdgcn_mfma_f32_16x16x32_bf16(kf[n], qf[kk], sacc[n], 0, 0, 0);
      }
      __builtin_amdgcn_s_setprio(0);

      // masked logits -> p = exp2(logit); masked -> exp2(KNEG) = 0
      float vals[4][4];
      {
        unsigned a = mk.x >> (lhi * 4);
        unsigned b = mk.y >> (lhi * 4);
        if (it < diag) {
          #pragma unroll
          for (int n = 0; n < 4; ++n) {
            unsigned wsh = ((n < 2) ? a : b) >> ((n & 1) << 4);
            #pragma unroll
            for (int r = 0; r < 4; ++r)
              vals[n][r] = ((wsh >> r) & 1u) ? sacc[n][r] : KNEG;
          }
        } else {  // diagonal tile
          #pragma unroll
          for (int n = 0; n < 4; ++n) {
            unsigned wsh = ((n < 2) ? a : b) >> ((n & 1) << 4);
            int kb2 = s0 + n * 16 + lhi * 4;
            #pragma unroll
            for (int r = 0; r < 4; ++r) {
              float vv = (kb2 + r > lq) ? KNEG : sacc[n][r];
              vals[n][r] = ((wsh >> r) & 1u) ? vv : KNEG;
            }
          }
        }
      }

      #pragma unroll
      for (int n = 0; n < 4; ++n)
        #pragma unroll
        for (int r = 0; r < 4; ++r)
          vals[n][r] = fexp2(vals[n][r]);

      // pack P to bf16 pairs
      unsigned pk[4][2];
      #pragma unroll
      for (int n = 0; n < 4; ++n)
        #pragma unroll
        for (int rp = 0; rp < 2; ++rp)
          asm("v_cvt_pk_bf16_f32 %0, %1, %2"
              : "=v"(pk[n][rp])
              : "v"(vals[n][2 * rp]), "v"(vals[n][2 * rp + 1]));

      // PV + row-sum (ones-vector MFMA shares the A fragment)
      #pragma unroll
      for (int kk = 0; kk < 2; ++kk) {
        unsigned a0 = __shfl(pk[2 * kk][0], srcA);
        unsigned a1 = __shfl(pk[2 * kk][1], srcA);
        unsigned a2 = __shfl(pk[2 * kk][0], srcB);
        unsigned a3 = __shfl(pk[2 * kk][1], srcB);
        unsigned b0 = __shfl(pk[2 * kk + 1][0], srcA);
        unsigned b1 = __shfl(pk[2 * kk + 1][1], srcA);
        unsigned b2 = __shfl(pk[2 * kk + 1][0], srcB);
        unsigned b3 = __shfl(pk[2 * kk + 1][1], srcB);
        union { bf16x8 v; unsigned u[4]; } af;
        af.u[0] = hi2 ? b0 : a0;
        af.u[1] = hi2 ? b1 : a1;
        af.u[2] = hi2 ? b2 : a2;
        af.u[3] = hi2 ? b3 : a3;
        __builtin_amdgcn_s_setprio(1);
        osum = __builtin_amdgcn_mfma_f32_16x16x32_bf16(af.v, onesf.v, osum, 0, 0, 0);
        #pragma unroll
        for (int n = 0; n < 4; ++n) {
          int rv = n * 16 + l15;
          int col = (kk * 32 + lhi * 8) ^ ((rv & 7) << 3);
          bf16x8 vf = *(const bf16x8*)&Vs[cur][rv * 64 + col];
          oacc[n] = __builtin_amdgcn_mfma_f32_16x16x32_bf16(af.v, vf, oacc[n], 0, 0, 0);
        }
        __builtin_amdgcn_s_setprio(0);
      }
      cur ^= 1;
    }

    // ---------- finalize (osum[r] already in (lhi,r) row layout) ----------
    const int row0 = w * 16 + lhi * 4;

    if (split) {
      int prefix = bx + max(bx - 28, 0) + max(bx - 56, 0);
      float* pg = parts + (size_t)((prefix + c) * 12 + h) * 4224;
      #pragma unroll
      for (int n = 0; n < 4; ++n)
        #pragma unroll
        for (int r = 0; r < 4; ++r)
          pg[(size_t)(row0 + r) * 64 + n * 16 + l15] = oacc[n][r];
      if (l15 == 0) {
        #pragma unroll
        for (int r = 0; r < 4; ++r)
          pg[4096 + row0 + r] = osum[r];
      }
    } else {
      float rq[4];
      #pragma unroll
      for (int r = 0; r < 4; ++r) rq[r] = 1.0f / osum[r];
      #pragma unroll
      for (int n = 0; n < 4; ++n) {
        int d = n * 16 + l15;
        size_t base = (size_t)h * 262144 + (size_t)d * 4096 + (size_t)(l0 + row0);
        us4 o;
        #pragma unroll
        for (int r = 0; r < 4; ++r) o[r] = f2bf(oacc[n][r] * rq[r]);
        *(us4*)(scr + base) = o;
      }
    }
  }
}

// -------- fused: merge_k (blocks 0..431) + fixrows (blocks 432..1199) ------

__global__ __launch_bounds__(256) void merge_fix(
    const float* __restrict__ parts, const unsigned short* __restrict__ qkv,
    const unsigned short* __restrict__ vt, const unsigned* __restrict__ maskw,
    const int* __restrict__ mask_future, const int* __restrict__ cnt,
    const int* __restrict__ list, unsigned short* __restrict__ scr) {
  const int b = blockIdx.x;
  const bool causal = (mask_future[0] != 0);
  if (b < 432) {
    if (!causal) return;  // non-causal: no splits
    const int sg = b;
    const int bx = 28 + sg / 12;
    const int h = sg % 12;
    const int nch = 2 + (bx >= 56);
    const int prefix = bx + max(bx - 28, 0) + max(bx - 56, 0);
    const int t = threadIdx.x;
    const int row = t >> 2;
    const int dg = (t & 3) * 16;

    const float* pg[3];
    for (int cc = 0; cc < 3; ++cc)
      pg[cc] = parts + (size_t)((prefix + min(cc, nch - 1)) * 12 + h) * 4224;

    float L = pg[0][4096 + row] + pg[1][4096 + row];
    if (nch == 3) L += pg[2][4096 + row];
    if (L == 0.f) return;  // degenerate row: fixrows owns it (no race)
    float rL = 1.0f / L;

    #pragma unroll
    for (int dd = 0; dd < 16; ++dd) {
      int d = dg + dd;
      float o = pg[0][(size_t)row * 64 + d] + pg[1][(size_t)row * 64 + d];
      if (nch == 3) o += pg[2][(size_t)row * 64 + d];
      scr[(size_t)h * 262144 + (size_t)d * 4096 + bx * 64 + row] = f2bf(o * rL);
    }
  } else {
    const int bb = b - 432;
    const int i = bb / 12;
    const int h = bb % 12;
    int n = *cnt; if (n > 64) n = 64;
    if (i >= n) return;
    const int row = list[i];
    const int tid = threadIdx.x;
    const int lane = tid & 63;
    const int wv = tid >> 6;

    __shared__ float qs[64];
    __shared__ float ps[4096];
    __shared__ float red[16];

    if (tid < 64) qs[tid] = bf2f(qkv[(size_t)row * 2304 + h * 192 + tid]);
    __syncthreads();

    float pv[16];
    float mymax = -INFINITY;
    #pragma unroll
    for (int kk = 0; kk < 16; ++kk) {
      int key = tid * 16 + kk;
      const unsigned short* kp = qkv + (size_t)key * 2304 + h * 192 + 64;
      float s = 0.f;
      #pragma unroll
      for (int d8 = 0; d8 < 8; ++d8) {
        bf16x8 kv8 = *(const bf16x8*)(kp + d8 * 8);
        #pragma unroll
        for (int e = 0; e < 8; ++e)
          s += qs[d8 * 8 + e] * bf2f((unsigned short)kv8[e]);
      }
      s *= 0.125f;
      unsigned bit = (maskw[row * 128 + (key >> 5)] >> (key & 31)) & 1u;
      float val = bit ? ((causal && key > row) ? s - 10000.f : s) : -10000.f;
      pv[kk] = val;
      mymax = fmaxf(mymax, val);
    }
    for (int xx = 1; xx < 64; xx <<= 1) mymax = fmaxf(mymax, __shfl_xor(mymax, xx));
    if (lane == 0) red[wv] = mymax;
    __syncthreads();
    const float M = fmaxf(fmaxf(red[0], red[1]), fmaxf(red[2], red[3]));

    float sum = 0.f;
    #pragma unroll
    for (int kk = 0; kk < 16; ++kk) {
      float p = fexp2((pv[kk] - M) * L2E);
      ps[tid * 16 + kk] = p;
      sum += p;
    }
    for (int xx = 1; xx < 64; xx <<= 1) sum += __shfl_xor(sum, xx);
    if (lane == 0) red[8 + wv] = sum;
    __syncthreads();
    const float L = red[8] + red[9] + red[10] + red[11];

    const int d = tid >> 2, qq = tid & 3;
    float acc = 0.f;
    for (int jb = qq * 1024; jb < qq * 1024 + 1024; jb += 8) {
      bf16x8 vv8 = *(const bf16x8*)&vt[(size_t)(h * 64 + d) * 4096 + jb];
      #pragma unroll
      for (int e = 0; e < 8; ++e)
        acc += ps[jb + e] * bf2f((unsigned short)vv8[e]);
    }
    acc += __shfl_xor(acc, 1);
    acc += __shfl_xor(acc, 2);
    if (qq == 0)
      scr[(size_t)h * 262144 + (size_t)d * 4096 + row] = f2bf(acc / L);
  }
}

// -------------------- launch --------------------

extern "C" void kernel_launch(void* const* d_in, const int* in_sizes, int n_in,
                              void* d_out, int out_size, void* d_ws, size_t ws_size,
                              hipStream_t stream) {
  const float* q = (const float*)d_in[0];
  const float* k = (const float*)d_in[1];
  const float* v = (const float*)d_in[2];
  const int* attn_mask = (const int*)d_in[3];
  const int* mask_future = (const int*)d_in[4];
  const float* W_qkv = (const float*)d_in[5];
  const float* W_out = (const float*)d_in[6];
  float* out = (float*)d_out;

  char* ws = (char*)d_ws;
  unsigned short* xb    = (unsigned short*)(ws);            // [0,18.87M) live until qkv GEMM
  unsigned short* vt    = (unsigned short*)(ws);            // [0,6.29M) after tv_rowflag
  char*           ctl   = ws + 6291456;                     // 4KB, memset AFTER gemm
  int*            cnt   = (int*)(ctl + 256);
  int*            list  = (int*)(ctl + 1024);               // [64]
  float*          parts = (float*)(ws + 6295552);           // 1296*4224*4 = 21.90MB
  unsigned short* wqkvb = (unsigned short*)(ws + 18874368); // dead after qkv GEMM
  unsigned short* qkvb  = (unsigned short*)(ws + 29491200);
  unsigned*       maskw = (unsigned*)(ws + 48365568);
  unsigned short* scr   = (unsigned short*)(ws + 50462720);
  unsigned short* woutb = (unsigned short*)(ws + 56754176);
  if (ws_size < 57933824) return;

  pack_all<<<9536, 256, 0, stream>>>(q, k, v, W_qkv, W_out, attn_mask,
                                     xb, wqkvb, woutb, maskw);
  gemm_bt<unsigned short, 3><<<dim3(32, 24), 256, 0, stream>>>(xb, wqkvb, qkvb, 4096, 2304, 2304);
  hipMemsetAsync(ctl, 0, 4096, stream);   // AFTER gemm: xb dead (R6 lesson)
  tv_rowflag<<<1024, 256, 0, stream>>>(qkvb, vt, maskw, mask_future, cnt, list);
  attn_kernel<<<1024, 256, 0, stream>>>(qkvb, vt, maskw, mask_future, parts, scr);
  merge_fix<<<1200, 256, 0, stream>>>(parts, qkvb, vt, maskw, mask_future, cnt, list, scr);
  gemm_bt<float, 1><<<dim3(32, 24), 256, 0, stream>>>(scr, woutb, out, 4096, 768, 768);
}

// Round 19
// 163.151 us; speedup vs baseline: 2.0010x; 1.1268x over previous
//
#include <hip/hip_runtime.h>

// ---------------------------------------------------------------------------
// FastMultiHeadAttention on MI355X (gfx950)
// Round 19: R18 (183.8us) + T2 XOR-swizzle on gemm_bt's LDS tiles. The QKV
// GEMM is now the top dispatch (72us, SQ_LDS_BANK_CONFLICT=1.86e7): As/Bs
// ds_read_b128 at row-stride 128B is a 16-way conflict. Apply the identical
// pre-swizzled-source + swizzled-read pattern the attention kernel has used
// (verified) since R2: stage cb^=row&7, read col^=(row&7)<<3. Everything
// else unchanged.
// ---------------------------------------------------------------------------

typedef __attribute__((ext_vector_type(8))) short bf16x8;
typedef __attribute__((ext_vector_type(4))) float f32x4;
typedef __attribute__((ext_vector_type(4))) unsigned short us4;

#define KNEG -15000.0f              // masked logit in log2 units; exp2 -> 0
#define CEXP 0.18033688011112042f   // 0.125 * log2(e)
#define L2E  1.4426950408889634f

__device__ __forceinline__ unsigned short f2bf(float f) {
  union { float f; unsigned u; } x; x.f = f;
  unsigned r = x.u + 0x7fffu + ((x.u >> 16) & 1u);
  return (unsigned short)(r >> 16);
}

__device__ __forceinline__ float bf2f(unsigned short u) {
  union { unsigned u; float f; } x; x.u = (unsigned)u << 16;
  return x.f;
}

__device__ __forceinline__ float fexp2(float x) {
  return __builtin_amdgcn_exp2f(x);
}

__device__ __forceinline__ void load_lds16(const void* g, void* l) {
  __builtin_amdgcn_global_load_lds(
      (const __attribute__((address_space(1))) void*)g,
      (__attribute__((address_space(3))) void*)l, 16, 0, 0);
}

// -------------------- fused pack kernel --------------------

__device__ __forceinline__ void pack8(const float* __restrict__ src,
                                      unsigned short* __restrict__ dst) {
  const float4* p = (const float4*)src;
  float4 a = p[0], b = p[1];
  bf16x8 o;
  o[0] = (short)f2bf(a.x); o[1] = (short)f2bf(a.y);
  o[2] = (short)f2bf(a.z); o[3] = (short)f2bf(a.w);
  o[4] = (short)f2bf(b.x); o[5] = (short)f2bf(b.y);
  o[6] = (short)f2bf(b.z); o[7] = (short)f2bf(b.w);
  *(bf16x8*)dst = o;
}

__global__ __launch_bounds__(256) void pack_all(
    const float* __restrict__ q, const float* __restrict__ k,
    const float* __restrict__ v, const float* __restrict__ W_qkv,
    const float* __restrict__ W_out, const int* __restrict__ mask,
    unsigned short* __restrict__ xb, unsigned short* __restrict__ wqkvb,
    unsigned short* __restrict__ woutb, unsigned* __restrict__ maskw) {
  const int b = blockIdx.x;
  const int tid = threadIdx.x;
  if (b < 4608) {
    int idx = b * 256 + tid;
    int t = idx / 288;
    int c2 = (idx - t * 288) * 8;
    const float* src;
    int c;
    if (c2 < 768)       { src = q; c = c2; }
    else if (c2 < 1536) { src = k; c = c2 - 768; }
    else                { src = v; c = c2 - 1536; }
    pack8(src + (size_t)t * 768 + c, xb + (size_t)t * 2304 + c2);
  } else if (b < 7200) {
    int idx = (b - 4608) * 256 + tid;
    pack8(W_qkv + (size_t)idx * 8, wqkvb + (size_t)idx * 8);
  } else if (b < 7488) {
    int idx = (b - 7200) * 256 + tid;
    pack8(W_out + (size_t)idx * 8, woutb + (size_t)idx * 8);
  } else {
    int lane = tid & 63;
    int wid0 = ((b - 7488) * 256 + tid) >> 6;
    for (int wid = wid0; wid < 262144; wid += 8192) {
      int row = wid >> 6;
      int wp = wid & 63;
      int s = wp * 64 + lane;
      int mval = mask[(size_t)row * 4096 + s];
      unsigned long long bb = __ballot(mval != 0);
      if (lane == 0) {
        maskw[row * 128 + wp * 2]     = (unsigned)bb;
        maskw[row * 128 + wp * 2 + 1] = (unsigned)(bb >> 32);
      }
    }
  }
}

// -------- fused: transposeV (blocks 0..767) + rowflag (blocks 768..1023) ---

__global__ __launch_bounds__(256) void tv_rowflag(
    const unsigned short* __restrict__ qkvb, unsigned short* __restrict__ vt,
    const unsigned* __restrict__ maskw, const int* __restrict__ mask_future,
    int* __restrict__ cnt, int* __restrict__ list) {
  const int b = blockIdx.x;
  const int tid = threadIdx.x;
  if (b < 768) {
    __shared__ unsigned short tl[64][65];
    const int t0 = (b & 63) * 64;
    const int hsrc = (b >> 6) * 192 + 128;
    for (int pass = 0; pass < 2; ++pass) {
      int r = (tid >> 3) + pass * 32;
      int fc = (tid & 7) * 8;
      bf16x8 vv = *(const bf16x8*)&qkvb[(size_t)(t0 + r) * 2304 + hsrc + fc];
      for (int e = 0; e < 8; ++e) tl[fc + e][r] = (unsigned short)vv[e];
    }
    __syncthreads();
    const int f = tid >> 2;
    const int sg = (tid & 3) * 16;
    for (int j = 0; j < 2; ++j) {
      bf16x8 o;
      for (int e = 0; e < 8; ++e) o[e] = (short)tl[f][sg + j * 8 + e];
      *(bf16x8*)&vt[(size_t)((b >> 6) * 64 + f) * 4096 + t0 + sg + j * 8] = o;
    }
  } else {
    const bool causal = (mask_future[0] != 0);
    int wv = ((b - 768) * 256 + tid) >> 6;  // 0..1023
    int lane = tid & 63;
    for (int row = wv * 4; row < wv * 4 + 4; ++row) {
      unsigned acc = 0;
      int jmax = causal ? (row >> 5) : 127;
      for (int j = lane; j <= jmax; j += 64) {
        unsigned wb = maskw[row * 128 + j];
        if (causal && j == jmax) {
          int rem = row & 31;
          wb &= (rem == 31) ? 0xffffffffu : ((2u << rem) - 1u);
        }
        acc |= wb;
      }
      if (!__any(acc != 0)) {
        if (lane == 0) {
          int i = atomicAdd(cnt, 1);
          if (i < 64) list[i] = row;
        }
      }
    }
  }
}

// ------------- GEMM: C[M][N] = A[M][K] * B[N][K]^T, BM=128, BN=NF*32 -------
// T2: LDS tiles stored with chunk-swizzle (cb ^= row&7 via pre-swizzled
// global source), fragments read with col ^= (row&7)<<3. Conflict-free
// ds_read_b128 (same verified pattern as attn's Klds/Vs).

__device__ __forceinline__ void storeC(float* p, float v) { *p = v; }
__device__ __forceinline__ void storeC(unsigned short* p, float v) { *p = f2bf(v); }

template <typename OutT, int NF>
__global__ __launch_bounds__(256) void gemm_bt(const unsigned short* __restrict__ A,
                                               const unsigned short* __restrict__ B,
                                               OutT* __restrict__ C,
                                               int M, int N, int K) {
  constexpr int BN = NF * 32;
  __shared__ unsigned short As[128 * 64];
  __shared__ unsigned short Bs[BN * 64];
  const int tid = threadIdx.x;
  const int lane = tid & 63;
  const int w = tid >> 6;
  const int wr = w >> 1, wc = w & 1;
  const int l15 = lane & 15, lhi = lane >> 4;

  int lblk = blockIdx.y * gridDim.x + blockIdx.x;
  int nwg = gridDim.x * gridDim.y;
  int sw = (lblk & 7) * (nwg >> 3) + (lblk >> 3);
  int bxg = sw % gridDim.x;
  int byg = sw / gridDim.x;

  const size_t abase = (size_t)(bxg * 128) * K;
  const size_t bbase = (size_t)(byg * BN) * K;

  f32x4 acc[4][NF] = {};

  for (int k0 = 0; k0 < K; k0 += 64) {
    __syncthreads();
    #pragma unroll
    for (int i = 0; i < 4; ++i) {
      int c = (w << 8) + (i << 6) + lane;
      int row = c >> 3, cb = (c & 7) ^ (row & 7);
      load_lds16(A + abase + (size_t)row * K + k0 + cb * 8, &As[c * 8]);
    }
    #pragma unroll
    for (int i = 0; i < NF; ++i) {
      int c = w * (NF * 64) + (i << 6) + lane;
      int row = c >> 3, cb = (c & 7) ^ (row & 7);
      load_lds16(B + bbase + (size_t)row * K + k0 + cb * 8, &Bs[c * 8]);
    }
    __syncthreads();
    #pragma unroll
    for (int kk = 0; kk < 2; ++kk) {
      bf16x8 af[4], bfr[NF];
      #pragma unroll
      for (int m = 0; m < 4; ++m) {
        int ra = wr * 64 + m * 16 + l15;
        int col = (kk * 32 + lhi * 8) ^ ((ra & 7) << 3);
        af[m] = *(const bf16x8*)&As[ra * 64 + col];
      }
      #pragma unroll
      for (int n = 0; n < NF; ++n) {
        int rb = wc * NF * 16 + n * 16 + l15;
        int col = (kk * 32 + lhi * 8) ^ ((rb & 7) << 3);
        bfr[n] = *(const bf16x8*)&Bs[rb * 64 + col];
      }
      #pragma unroll
      for (int m = 0; m < 4; ++m)
        #pragma unroll
        for (int n = 0; n < NF; ++n)
          acc[m][n] = __builtin_amdgcn_mfma_f32_16x16x32_bf16(af[m], bfr[n], acc[m][n], 0, 0, 0);
    }
  }

  #pragma unroll
  for (int m = 0; m < 4; ++m) {
    int row0 = bxg * 128 + wr * 64 + m * 16 + lhi * 4;
    #pragma unroll
    for (int n = 0; n < NF; ++n) {
      int col = byg * BN + wc * NF * 16 + n * 16 + l15;
      #pragma unroll
      for (int r = 0; r < 4; ++r)
        storeC(&C[(size_t)(row0 + r) * N + col], acc[m][n][r]);
    }
  }
}

// ------------ attention (R18 body, static schedule, 5 blocks/CU) -----------

__global__ __launch_bounds__(256) void attn_kernel(
    const unsigned short* __restrict__ qkv,  // [4096][2304] bf16
    const unsigned short* __restrict__ vt,   // [768][4096] bf16 V^T
    const unsigned* __restrict__ maskw,      // [4096][128]
    const int* __restrict__ mask_future,
    float* __restrict__ parts,               // [1296][4224] f32 (O|l)
    unsigned short* __restrict__ scr) {      // scrambled [4096*768] bf16
  const int tid = threadIdx.x;
  const int lane = tid & 63;
  const int w = tid >> 6;
  const int l15 = lane & 15, lhi = lane >> 4;
  const bool causal = (mask_future[0] != 0);
  const int srcA = l15 + (((2 * lhi) & 3) << 4);
  const int srcB = l15 + (((2 * lhi + 1) & 3) << 4);
  const int hi2 = lhi >> 1;
  const int blk = blockIdx.x;

  // all-ones bf16 B-fragment for row-sum MFMA
  union { bf16x8 v; unsigned u[4]; } onesf;
  #pragma unroll
  for (int i = 0; i < 4; ++i) onesf.u[i] = 0x3F803F80u;

  __shared__ unsigned short Klds[2][64 * 64];  // [key][d], swizzled
  __shared__ unsigned short Vs[2][64 * 64];    // [d][key], swizzled
  // total shared = 32768B exactly -> 5 blocks/CU

  // per-lane staging geometry (item-invariant)
  int srow[2], scb[2];
  #pragma unroll
  for (int i = 0; i < 2; ++i) {
    int cc = (w << 7) + (i << 6) + lane;
    srow[i] = cc >> 3;
    scb[i] = ((cc & 7) ^ (srow[i] & 7)) * 8;
  }

  for (int s = 0; s < 2; ++s) {
    int idx;
    if (s == 0) idx = blk;
    else if (blk >= 752) idx = 1024 + (1023 - blk);
    else break;

    __syncthreads();  // previous item's LDS reads complete before restage

    int c, bx, h;
    if (idx < 444)      { c = 0; bx = 63 - idx / 12; h = idx % 12; }
    else if (idx < 552) { int j = idx - 444; c = 1; bx = 63 - j / 12; h = j % 12; }
    else if (idx < 1008) {
      int j = idx - 552; int L = 27 - j / 24; int u = j % 24;
      c = (u < 12) ? 1 : 0; bx = c ? (27 + L) : (L - 1); h = u % 12;
    } else {
      int j = idx - 1008; int L = 8 - j / 36; int u = j % 36;
      c = (u < 12) ? 2 : ((u < 24) ? 1 : 0);
      bx = (c == 2) ? (55 + L) : ((c == 1) ? (27 + L) : (L - 1)); h = u % 12;
    }

    int t0c, t1c, diag;
    bool split;
    if (causal) {
      t0c = c * 28;
      t1c = min(t0c + 28, bx + 1);
      diag = bx;
      split = (bx >= 28);
    } else {  // non-causal: c=0 items do the whole range, others skip
      if (c != 0) continue;
      t0c = 0; t1c = 64; diag = 64; split = false;
    }
    const int hoff = h * 192;
    const int l0 = bx << 6;
    const int lq = l0 + w * 16 + l15;

    // hoisted staging base pointers (advance by tile)
    const unsigned short* kb[2];
    const unsigned short* vb[2];
    #pragma unroll
    for (int i = 0; i < 2; ++i) {
      kb[i] = qkv + (size_t)(t0c * 64 + srow[i]) * 2304 + hoff + 64 + scb[i];
      vb[i] = vt + (size_t)(h * 64 + srow[i]) * 4096 + t0c * 64 + scb[i];
    }

    // Q B-fragments, pre-scaled by CEXP (logits emerge in log2 units)
    bf16x8 qf[2];
    {
      const unsigned short* qp = qkv + (size_t)lq * 2304 + hoff;
      qf[0] = *(const bf16x8*)(qp + lhi * 8);
      qf[1] = *(const bf16x8*)(qp + 32 + lhi * 8);
      #pragma unroll
      for (int i = 0; i < 2; ++i) {
        union { bf16x8 v; unsigned u[4]; } qa; qa.v = qf[i];
        #pragma unroll
        for (int p = 0; p < 4; ++p) {
          float lo = bf2f((unsigned short)(qa.u[p] & 0xffff)) * CEXP;
          float hi = bf2f((unsigned short)(qa.u[p] >> 16)) * CEXP;
          asm("v_cvt_pk_bf16_f32 %0, %1, %2" : "=v"(qa.u[p]) : "v"(lo), "v"(hi));
        }
        qf[i] = qa.v;
      }
    }
    // prologue: stage tile t0c -> buf 0
    #pragma unroll
    for (int i = 0; i < 2; ++i) {
      int cc = (w << 7) + (i << 6) + lane;
      load_lds16(kb[i], &Klds[0][cc * 8]);
      load_lds16(vb[i], &Vs[0][cc * 8]);
    }
    const unsigned* mrow_p = maskw + lq * 128;
    uint2 mk_next = *(const uint2*)(mrow_p + t0c * 2);

    f32x4 oacc[4] = {};
    f32x4 osum = {};  // row sums of P, rows = w*16 + lhi*4 + r
    int cur = 0;

    for (int it = t0c; it < t1c; ++it) {
      __syncthreads();  // drains stage(it); protects buf reuse

      if (it + 1 < t1c) {
        #pragma unroll
        for (int i = 0; i < 2; ++i) {
          kb[i] += 64 * 2304;
          vb[i] += 64;
          int cc = (w << 7) + (i << 6) + lane;
          load_lds16(kb[i], &Klds[cur ^ 1][cc * 8]);
          load_lds16(vb[i], &Vs[cur ^ 1][cc * 8]);
        }
      }
      uint2 mk = mk_next;
      if (it + 1 < t1c) mk_next = *(const uint2*)(mrow_p + (it + 1) * 2);

      const int s0 = it * 64;

      // S^T (log2 units) = mfma(A=K, B=Q·CEXP); lane: S[q=lq][k=s0+n*16+lhi*4+r]
      f32x4 sacc[4] = {};
      __builtin_amdgcn_s_setprio(1);
      #pragma unroll
      for (int kk = 0; kk < 2; ++kk) {
        bf16x8 kf[4];
        #pragma unroll
        for (int n = 0; n < 4; ++n) {
          int rk = n * 16 + l15;
          int col = (kk * 32 + lhi * 8) ^ ((rk & 7) << 3);
          kf[n] = *(const bf16x8*)&Klds[cur][rk * 64 + col];
        }
        #pragma unroll
        for (int n = 0; n < 4; ++n)
          sacc[n] = __builtin_amdgcn_mfma_f32_16x16x32_bf16(kf[n], qf[kk], sacc[n], 0, 0, 0);
      }
      __builtin_amdgcn_s_setprio(0);

      // masked logits -> p = exp2(logit); masked -> exp2(KNEG) = 0
      float vals[4][4];
      {
        unsigned a = mk.x >> (lhi * 4);
        unsigned b = mk.y >> (lhi * 4);
        if (it < diag) {
          #pragma unroll
          for (int n = 0; n < 4; ++n) {
            unsigned wsh = ((n < 2) ? a : b) >> ((n & 1) << 4);
            #pragma unroll
            for (int r = 0; r < 4; ++r)
              vals[n][r] = ((wsh >> r) & 1u) ? sacc[n][r] : KNEG;
          }
        } else {  // diagonal tile
          #pragma unroll
          for (int n = 0; n < 4; ++n) {
            unsigned wsh = ((n < 2) ? a : b) >> ((n & 1) << 4);
            int kb2 = s0 + n * 16 + lhi * 4;
            #pragma unroll
            for (int r = 0; r < 4; ++r) {
              float vv = (kb2 + r > lq) ? KNEG : sacc[n][r];
              vals[n][r] = ((wsh >> r) & 1u) ? vv : KNEG;
            }
          }
        }
      }

      #pragma unroll
      for (int n = 0; n < 4; ++n)
        #pragma unroll
        for (int r = 0; r < 4; ++r)
          vals[n][r] = fexp2(vals[n][r]);

      // pack P to bf16 pairs
      unsigned pk[4][2];
      #pragma unroll
      for (int n = 0; n < 4; ++n)
        #pragma unroll
        for (int rp = 0; rp < 2; ++rp)
          asm("v_cvt_pk_bf16_f32 %0, %1, %2"
              : "=v"(pk[n][rp])
              : "v"(vals[n][2 * rp]), "v"(vals[n][2 * rp + 1]));

      // PV + row-sum (ones-vector MFMA shares the A fragment)
      #pragma unroll
      for (int kk = 0; kk < 2; ++kk) {
        unsigned a0 = __shfl(pk[2 * kk][0], srcA);
        unsigned a1 = __shfl(pk[2 * kk][1], srcA);
        unsigned a2 = __shfl(pk[2 * kk][0], srcB);
        unsigned a3 = __shfl(pk[2 * kk][1], srcB);
        unsigned b0 = __shfl(pk[2 * kk + 1][0], srcA);
        unsigned b1 = __shfl(pk[2 * kk + 1][1], srcA);
        unsigned b2 = __shfl(pk[2 * kk + 1][0], srcB);
        unsigned b3 = __shfl(pk[2 * kk + 1][1], srcB);
        union { bf16x8 v; unsigned u[4]; } af;
        af.u[0] = hi2 ? b0 : a0;
        af.u[1] = hi2 ? b1 : a1;
        af.u[2] = hi2 ? b2 : a2;
        af.u[3] = hi2 ? b3 : a3;
        __builtin_amdgcn_s_setprio(1);
        osum = __builtin_amdgcn_mfma_f32_16x16x32_bf16(af.v, onesf.v, osum, 0, 0, 0);
        #pragma unroll
        for (int n = 0; n < 4; ++n) {
          int rv = n * 16 + l15;
          int col = (kk * 32 + lhi * 8) ^ ((rv & 7) << 3);
          bf16x8 vf = *(const bf16x8*)&Vs[cur][rv * 64 + col];
          oacc[n] = __builtin_amdgcn_mfma_f32_16x16x32_bf16(af.v, vf, oacc[n], 0, 0, 0);
        }
        __builtin_amdgcn_s_setprio(0);
      }
      cur ^= 1;
    }

    // ---------- finalize (osum[r] already in (lhi,r) row layout) ----------
    const int row0 = w * 16 + lhi * 4;

    if (split) {
      int prefix = bx + max(bx - 28, 0) + max(bx - 56, 0);
      float* pg = parts + (size_t)((prefix + c) * 12 + h) * 4224;
      #pragma unroll
      for (int n = 0; n < 4; ++n)
        #pragma unroll
        for (int r = 0; r < 4; ++r)
          pg[(size_t)(row0 + r) * 64 + n * 16 + l15] = oacc[n][r];
      if (l15 == 0) {
        #pragma unroll
        for (int r = 0; r < 4; ++r)
          pg[4096 + row0 + r] = osum[r];
      }
    } else {
      float rq[4];
      #pragma unroll
      for (int r = 0; r < 4; ++r) rq[r] = 1.0f / osum[r];
      #pragma unroll
      for (int n = 0; n < 4; ++n) {
        int d = n * 16 + l15;
        size_t base = (size_t)h * 262144 + (size_t)d * 4096 + (size_t)(l0 + row0);
        us4 o;
        #pragma unroll
        for (int r = 0; r < 4; ++r) o[r] = f2bf(oacc[n][r] * rq[r]);
        *(us4*)(scr + base) = o;
      }
    }
  }
}

// -------- fused: merge_k (blocks 0..431) + fixrows (blocks 432..1199) ------

__global__ __launch_bounds__(256) void merge_fix(
    const float* __restrict__ parts, const unsigned short* __restrict__ qkv,
    const unsigned short* __restrict__ vt, const unsigned* __restrict__ maskw,
    const int* __restrict__ mask_future, const int* __restrict__ cnt,
    const int* __restrict__ list, unsigned short* __restrict__ scr) {
  const int b = blockIdx.x;
  const bool causal = (mask_future[0] != 0);
  if (b < 432) {
    if (!causal) return;  // non-causal: no splits
    const int sg = b;
    const int bx = 28 + sg / 12;
    const int h = sg % 12;
    const int nch = 2 + (bx >= 56);
    const int prefix = bx + max(bx - 28, 0) + max(bx - 56, 0);
    const int t = threadIdx.x;
    const int row = t >> 2;
    const int dg = (t & 3) * 16;

    const float* pg[3];
    for (int cc = 0; cc < 3; ++cc)
      pg[cc] = parts + (size_t)((prefix + min(cc, nch - 1)) * 12 + h) * 4224;

    float L = pg[0][4096 + row] + pg[1][4096 + row];
    if (nch == 3) L += pg[2][4096 + row];
    if (L == 0.f) return;  // degenerate row: fixrows owns it (no race)
    float rL = 1.0f / L;

    #pragma unroll
    for (int dd = 0; dd < 16; ++dd) {
      int d = dg + dd;
      float o = pg[0][(size_t)row * 64 + d] + pg[1][(size_t)row * 64 + d];
      if (nch == 3) o += pg[2][(size_t)row * 64 + d];
      scr[(size_t)h * 262144 + (size_t)d * 4096 + bx * 64 + row] = f2bf(o * rL);
    }
  } else {
    const int bb = b - 432;
    const int i = bb / 12;
    const int h = bb % 12;
    int n = *cnt; if (n > 64) n = 64;
    if (i >= n) return;
    const int row = list[i];
    const int tid = threadIdx.x;
    const int lane = tid & 63;
    const int wv = tid >> 6;

    __shared__ float qs[64];
    __shared__ float ps[4096];
    __shared__ float red[16];

    if (tid < 64) qs[tid] = bf2f(qkv[(size_t)row * 2304 + h * 192 + tid]);
    __syncthreads();

    float pv[16];
    float mymax = -INFINITY;
    #pragma unroll
    for (int kk = 0; kk < 16; ++kk) {
      int key = tid * 16 + kk;
      const unsigned short* kp = qkv + (size_t)key * 2304 + h * 192 + 64;
      float s = 0.f;
      #pragma unroll
      for (int d8 = 0; d8 < 8; ++d8) {
        bf16x8 kv8 = *(const bf16x8*)(kp + d8 * 8);
        #pragma unroll
        for (int e = 0; e < 8; ++e)
          s += qs[d8 * 8 + e] * bf2f((unsigned short)kv8[e]);
      }
      s *= 0.125f;
      unsigned bit = (maskw[row * 128 + (key >> 5)] >> (key & 31)) & 1u;
      float val = bit ? ((causal && key > row) ? s - 10000.f : s) : -10000.f;
      pv[kk] = val;
      mymax = fmaxf(mymax, val);
    }
    for (int xx = 1; xx < 64; xx <<= 1) mymax = fmaxf(mymax, __shfl_xor(mymax, xx));
    if (lane == 0) red[wv] = mymax;
    __syncthreads();
    const float M = fmaxf(fmaxf(red[0], red[1]), fmaxf(red[2], red[3]));

    float sum = 0.f;
    #pragma unroll
    for (int kk = 0; kk < 16; ++kk) {
      float p = fexp2((pv[kk] - M) * L2E);
      ps[tid * 16 + kk] = p;
      sum += p;
    }
    for (int xx = 1; xx < 64; xx <<= 1) sum += __shfl_xor(sum, xx);
    if (lane == 0) red[8 + wv] = sum;
    __syncthreads();
    const float L = red[8] + red[9] + red[10] + red[11];

    const int d = tid >> 2, qq = tid & 3;
    float acc = 0.f;
    for (int jb = qq * 1024; jb < qq * 1024 + 1024; jb += 8) {
      bf16x8 vv8 = *(const bf16x8*)&vt[(size_t)(h * 64 + d) * 4096 + jb];
      #pragma unroll
      for (int e = 0; e < 8; ++e)
        acc += ps[jb + e] * bf2f((unsigned short)vv8[e]);
    }
    acc += __shfl_xor(acc, 1);
    acc += __shfl_xor(acc, 2);
    if (qq == 0)
      scr[(size_t)h * 262144 + (size_t)d * 4096 + row] = f2bf(acc / L);
  }
}

// -------------------- launch --------------------

extern "C" void kernel_launch(void* const* d_in, const int* in_sizes, int n_in,
                              void* d_out, int out_size, void* d_ws, size_t ws_size,
                              hipStream_t stream) {
  const float* q = (const float*)d_in[0];
  const float* k = (const float*)d_in[1];
  const float* v = (const float*)d_in[2];
  const int* attn_mask = (const int*)d_in[3];
  const int* mask_future = (const int*)d_in[4];
  const float* W_qkv = (const float*)d_in[5];
  const float* W_out = (const float*)d_in[6];
  float* out = (float*)d_out;

  char* ws = (char*)d_ws;
  unsigned short* xb    = (unsigned short*)(ws);            // [0,18.87M) live until qkv GEMM
  unsigned short* vt    = (unsigned short*)(ws);            // [0,6.29M) after tv_rowflag
  char*           ctl   = ws + 6291456;                     // 4KB, memset AFTER gemm
  int*            cnt   = (int*)(ctl + 256);
  int*            list  = (int*)(ctl + 1024);               // [64]
  float*          parts = (float*)(ws + 6295552);           // 1296*4224*4 = 21.90MB
  unsigned short* wqkvb = (unsigned short*)(ws + 18874368); // dead after qkv GEMM
  unsigned short* qkvb  = (unsigned short*)(ws + 29491200);
  unsigned*       maskw = (unsigned*)(ws + 48365568);
  unsigned short* scr   = (unsigned short*)(ws + 50462720);
  unsigned short* woutb = (unsigned short*)(ws + 56754176);
  if (ws_size < 57933824) return;

  pack_all<<<9536, 256, 0, stream>>>(q, k, v, W_qkv, W_out, attn_mask,
                                     xb, wqkvb, woutb, maskw);
  gemm_bt<unsigned short, 3><<<dim3(32, 24), 256, 0, stream>>>(xb, wqkvb, qkvb, 4096, 2304, 2304);
  hipMemsetAsync(ctl, 0, 4096, stream);   // AFTER gemm: xb dead (R6 lesson)
  tv_rowflag<<<1024, 256, 0, stream>>>(qkvb, vt, maskw, mask_future, cnt, list);
  attn_kernel<<<1024, 256, 0, stream>>>(qkvb, vt, maskw, mask_future, parts, scr);
  merge_fix<<<1200, 256, 0, stream>>>(parts, qkvb, vt, maskw, mask_future, cnt, list, scr);
  gemm_bt<float, 1><<<dim3(32, 24), 256, 0, stream>>>(scr, woutb, out, 4096, 768, 768);
}

// Round 20
// 162.935 us; speedup vs baseline: 2.0036x; 1.0013x over previous
//
#include <hip/hip_runtime.h>

// ---------------------------------------------------------------------------
// FastMultiHeadAttention on MI355X (gfx950)
// Round 20: R19 (163.2us) + attn grid 1024->1280 blocks (5/CU, the LDS-32KB
// capacity unlocked in R18 but left unfilled by the 1024-block grid).
// Static longest-first mapping: block b -> item b; blocks 1264..1279 also
// take tail item 1280+(1279-b) (the 16 len-1 items). Makespan unchanged;
// +25% resident TLP. Everything else identical to R19.
// ---------------------------------------------------------------------------

typedef __attribute__((ext_vector_type(8))) short bf16x8;
typedef __attribute__((ext_vector_type(4))) float f32x4;
typedef __attribute__((ext_vector_type(4))) unsigned short us4;

#define KNEG -15000.0f              // masked logit in log2 units; exp2 -> 0
#define CEXP 0.18033688011112042f   // 0.125 * log2(e)
#define L2E  1.4426950408889634f

__device__ __forceinline__ unsigned short f2bf(float f) {
  union { float f; unsigned u; } x; x.f = f;
  unsigned r = x.u + 0x7fffu + ((x.u >> 16) & 1u);
  return (unsigned short)(r >> 16);
}

__device__ __forceinline__ float bf2f(unsigned short u) {
  union { unsigned u; float f; } x; x.u = (unsigned)u << 16;
  return x.f;
}

__device__ __forceinline__ float fexp2(float x) {
  return __builtin_amdgcn_exp2f(x);
}

__device__ __forceinline__ void load_lds16(const void* g, void* l) {
  __builtin_amdgcn_global_load_lds(
      (const __attribute__((address_space(1))) void*)g,
      (__attribute__((address_space(3))) void*)l, 16, 0, 0);
}

// -------------------- fused pack kernel --------------------

__device__ __forceinline__ void pack8(const float* __restrict__ src,
                                      unsigned short* __restrict__ dst) {
  const float4* p = (const float4*)src;
  float4 a = p[0], b = p[1];
  bf16x8 o;
  o[0] = (short)f2bf(a.x); o[1] = (short)f2bf(a.y);
  o[2] = (short)f2bf(a.z); o[3] = (short)f2bf(a.w);
  o[4] = (short)f2bf(b.x); o[5] = (short)f2bf(b.y);
  o[6] = (short)f2bf(b.z); o[7] = (short)f2bf(b.w);
  *(bf16x8*)dst = o;
}

__global__ __launch_bounds__(256) void pack_all(
    const float* __restrict__ q, const float* __restrict__ k,
    const float* __restrict__ v, const float* __restrict__ W_qkv,
    const float* __restrict__ W_out, const int* __restrict__ mask,
    unsigned short* __restrict__ xb, unsigned short* __restrict__ wqkvb,
    unsigned short* __restrict__ woutb, unsigned* __restrict__ maskw) {
  const int b = blockIdx.x;
  const int tid = threadIdx.x;
  if (b < 4608) {
    int idx = b * 256 + tid;
    int t = idx / 288;
    int c2 = (idx - t * 288) * 8;
    const float* src;
    int c;
    if (c2 < 768)       { src = q; c = c2; }
    else if (c2 < 1536) { src = k; c = c2 - 768; }
    else                { src = v; c = c2 - 1536; }
    pack8(src + (size_t)t * 768 + c, xb + (size_t)t * 2304 + c2);
  } else if (b < 7200) {
    int idx = (b - 4608) * 256 + tid;
    pack8(W_qkv + (size_t)idx * 8, wqkvb + (size_t)idx * 8);
  } else if (b < 7488) {
    int idx = (b - 7200) * 256 + tid;
    pack8(W_out + (size_t)idx * 8, woutb + (size_t)idx * 8);
  } else {
    int lane = tid & 63;
    int wid0 = ((b - 7488) * 256 + tid) >> 6;
    for (int wid = wid0; wid < 262144; wid += 8192) {
      int row = wid >> 6;
      int wp = wid & 63;
      int s = wp * 64 + lane;
      int mval = mask[(size_t)row * 4096 + s];
      unsigned long long bb = __ballot(mval != 0);
      if (lane == 0) {
        maskw[row * 128 + wp * 2]     = (unsigned)bb;
        maskw[row * 128 + wp * 2 + 1] = (unsigned)(bb >> 32);
      }
    }
  }
}

// -------- fused: transposeV (blocks 0..767) + rowflag (blocks 768..1023) ---

__global__ __launch_bounds__(256) void tv_rowflag(
    const unsigned short* __restrict__ qkvb, unsigned short* __restrict__ vt,
    const unsigned* __restrict__ maskw, const int* __restrict__ mask_future,
    int* __restrict__ cnt, int* __restrict__ list) {
  const int b = blockIdx.x;
  const int tid = threadIdx.x;
  if (b < 768) {
    __shared__ unsigned short tl[64][65];
    const int t0 = (b & 63) * 64;
    const int hsrc = (b >> 6) * 192 + 128;
    for (int pass = 0; pass < 2; ++pass) {
      int r = (tid >> 3) + pass * 32;
      int fc = (tid & 7) * 8;
      bf16x8 vv = *(const bf16x8*)&qkvb[(size_t)(t0 + r) * 2304 + hsrc + fc];
      for (int e = 0; e < 8; ++e) tl[fc + e][r] = (unsigned short)vv[e];
    }
    __syncthreads();
    const int f = tid >> 2;
    const int sg = (tid & 3) * 16;
    for (int j = 0; j < 2; ++j) {
      bf16x8 o;
      for (int e = 0; e < 8; ++e) o[e] = (short)tl[f][sg + j * 8 + e];
      *(bf16x8*)&vt[(size_t)((b >> 6) * 64 + f) * 4096 + t0 + sg + j * 8] = o;
    }
  } else {
    const bool causal = (mask_future[0] != 0);
    int wv = ((b - 768) * 256 + tid) >> 6;  // 0..1023
    int lane = tid & 63;
    for (int row = wv * 4; row < wv * 4 + 4; ++row) {
      unsigned acc = 0;
      int jmax = causal ? (row >> 5) : 127;
      for (int j = lane; j <= jmax; j += 64) {
        unsigned wb = maskw[row * 128 + j];
        if (causal && j == jmax) {
          int rem = row & 31;
          wb &= (rem == 31) ? 0xffffffffu : ((2u << rem) - 1u);
        }
        acc |= wb;
      }
      if (!__any(acc != 0)) {
        if (lane == 0) {
          int i = atomicAdd(cnt, 1);
          if (i < 64) list[i] = row;
        }
      }
    }
  }
}

// ------------- GEMM: C[M][N] = A[M][K] * B[N][K]^T, BM=128, BN=NF*32 -------
// T2: LDS tiles stored with chunk-swizzle (pre-swizzled global source),
// fragments read with col ^= (row&7)<<3. Conflict-free ds_read_b128.

__device__ __forceinline__ void storeC(float* p, float v) { *p = v; }
__device__ __forceinline__ void storeC(unsigned short* p, float v) { *p = f2bf(v); }

template <typename OutT, int NF>
__global__ __launch_bounds__(256) void gemm_bt(const unsigned short* __restrict__ A,
                                               const unsigned short* __restrict__ B,
                                               OutT* __restrict__ C,
                                               int M, int N, int K) {
  constexpr int BN = NF * 32;
  __shared__ unsigned short As[128 * 64];
  __shared__ unsigned short Bs[BN * 64];
  const int tid = threadIdx.x;
  const int lane = tid & 63;
  const int w = tid >> 6;
  const int wr = w >> 1, wc = w & 1;
  const int l15 = lane & 15, lhi = lane >> 4;

  int lblk = blockIdx.y * gridDim.x + blockIdx.x;
  int nwg = gridDim.x * gridDim.y;
  int sw = (lblk & 7) * (nwg >> 3) + (lblk >> 3);
  int bxg = sw % gridDim.x;
  int byg = sw / gridDim.x;

  const size_t abase = (size_t)(bxg * 128) * K;
  const size_t bbase = (size_t)(byg * BN) * K;

  f32x4 acc[4][NF] = {};

  for (int k0 = 0; k0 < K; k0 += 64) {
    __syncthreads();
    #pragma unroll
    for (int i = 0; i < 4; ++i) {
      int c = (w << 8) + (i << 6) + lane;
      int row = c >> 3, cb = (c & 7) ^ (row & 7);
      load_lds16(A + abase + (size_t)row * K + k0 + cb * 8, &As[c * 8]);
    }
    #pragma unroll
    for (int i = 0; i < NF; ++i) {
      int c = w * (NF * 64) + (i << 6) + lane;
      int row = c >> 3, cb = (c & 7) ^ (row & 7);
      load_lds16(B + bbase + (size_t)row * K + k0 + cb * 8, &Bs[c * 8]);
    }
    __syncthreads();
    #pragma unroll
    for (int kk = 0; kk < 2; ++kk) {
      bf16x8 af[4], bfr[NF];
      #pragma unroll
      for (int m = 0; m < 4; ++m) {
        int ra = wr * 64 + m * 16 + l15;
        int col = (kk * 32 + lhi * 8) ^ ((ra & 7) << 3);
        af[m] = *(const bf16x8*)&As[ra * 64 + col];
      }
      #pragma unroll
      for (int n = 0; n < NF; ++n) {
        int rb = wc * NF * 16 + n * 16 + l15;
        int col = (kk * 32 + lhi * 8) ^ ((rb & 7) << 3);
        bfr[n] = *(const bf16x8*)&Bs[rb * 64 + col];
      }
      #pragma unroll
      for (int m = 0; m < 4; ++m)
        #pragma unroll
        for (int n = 0; n < NF; ++n)
          acc[m][n] = __builtin_amdgcn_mfma_f32_16x16x32_bf16(af[m], bfr[n], acc[m][n], 0, 0, 0);
    }
  }

  #pragma unroll
  for (int m = 0; m < 4; ++m) {
    int row0 = bxg * 128 + wr * 64 + m * 16 + lhi * 4;
    #pragma unroll
    for (int n = 0; n < NF; ++n) {
      int col = byg * BN + wc * NF * 16 + n * 16 + l15;
      #pragma unroll
      for (int r = 0; r < 4; ++r)
        storeC(&C[(size_t)(row0 + r) * N + col], acc[m][n][r]);
    }
  }
}

// ------------ attention (R19 body, static schedule, 5 blocks/CU) -----------
// Grid 1280. Block b -> item b; blocks 1264..1279 also take tail item
// 1280+(1279-b) (16 len-1 items). Items sorted longest-first by idx.

__global__ __launch_bounds__(256) void attn_kernel(
    const unsigned short* __restrict__ qkv,  // [4096][2304] bf16
    const unsigned short* __restrict__ vt,   // [768][4096] bf16 V^T
    const unsigned* __restrict__ maskw,      // [4096][128]
    const int* __restrict__ mask_future,
    float* __restrict__ parts,               // [1296][4224] f32 (O|l)
    unsigned short* __restrict__ scr) {      // scrambled [4096*768] bf16
  const int tid = threadIdx.x;
  const int lane = tid & 63;
  const int w = tid >> 6;
  const int l15 = lane & 15, lhi = lane >> 4;
  const bool causal = (mask_future[0] != 0);
  const int srcA = l15 + (((2 * lhi) & 3) << 4);
  const int srcB = l15 + (((2 * lhi + 1) & 3) << 4);
  const int hi2 = lhi >> 1;
  const int blk = blockIdx.x;

  // all-ones bf16 B-fragment for row-sum MFMA
  union { bf16x8 v; unsigned u[4]; } onesf;
  #pragma unroll
  for (int i = 0; i < 4; ++i) onesf.u[i] = 0x3F803F80u;

  __shared__ unsigned short Klds[2][64 * 64];  // [key][d], swizzled
  __shared__ unsigned short Vs[2][64 * 64];    // [d][key], swizzled
  // total shared = 32768B exactly -> 5 blocks/CU

  // per-lane staging geometry (item-invariant)
  int srow[2], scb[2];
  #pragma unroll
  for (int i = 0; i < 2; ++i) {
    int cc = (w << 7) + (i << 6) + lane;
    srow[i] = cc >> 3;
    scb[i] = ((cc & 7) ^ (srow[i] & 7)) * 8;
  }

  for (int s = 0; s < 2; ++s) {
    int idx;
    if (s == 0) idx = blk;
    else if (blk >= 1264) idx = 1280 + (1279 - blk);
    else break;

    __syncthreads();  // previous item's LDS reads complete before restage

    int c, bx, h;
    if (idx < 444)      { c = 0; bx = 63 - idx / 12; h = idx % 12; }
    else if (idx < 552) { int j = idx - 444; c = 1; bx = 63 - j / 12; h = j % 12; }
    else if (idx < 1008) {
      int j = idx - 552; int L = 27 - j / 24; int u = j % 24;
      c = (u < 12) ? 1 : 0; bx = c ? (27 + L) : (L - 1); h = u % 12;
    } else {
      int j = idx - 1008; int L = 8 - j / 36; int u = j % 36;
      c = (u < 12) ? 2 : ((u < 24) ? 1 : 0);
      bx = (c == 2) ? (55 + L) : ((c == 1) ? (27 + L) : (L - 1)); h = u % 12;
    }

    int t0c, t1c, diag;
    bool split;
    if (causal) {
      t0c = c * 28;
      t1c = min(t0c + 28, bx + 1);
      diag = bx;
      split = (bx >= 28);
    } else {  // non-causal: c=0 items do the whole range, others skip
      if (c != 0) continue;
      t0c = 0; t1c = 64; diag = 64; split = false;
    }
    const int hoff = h * 192;
    const int l0 = bx << 6;
    const int lq = l0 + w * 16 + l15;

    // hoisted staging base pointers (advance by tile)
    const unsigned short* kb[2];
    const unsigned short* vb[2];
    #pragma unroll
    for (int i = 0; i < 2; ++i) {
      kb[i] = qkv + (size_t)(t0c * 64 + srow[i]) * 2304 + hoff + 64 + scb[i];
      vb[i] = vt + (size_t)(h * 64 + srow[i]) * 4096 + t0c * 64 + scb[i];
    }

    // Q B-fragments, pre-scaled by CEXP (logits emerge in log2 units)
    bf16x8 qf[2];
    {
      const unsigned short* qp = qkv + (size_t)lq * 2304 + hoff;
      qf[0] = *(const bf16x8*)(qp + lhi * 8);
      qf[1] = *(const bf16x8*)(qp + 32 + lhi * 8);
      #pragma unroll
      for (int i = 0; i < 2; ++i) {
        union { bf16x8 v; unsigned u[4]; } qa; qa.v = qf[i];
        #pragma unroll
        for (int p = 0; p < 4; ++p) {
          float lo = bf2f((unsigned short)(qa.u[p] & 0xffff)) * CEXP;
          float hi = bf2f((unsigned short)(qa.u[p] >> 16)) * CEXP;
          asm("v_cvt_pk_bf16_f32 %0, %1, %2" : "=v"(qa.u[p]) : "v"(lo), "v"(hi));
        }
        qf[i] = qa.v;
      }
    }
    // prologue: stage tile t0c -> buf 0
    #pragma unroll
    for (int i = 0; i < 2; ++i) {
      int cc = (w << 7) + (i << 6) + lane;
      load_lds16(kb[i], &Klds[0][cc * 8]);
      load_lds16(vb[i], &Vs[0][cc * 8]);
    }
    const unsigned* mrow_p = maskw + lq * 128;
    uint2 mk_next = *(const uint2*)(mrow_p + t0c * 2);

    f32x4 oacc[4] = {};
    f32x4 osum = {};  // row sums of P, rows = w*16 + lhi*4 + r
    int cur = 0;

    for (int it = t0c; it < t1c; ++it) {
      __syncthreads();  // drains stage(it); protects buf reuse

      if (it + 1 < t1c) {
        #pragma unroll
        for (int i = 0; i < 2; ++i) {
          kb[i] += 64 * 2304;
          vb[i] += 64;
          int cc = (w << 7) + (i << 6) + lane;
          load_lds16(kb[i], &Klds[cur ^ 1][cc * 8]);
          load_lds16(vb[i], &Vs[cur ^ 1][cc * 8]);
        }
      }
      uint2 mk = mk_next;
      if (it + 1 < t1c) mk_next = *(const uint2*)(mrow_p + (it + 1) * 2);

      const int s0 = it * 64;

      // S^T (log2 units) = mfma(A=K, B=Q·CEXP); lane: S[q=lq][k=s0+n*16+lhi*4+r]
      f32x4 sacc[4] = {};
      __builtin_amdgcn_s_setprio(1);
      #pragma unroll
      for (int kk = 0; kk < 2; ++kk) {
        bf16x8 kf[4];
        #pragma unroll
        for (int n = 0; n < 4; ++n) {
          int rk = n * 16 + l15;
          int col = (kk * 32 + lhi * 8) ^ ((rk & 7) << 3);
          kf[n] = *(const bf16x8*)&Klds[cur][rk * 64 + col];
        }
        #pragma unroll
        for (int n = 0; n < 4; ++n)
          sacc[n] = __builtin_amdgcn_mfma_f32_16x16x32_bf16(kf[n], qf[kk], sacc[n], 0, 0, 0);
      }
      __builtin_amdgcn_s_setprio(0);

      // masked logits -> p = exp2(logit); masked -> exp2(KNEG) = 0
      float vals[4][4];
      {
        unsigned a = mk.x >> (lhi * 4);
        unsigned b = mk.y >> (lhi * 4);
        if (it < diag) {
          #pragma unroll
          for (int n = 0; n < 4; ++n) {
            unsigned wsh = ((n < 2) ? a : b) >> ((n & 1) << 4);
            #pragma unroll
            for (int r = 0; r < 4; ++r)
              vals[n][r] = ((wsh >> r) & 1u) ? sacc[n][r] : KNEG;
          }
        } else {  // diagonal tile
          #pragma unroll
          for (int n = 0; n < 4; ++n) {
            unsigned wsh = ((n < 2) ? a : b) >> ((n & 1) << 4);
            int kb2 = s0 + n * 16 + lhi * 4;
            #pragma unroll
            for (int r = 0; r < 4; ++r) {
              float vv = (kb2 + r > lq) ? KNEG : sacc[n][r];
              vals[n][r] = ((wsh >> r) & 1u) ? vv : KNEG;
            }
          }
        }
      }

      #pragma unroll
      for (int n = 0; n < 4; ++n)
        #pragma unroll
        for (int r = 0; r < 4; ++r)
          vals[n][r] = fexp2(vals[n][r]);

      // pack P to bf16 pairs
      unsigned pk[4][2];
      #pragma unroll
      for (int n = 0; n < 4; ++n)
        #pragma unroll
        for (int rp = 0; rp < 2; ++rp)
          asm("v_cvt_pk_bf16_f32 %0, %1, %2"
              : "=v"(pk[n][rp])
              : "v"(vals[n][2 * rp]), "v"(vals[n][2 * rp + 1]));

      // PV + row-sum (ones-vector MFMA shares the A fragment)
      #pragma unroll
      for (int kk = 0; kk < 2; ++kk) {
        unsigned a0 = __shfl(pk[2 * kk][0], srcA);
        unsigned a1 = __shfl(pk[2 * kk][1], srcA);
        unsigned a2 = __shfl(pk[2 * kk][0], srcB);
        unsigned a3 = __shfl(pk[2 * kk][1], srcB);
        unsigned b0 = __shfl(pk[2 * kk + 1][0], srcA);
        unsigned b1 = __shfl(pk[2 * kk + 1][1], srcA);
        unsigned b2 = __shfl(pk[2 * kk + 1][0], srcB);
        unsigned b3 = __shfl(pk[2 * kk + 1][1], srcB);
        union { bf16x8 v; unsigned u[4]; } af;
        af.u[0] = hi2 ? b0 : a0;
        af.u[1] = hi2 ? b1 : a1;
        af.u[2] = hi2 ? b2 : a2;
        af.u[3] = hi2 ? b3 : a3;
        __builtin_amdgcn_s_setprio(1);
        osum = __builtin_amdgcn_mfma_f32_16x16x32_bf16(af.v, onesf.v, osum, 0, 0, 0);
        #pragma unroll
        for (int n = 0; n < 4; ++n) {
          int rv = n * 16 + l15;
          int col = (kk * 32 + lhi * 8) ^ ((rv & 7) << 3);
          bf16x8 vf = *(const bf16x8*)&Vs[cur][rv * 64 + col];
          oacc[n] = __builtin_amdgcn_mfma_f32_16x16x32_bf16(af.v, vf, oacc[n], 0, 0, 0);
        }
        __builtin_amdgcn_s_setprio(0);
      }
      cur ^= 1;
    }

    // ---------- finalize (osum[r] already in (lhi,r) row layout) ----------
    const int row0 = w * 16 + lhi * 4;

    if (split) {
      int prefix = bx + max(bx - 28, 0) + max(bx - 56, 0);
      float* pg = parts + (size_t)((prefix + c) * 12 + h) * 4224;
      #pragma unroll
      for (int n = 0; n < 4; ++n)
        #pragma unroll
        for (int r = 0; r < 4; ++r)
          pg[(size_t)(row0 + r) * 64 + n * 16 + l15] = oacc[n][r];
      if (l15 == 0) {
        #pragma unroll
        for (int r = 0; r < 4; ++r)
          pg[4096 + row0 + r] = osum[r];
      }
    } else {
      float rq[4];
      #pragma unroll
      for (int r = 0; r < 4; ++r) rq[r] = 1.0f / osum[r];
      #pragma unroll
      for (int n = 0; n < 4; ++n) {
        int d = n * 16 + l15;
        size_t base = (size_t)h * 262144 + (size_t)d * 4096 + (size_t)(l0 + row0);
        us4 o;
        #pragma unroll
        for (int r = 0; r < 4; ++r) o[r] = f2bf(oacc[n][r] * rq[r]);
        *(us4*)(scr + base) = o;
      }
    }
  }
}

// -------- fused: merge_k (blocks 0..431) + fixrows (blocks 432..1199) ------

__global__ __launch_bounds__(256) void merge_fix(
    const float* __restrict__ parts, const unsigned short* __restrict__ qkv,
    const unsigned short* __restrict__ vt, const unsigned* __restrict__ maskw,
    const int* __restrict__ mask_future, const int* __restrict__ cnt,
    const int* __restrict__ list, unsigned short* __restrict__ scr) {
  const int b = blockIdx.x;
  const bool causal = (mask_future[0] != 0);
  if (b < 432) {
    if (!causal) return;  // non-causal: no splits
    const int sg = b;
    const int bx = 28 + sg / 12;
    const int h = sg % 12;
    const int nch = 2 + (bx >= 56);
    const int prefix = bx + max(bx - 28, 0) + max(bx - 56, 0);
    const int t = threadIdx.x;
    const int row = t >> 2;
    const int dg = (t & 3) * 16;

    const float* pg[3];
    for (int cc = 0; cc < 3; ++cc)
      pg[cc] = parts + (size_t)((prefix + min(cc, nch - 1)) * 12 + h) * 4224;

    float L = pg[0][4096 + row] + pg[1][4096 + row];
    if (nch == 3) L += pg[2][4096 + row];
    if (L == 0.f) return;  // degenerate row: fixrows owns it (no race)
    float rL = 1.0f / L;

    #pragma unroll
    for (int dd = 0; dd < 16; ++dd) {
      int d = dg + dd;
      float o = pg[0][(size_t)row * 64 + d] + pg[1][(size_t)row * 64 + d];
      if (nch == 3) o += pg[2][(size_t)row * 64 + d];
      scr[(size_t)h * 262144 + (size_t)d * 4096 + bx * 64 + row] = f2bf(o * rL);
    }
  } else {
    const int bb = b - 432;
    const int i = bb / 12;
    const int h = bb % 12;
    int n = *cnt; if (n > 64) n = 64;
    if (i >= n) return;
    const int row = list[i];
    const int tid = threadIdx.x;
    const int lane = tid & 63;
    const int wv = tid >> 6;

    __shared__ float qs[64];
    __shared__ float ps[4096];
    __shared__ float red[16];

    if (tid < 64) qs[tid] = bf2f(qkv[(size_t)row * 2304 + h * 192 + tid]);
    __syncthreads();

    float pv[16];
    float mymax = -INFINITY;
    #pragma unroll
    for (int kk = 0; kk < 16; ++kk) {
      int key = tid * 16 + kk;
      const unsigned short* kp = qkv + (size_t)key * 2304 + h * 192 + 64;
      float s = 0.f;
      #pragma unroll
      for (int d8 = 0; d8 < 8; ++d8) {
        bf16x8 kv8 = *(const bf16x8*)(kp + d8 * 8);
        #pragma unroll
        for (int e = 0; e < 8; ++e)
          s += qs[d8 * 8 + e] * bf2f((unsigned short)kv8[e]);
      }
      s *= 0.125f;
      unsigned bit = (maskw[row * 128 + (key >> 5)] >> (key & 31)) & 1u;
      float val = bit ? ((causal && key > row) ? s - 10000.f : s) : -10000.f;
      pv[kk] = val;
      mymax = fmaxf(mymax, val);
    }
    for (int xx = 1; xx < 64; xx <<= 1) mymax = fmaxf(mymax, __shfl_xor(mymax, xx));
    if (lane == 0) red[wv] = mymax;
    __syncthreads();
    const float M = fmaxf(fmaxf(red[0], red[1]), fmaxf(red[2], red[3]));

    float sum = 0.f;
    #pragma unroll
    for (int kk = 0; kk < 16; ++kk) {
      float p = fexp2((pv[kk] - M) * L2E);
      ps[tid * 16 + kk] = p;
      sum += p;
    }
    for (int xx = 1; xx < 64; xx <<= 1) sum += __shfl_xor(sum, xx);
    if (lane == 0) red[8 + wv] = sum;
    __syncthreads();
    const float L = red[8] + red[9] + red[10] + red[11];

    const int d = tid >> 2, qq = tid & 3;
    float acc = 0.f;
    for (int jb = qq * 1024; jb < qq * 1024 + 1024; jb += 8) {
      bf16x8 vv8 = *(const bf16x8*)&vt[(size_t)(h * 64 + d) * 4096 + jb];
      #pragma unroll
      for (int e = 0; e < 8; ++e)
        acc += ps[jb + e] * bf2f((unsigned short)vv8[e]);
    }
    acc += __shfl_xor(acc, 1);
    acc += __shfl_xor(acc, 2);
    if (qq == 0)
      scr[(size_t)h * 262144 + (size_t)d * 4096 + row] = f2bf(acc / L);
  }
}

// -------------------- launch --------------------

extern "C" void kernel_launch(void* const* d_in, const int* in_sizes, int n_in,
                              void* d_out, int out_size, void* d_ws, size_t ws_size,
                              hipStream_t stream) {
  const float* q = (const float*)d_in[0];
  const float* k = (const float*)d_in[1];
  const float* v = (const float*)d_in[2];
  const int* attn_mask = (const int*)d_in[3];
  const int* mask_future = (const int*)d_in[4];
  const float* W_qkv = (const float*)d_in[5];
  const float* W_out = (const float*)d_in[6];
  float* out = (float*)d_out;

  char* ws = (char*)d_ws;
  unsigned short* xb    = (unsigned short*)(ws);            // [0,18.87M) live until qkv GEMM
  unsigned short* vt    = (unsigned short*)(ws);            // [0,6.29M) after tv_rowflag
  char*           ctl   = ws + 6291456;                     // 4KB, memset AFTER gemm
  int*            cnt   = (int*)(ctl + 256);
  int*            list  = (int*)(ctl + 1024);               // [64]
  float*          parts = (float*)(ws + 6295552);           // 1296*4224*4 = 21.90MB
  unsigned short* wqkvb = (unsigned short*)(ws + 18874368); // dead after qkv GEMM
  unsigned short* qkvb  = (unsigned short*)(ws + 29491200);
  unsigned*       maskw = (unsigned*)(ws + 48365568);
  unsigned short* scr   = (unsigned short*)(ws + 50462720);
  unsigned short* woutb = (unsigned short*)(ws + 56754176);
  if (ws_size < 57933824) return;

  pack_all<<<9536, 256, 0, stream>>>(q, k, v, W_qkv, W_out, attn_mask,
                                     xb, wqkvb, woutb, maskw);
  gemm_bt<unsigned short, 3><<<dim3(32, 24), 256, 0, stream>>>(xb, wqkvb, qkvb, 4096, 2304, 2304);
  hipMemsetAsync(ctl, 0, 4096, stream);   // AFTER gemm: xb dead (R6 lesson)
  tv_rowflag<<<1024, 256, 0, stream>>>(qkvb, vt, maskw, mask_future, cnt, list);
  attn_kernel<<<1280, 256, 0, stream>>>(qkvb, vt, maskw, mask_future, parts, scr);
  merge_fix<<<1200, 256, 0, stream>>>(parts, qkvb, vt, maskw, mask_future, cnt, list, scr);
  gemm_bt<float, 1><<<dim3(32, 24), 256, 0, stream>>>(scr, woutb, out, 4096, 768, 768);
}